// Round 4
// baseline (5153.183 us; speedup 1.0000x reference)
//
#include <hip/hip_runtime.h>
#include <cstdint>

typedef unsigned short bfraw;
typedef __attribute__((ext_vector_type(8))) short short8;
typedef __attribute__((ext_vector_type(4))) float f32x4;
typedef __attribute__((ext_vector_type(4))) unsigned int u32x4;

#define DEV static __device__ __forceinline__

constexpr int NCHUNK = 8;
constexpr int CHUNK = 6250;
constexpr int CHUNK_LD = 6272;
constexpr int LAYERS = 6;

DEV float b2f(bfraw s) { return __uint_as_float(((unsigned)s) << 16); }
DEV bfraw f2b(float f) {
  unsigned u = __float_as_uint(f);
  u += 0x7FFFu + ((u >> 16) & 1u);
  return (bfraw)(u >> 16);
}
DEV float keyinv16(unsigned k) {
  unsigned raw = (k & 0x8000u) ? (k ^ 0x8000u) : (~k & 0xFFFFu);
  return b2f((bfraw)raw);
}

// ---------------- fp32 -> bf16 conversion ----------------
__global__ __launch_bounds__(256) void k_cvt(const float* __restrict__ src,
                                             bfraw* __restrict__ dst, int n4) {
  int i = blockIdx.x * 256 + threadIdx.x;
  if (i < n4) {
    float4 v = ((const float4*)src)[i];
    ushort4 o;
    o.x = f2b(v.x); o.y = f2b(v.y); o.z = f2b(v.z); o.w = f2b(v.w);
    ((ushort4*)dst)[i] = o;
  }
}

// strided-chunk fp32 -> bf16 (gathers nch chunks of n4PerChunk float4s)
__global__ __launch_bounds__(256) void k_cvt_s(const float* __restrict__ src,
                                               bfraw* __restrict__ dst,
                                               int n4PerChunk, long srcStride4, int nch) {
  long i = (long)blockIdx.x * 256 + threadIdx.x;
  if (i < (long)n4PerChunk * nch) {
    int c = (int)(i / n4PerChunk);
    int j = (int)(i % n4PerChunk);
    float4 v = ((const float4*)src)[c * srcStride4 + j];
    ushort4 o;
    o.x = f2b(v.x); o.y = f2b(v.y); o.z = f2b(v.z); o.w = f2b(v.w);
    ((ushort4*)dst)[i] = o;
  }
}

// ---------------- transpose sa Wv slice: WvT[l][k][j] = sa_in_w[l,1024+j,k] ----------------
__global__ __launch_bounds__(256) void k_tr(const float* __restrict__ sa_in_w,
                                            bfraw* __restrict__ WvT) {
  __shared__ float tile[32][33];
  const int tx = threadIdx.x & 31, ty = threadIdx.x >> 5;  // 32 x 8
  const int j0 = blockIdx.y * 32, k0 = blockIdx.x * 32;
  const long l = blockIdx.z;
#pragma unroll
  for (int p = 0; p < 4; ++p)
    tile[ty + p * 8][tx] = sa_in_w[(l * 1536 + 1024 + j0 + ty + p * 8) * 512 + k0 + tx];
  __syncthreads();
#pragma unroll
  for (int p = 0; p < 4; ++p)
    WvT[l * 262144 + (long)(k0 + ty + p * 8) * 512 + j0 + tx] = f2b(tile[tx][ty + p * 8]);
}

// ---------------- bsa[l,m] = sum_j Wo[l,m,j]*bv[l,j] + bo[l,m] ----------------
__global__ __launch_bounds__(256) void k_bsa(const float* __restrict__ sa_out_w,
                                             const float* __restrict__ sa_in_b,
                                             const float* __restrict__ sa_out_b,
                                             float* __restrict__ bsa) {
  __shared__ float bv[512];
  const int t = threadIdx.x;
  const long l = blockIdx.x;
  bv[t] = sa_in_b[l * 1536 + 1024 + t];
  bv[t + 256] = sa_in_b[l * 1536 + 1024 + t + 256];
  __syncthreads();
#pragma unroll
  for (int h = 0; h < 2; ++h) {
    int m = t + h * 256;
    const float* wr = sa_out_w + (l * 512 + m) * 512;
    float s = 0.f;
    for (int q = 0; q < 128; ++q) {
      float4 v = ((const float4*)wr)[q];
      s += v.x * bv[q * 4] + v.y * bv[q * 4 + 1] + v.z * bv[q * 4 + 2] + v.w * bv[q * 4 + 3];
    }
    bsa[l * 512 + m] = s + sa_out_b[l * 512 + m];
  }
}

// ---------------- Generic bt-GEMM: C[M,N] = A[M,K] @ B[N,K]^T (+bias) ----------------
// TM=128: 4 waves 2x2, each 4x4 of 16x16x32 MFMA. TM=64: 4 waves 1x4, each 4x2.
// XOR-swizzled LDS. DEPTH-2 register prefetch (two named tile sets, macro-expanded
// so all register indexing is compile-time): loads for kt+2 are issued right after
// staging kt, giving ~2 compute-phases of lead to cover HBM latency instead of 1.
// Epilogue stages output tile in LDS, streams out nt dwordx4.
template <int TM, bool OUTF32, bool OUTBF, bool RELU, bool BIAS, bool SWZ>
__global__ __launch_bounds__(256, 2) void k_gemm(
    const bfraw* __restrict__ A, int lda, long sA,
    const bfraw* __restrict__ B, int ldb, long sB,
    float* __restrict__ Cf, bfraw* __restrict__ Cb, int ldc, long sC,
    const float* __restrict__ bias, int sBias,
    int N, int K) {
  constexpr int WR = TM / 64;       // wave-row groups (2 or 1)
  constexpr int CW = 32 * WR;       // cols per wave (64 or 32)
  constexpr int JT = CW / 16;       // j tiles (4 or 2)
  constexpr int AP = TM / 32;       // A staging loads (4 or 2)
  constexpr int STAGE_B = TM * 64 * 2 + 128 * 64 * 2;
  constexpr int EPP = OUTF32 ? 132 : 136;  // epilogue LDS pitch (elements)
  constexpr int EP_B = OUTF32 ? TM * 132 * 4 : TM * 136 * 2;
  constexpr int SMEM_B = STAGE_B > EP_B ? STAGE_B : EP_B;
  __shared__ __align__(16) char smem[SMEM_B];
  bfraw* lsA = (bfraw*)smem;
  bfraw* lsB = (bfraw*)(smem + TM * 64 * 2);
  const int t = threadIdx.x;
  const int lane = t & 63;
  const int wave = t >> 6;
  const int wr = (TM == 128) ? (wave & 1) : 0;
  const int wc = (TM == 128) ? (wave >> 1) : wave;
  int bx, by;
  if (SWZ) {
    int l = blockIdx.x;
    int xcd = l & 7;
    int s = l >> 3;
    by = s / 7;
    int bxi = s % 7;
    bx = bxi * 8 + xcd;
    if (bx * 128 >= N) return;
  } else {
    bx = blockIdx.x;
    by = blockIdx.y;
  }
  const int z = blockIdx.z;
  A += (long)z * sA;
  B += (long)z * sB;

  const int sRow = t >> 3;  // 0..31
  const int sCh = t & 7;
  const int rowA0 = by * TM;
  const int colB0 = bx * 128;

  f32x4 acc[4][JT];
#pragma unroll
  for (int i = 0; i < 4; ++i)
#pragma unroll
    for (int j = 0; j < JT; ++j) {
      acc[i][j][0] = 0.f; acc[i][j][1] = 0.f; acc[i][j][2] = 0.f; acc[i][j][3] = 0.f;
    }

  const int nk = K >> 6;
  uint4 ra0[AP], rb0[4], ra1[AP], rb1[4];

#define LOAD_TILES(ktv, ra, rb)                                                   \
  {                                                                               \
    const int kt_ = (ktv);                                                        \
    _Pragma("unroll") for (int p = 0; p < AP; ++p) {                              \
      int fr = p * 32 + sRow;                                                     \
      int kc = sCh ^ (fr & 7);                                                    \
      ra[p] = *(const uint4*)(A + (long)(rowA0 + fr) * lda + kt_ * 64 + kc * 8);  \
    }                                                                             \
    _Pragma("unroll") for (int p = 0; p < 4; ++p) {                               \
      int fr = p * 32 + sRow;                                                     \
      int kc = sCh ^ (fr & 7);                                                    \
      int rB = colB0 + fr;                                                        \
      if (rB >= N) rB = N - 1;                                                    \
      rb[p] = *(const uint4*)(B + (long)rB * ldb + kt_ * 64 + kc * 8);            \
    }                                                                             \
  }

#define STAGE_LDS(ra, rb)                                                         \
  {                                                                               \
    __syncthreads();                                                              \
    _Pragma("unroll") for (int p = 0; p < AP; ++p) {                              \
      int fr = p * 32 + sRow;                                                     \
      *(uint4*)(lsA + fr * 64 + sCh * 8) = ra[p];                                 \
    }                                                                             \
    _Pragma("unroll") for (int p = 0; p < 4; ++p) {                               \
      int fr = p * 32 + sRow;                                                     \
      *(uint4*)(lsB + fr * 64 + sCh * 8) = rb[p];                                 \
    }                                                                             \
    __syncthreads();                                                              \
  }

#define COMPUTE_TILE()                                                            \
  {                                                                               \
    _Pragma("unroll") for (int ks = 0; ks < 2; ++ks) {                            \
      short8 af[4], bfm[JT];                                                      \
      _Pragma("unroll") for (int i = 0; i < 4; ++i) {                             \
        int r = wr * 64 + i * 16 + (lane & 15);                                   \
        int q = ks * 4 + (lane >> 4);                                             \
        af[i] = *(const short8*)(lsA + r * 64 + ((q ^ (r & 7)) * 8));             \
      }                                                                           \
      _Pragma("unroll") for (int j = 0; j < JT; ++j) {                            \
        int n = wc * CW + j * 16 + (lane & 15);                                   \
        int q = ks * 4 + (lane >> 4);                                             \
        bfm[j] = *(const short8*)(lsB + n * 64 + ((q ^ (n & 7)) * 8));            \
      }                                                                           \
      _Pragma("unroll") for (int i = 0; i < 4; ++i)                               \
        _Pragma("unroll") for (int j = 0; j < JT; ++j)                            \
          acc[i][j] = __builtin_amdgcn_mfma_f32_16x16x32_bf16(af[i], bfm[j], acc[i][j], 0, 0, 0); \
    }                                                                             \
  }

  LOAD_TILES(0, ra0, rb0);
  if (nk > 1) LOAD_TILES(1, ra1, rb1);
  for (int kt = 0; kt < nk; kt += 2) {
    STAGE_LDS(ra0, rb0);
    if (kt + 2 < nk) LOAD_TILES(kt + 2, ra0, rb0);
    COMPUTE_TILE();
    if (kt + 1 < nk) {
      STAGE_LDS(ra1, rb1);
      if (kt + 3 < nk) LOAD_TILES(kt + 3, ra1, rb1);
      COMPUTE_TILE();
    }
  }
#undef LOAD_TILES
#undef STAGE_LDS
#undef COMPUTE_TILE

  // ---- epilogue: stage tile in LDS, stream out with nt dwordx4 ----
  __syncthreads();  // all waves done reading lsA/lsB before we alias over them
  const int Nrem = N - colB0;  // valid cols in this tile (may exceed 128)
  if (OUTBF) {
    unsigned short* ep = (unsigned short*)smem;
#pragma unroll
    for (int j = 0; j < JT; ++j) {
      int cl = wc * CW + j * 16 + (lane & 15);
      int n = colB0 + cl;
      float bv = 0.f;
      if (BIAS) bv = (n < N) ? bias[(long)z * sBias + n] : 0.f;
#pragma unroll
      for (int i = 0; i < 4; ++i) {
        int r0 = wr * 64 + i * 16 + ((lane >> 4) << 2);
#pragma unroll
        for (int r = 0; r < 4; ++r) {
          float v = acc[i][j][r] + bv;
          if (RELU) v = fmaxf(v, 0.f);
          ep[(r0 + r) * EPP + cl] = f2b(v);
        }
      }
    }
    __syncthreads();
#pragma unroll
    for (int pass = 0; pass < TM / 16; ++pass) {
      int row = pass * 16 + (t >> 4);
      int c0 = (t & 15) * 8;
      long base = (long)(rowA0 + row) * ldc + (long)z * sC + colB0;
      if (c0 + 8 <= Nrem) {
        u32x4 v = *(const u32x4*)(ep + row * EPP + c0);
        __builtin_nontemporal_store(v, (u32x4*)(Cb + base + c0));
      } else if (c0 < Nrem) {
        for (int q = c0; q < Nrem && q < 128; ++q) Cb[base + q] = (bfraw)ep[row * EPP + q];
      }
    }
  }
  if (OUTF32) {
    float* ep = (float*)smem;
#pragma unroll
    for (int j = 0; j < JT; ++j) {
      int cl = wc * CW + j * 16 + (lane & 15);
      int n = colB0 + cl;
      float bv = 0.f;
      if (BIAS) bv = (n < N) ? bias[(long)z * sBias + n] : 0.f;
#pragma unroll
      for (int i = 0; i < 4; ++i) {
        int r0 = wr * 64 + i * 16 + ((lane >> 4) << 2);
#pragma unroll
        for (int r = 0; r < 4; ++r) {
          float v = acc[i][j][r] + bv;
          if (RELU) v = fmaxf(v, 0.f);
          ep[(r0 + r) * EPP + cl] = v;
        }
      }
    }
    __syncthreads();
#pragma unroll
    for (int pass = 0; pass < TM / 8; ++pass) {
      int row = pass * 8 + (t >> 5);
      int c0 = (t & 31) * 4;
      long base = (long)(rowA0 + row) * ldc + (long)z * sC + colB0;
      if (c0 + 4 <= Nrem) {
        f32x4 v = *(const f32x4*)(ep + row * EPP + c0);
        __builtin_nontemporal_store(v, (f32x4*)(Cf + base + c0));
      } else if (c0 < Nrem) {
        for (int q = c0; q < Nrem && q < 128; ++q) Cf[base + q] = ep[row * EPP + q];
      }
    }
  }
}

// ---------------- per-row top-64 of one bf16 score chunk (2-level radix select) ----------------
__global__ __launch_bounds__(256) void k_select(const bfraw* __restrict__ scores,
                                                float* __restrict__ cval, int* __restrict__ cidx,
                                                int chunk) {
  __shared__ unsigned short keys[CHUNK];
  __shared__ unsigned hist[256];
  __shared__ unsigned sh_sel, sh_rank, cnt_a, cnt_t;
  __shared__ unsigned tiebuf[64];
  const int t = threadIdx.x;
  const long b = blockIdx.x;
  const bfraw* row = scores + b * CHUNK_LD;
  for (int i = t; i < CHUNK; i += 256) {
    unsigned u = row[i];
    keys[i] = (u & 0x8000u) ? (unsigned short)(~u) : (unsigned short)(u | 0x8000u);
  }
  if (t == 0) { cnt_a = 0; cnt_t = 0; }
  unsigned prefix = 0, pmask = 0, rank = 64;
  for (int lev = 0; lev < 2; ++lev) {
    const int sh = 8 - lev * 8;
    hist[t] = 0;
    __syncthreads();
    for (int i = t; i < CHUNK; i += 256) {
      unsigned k = keys[i];
      if ((k & pmask) == prefix) atomicAdd(&hist[(k >> sh) & 255u], 1u);
    }
    __syncthreads();
    if (t < 64) {  // wave0: suffix-scan buckets, find bucket containing rank
      unsigned h0 = hist[t * 4], h1 = hist[t * 4 + 1], h2 = hist[t * 4 + 2], h3 = hist[t * 4 + 3];
      unsigned lsum = h0 + h1 + h2 + h3;
      unsigned suf = lsum;
#pragma unroll
      for (int off = 1; off < 64; off <<= 1) {
        unsigned vv = __shfl_down(suf, off);
        if (t + off < 64) suf += vv;
      }
      unsigned c = suf - lsum;
      unsigned hs[4] = {h0, h1, h2, h3};
#pragma unroll
      for (int q = 3; q >= 0; --q) {
        if (rank > c && rank <= c + hs[q]) { sh_sel = (unsigned)(t * 4 + q); sh_rank = rank - c; }
        c += hs[q];
      }
    }
    __syncthreads();
    prefix |= sh_sel << sh;
    pmask |= 255u << sh;
    rank = sh_rank;
    __syncthreads();
  }
  const unsigned cutkey = prefix;
  float* ov = cval + (b * NCHUNK + chunk) * 64;
  int* oi = cidx + (b * NCHUNK + chunk) * 64;
  for (int i = t; i < CHUNK; i += 256) {
    unsigned k = keys[i];
    if (k > cutkey) {
      unsigned p = atomicAdd(&cnt_a, 1u);
      ov[p] = keyinv16(k);
      oi[p] = chunk * CHUNK + i;
    } else if (k == cutkey) {
      unsigned p = atomicAdd(&cnt_t, 1u);
      if (p < 64) tiebuf[p] = (unsigned)i;
    }
  }
  __syncthreads();
  if (t == 0) {  // fill remaining slots from ties (lowest index first)
    int need = (int)rank;
    int tc = cnt_t < 64u ? (int)cnt_t : 64;
    int base = (int)cnt_a;
    float cv = keyinv16(cutkey);
    for (int s2 = 0; s2 < need; ++s2) {
      unsigned best = 0xFFFFFFFFu; int bq = 0;
      for (int q2 = 0; q2 < tc; ++q2)
        if (tiebuf[q2] < best) { best = tiebuf[q2]; bq = q2; }
      tiebuf[bq] = 0xFFFFFFFFu;
      ov[base + s2] = cv;
      oi[base + s2] = chunk * CHUNK + (int)best;
    }
  }
}

// ---------------- Refine: sort 512 cands, exact fp32 rescore top-64, top-32 + softmax ----------------
__global__ __launch_bounds__(256) void k_refine(const float* __restrict__ cval,
                                                const int* __restrict__ cidx,
                                                const float* __restrict__ x,
                                                const float* __restrict__ cf,
                                                int* __restrict__ tidx, float* __restrict__ w) {
  __shared__ float sv[512];
  __shared__ int si[512];
  __shared__ float xs[512];
  __shared__ float rv[64];
  __shared__ int ri[64];
  const int t = threadIdx.x;
  const long b = blockIdx.x;
  sv[t] = cval[b * 512 + t]; sv[t + 256] = cval[b * 512 + t + 256];
  si[t] = cidx[b * 512 + t]; si[t + 256] = cidx[b * 512 + t + 256];
  xs[t] = x[b * 512 + t]; xs[t + 256] = x[b * 512 + t + 256];
  __syncthreads();
  for (int k = 2; k <= 512; k <<= 1)
    for (int j = k >> 1; j >= 1; j >>= 1) {
      int i = ((t & ~(j - 1)) << 1) | (t & (j - 1));
      int p = i | j;
      bool dir = ((i & k) == 0);
      float va = sv[i], vb = sv[p];
      int ia = si[i], ib = si[p];
      bool pBetter = (vb > va) || (vb == va && ib < ia);
      if (pBetter == dir) { sv[i] = vb; sv[p] = va; si[i] = ib; si[p] = ia; }
      __syncthreads();
    }
  const int c = t >> 2, sub = t & 3;
  const int idx = si[c];
  const float* cr = cf + (long)idx * 512 + sub * 128;
  float s = 0.f;
#pragma unroll 8
  for (int q = 0; q < 32; ++q) {
    float4 vv = ((const float4*)cr)[q];
    const float* xr = xs + sub * 128 + q * 4;
    s += vv.x * xr[0] + vv.y * xr[1] + vv.z * xr[2] + vv.w * xr[3];
  }
  s += __shfl_xor(s, 1);
  s += __shfl_xor(s, 2);
  if (sub == 0) { rv[c] = s; ri[c] = idx; }
  __syncthreads();
  if (t < 64) {
    float v = rv[t];
    int ix = ri[t];
    for (int k = 2; k <= 64; k <<= 1)
      for (int j = k >> 1; j >= 1; j >>= 1) {
        float ov = __shfl_xor(v, j);
        int oi = __shfl_xor(ix, j);
        bool up = ((t & k) == 0);
        bool low = ((t & j) == 0);
        bool oBetter = (ov > v) || (ov == v && oi < ix);
        if (oBetter == (up == low)) { v = ov; ix = oi; }
      }
    float m = __shfl(v, 0);
    float e = (t < 32) ? __expf(v - m) : 0.f;
    float ssum = e;
#pragma unroll
    for (int off = 1; off < 64; off <<= 1) ssum += __shfl_xor(ssum, off);
    if (t < 32) {
      w[b * 32 + t] = e / ssum;
      tidx[b * 32 + t] = ix;
    }
  }
}

// ---------------- Build kv (B,33,512) bf16 ----------------
__global__ __launch_bounds__(256) void k_buildkv(const float* __restrict__ x, const bfraw* __restrict__ cfb,
                                                 const float* __restrict__ type_emb,
                                                 const float* __restrict__ pos_emb,
                                                 const float* __restrict__ w, const int* __restrict__ tidx,
                                                 bfraw* __restrict__ kv) {
  const int t = threadIdx.x;
  const long b = blockIdx.x;
  bfraw* out = kv + b * (33 * 512);
  const float* xr = x + b * 512;
  for (int d = t; d < 512; d += 256) out[d] = f2b(xr[d] + type_emb[d]);
  for (int j = 0; j < 32; ++j) {
    const long ci = tidx[b * 32 + j];
    const float wj = w[b * 32 + j];
    const bfraw* cr = cfb + ci * 512;
    bfraw* o = out + (j + 1) * 512;
    for (int d = t; d < 512; d += 256)
      o[d] = f2b(wj * b2f(cr[d]) + pos_emb[j * 512 + d] + type_emb[512 + d]);
  }
}

// ---------------- t init ----------------
__global__ __launch_bounds__(256) void k_init_t(const float* __restrict__ cls, float* __restrict__ tf,
                                                bfraw* __restrict__ tb) {
  const long i = (long)blockIdx.x * 256 + threadIdx.x;
  const int d = (int)(i & 511);
  tf[i] = cls[d];
  tb[i] = f2b(cls[d]);
}

// ---------------- wkT prep: wkT[i,h,d,e] = ca_in_w[i, 512 + h*64 + e, d] ----------------
__global__ __launch_bounds__(256) void k_prep(const float* __restrict__ ca_in_w, bfraw* __restrict__ wkT) {
  const long o = (long)blockIdx.x * 256 + threadIdx.x;
  const int e = (int)(o & 63);
  long r = o >> 6;
  const int d = (int)(r & 511); r >>= 9;
  const int h = (int)(r & 7);
  const int i = (int)(r >> 3);
  wkT[o] = f2b(ca_in_w[((long)i * 1536 + 512 + h * 64 + e) * 512 + d]);
}

// ---------------- CA attention core ----------------
__global__ __launch_bounds__(256) void k_attn(const bfraw* __restrict__ u, const bfraw* __restrict__ kv,
                                              bfraw* __restrict__ cout) {
  __shared__ __align__(16) bfraw kvs[33 * 512];
  __shared__ __align__(16) bfraw us[8 * 512];
  __shared__ float ps[8 * 33];
  const int t = threadIdx.x, lane = t & 63, wave = t >> 6;
  const long b = blockIdx.x;

  const uint4* kg = (const uint4*)(kv + b * (33 * 512));
  uint4* kd = (uint4*)kvs;
  for (int i = t; i < 33 * 512 / 8; i += 256) kd[i] = kg[i];
  const uint4* ug = (const uint4*)(u + b * (8 * 512));
  uint4* ud = (uint4*)us;
  for (int i = t; i < 8 * 512 / 8; i += 256) ud[i] = ug[i];
  __syncthreads();

  float u0[8], u1[8];
#pragma unroll
  for (int q = 0; q < 8; ++q) {
    u0[q] = b2f(us[wave * 512 + lane * 8 + q]);
    u1[q] = b2f(us[(wave + 4) * 512 + lane * 8 + q]);
  }
  for (int j = 0; j < 33; ++j) {
    short8 kk = *(const short8*)(kvs + j * 512 + lane * 8);
    float p0 = 0.f, p1 = 0.f;
#pragma unroll
    for (int q = 0; q < 8; ++q) {
      float kvv = b2f((bfraw)kk[q]);
      p0 += u0[q] * kvv;
      p1 += u1[q] * kvv;
    }
#pragma unroll
    for (int off = 1; off < 64; off <<= 1) {
      p0 += __shfl_xor(p0, off);
      p1 += __shfl_xor(p1, off);
    }
    if (lane == 0) {
      ps[wave * 33 + j] = p0 * 0.125f;
      ps[(wave + 4) * 33 + j] = p1 * 0.125f;
    }
  }
  __syncthreads();
#pragma unroll
  for (int hh = 0; hh < 2; ++hh) {
    int h = wave + hh * 4;
    float sv2 = (lane < 33) ? ps[h * 33 + lane] : -3.0e38f;
    float m = sv2;
#pragma unroll
    for (int off = 1; off < 64; off <<= 1) m = fmaxf(m, __shfl_xor(m, off));
    float e = (lane < 33) ? __expf(sv2 - m) : 0.f;
    float s = e;
#pragma unroll
    for (int off = 1; off < 64; off <<= 1) s += __shfl_xor(s, off);
    if (lane < 33) ps[h * 33 + lane] = e / s;
  }
  __syncthreads();
#pragma unroll
  for (int hh = 0; hh < 2; ++hh) {
    int h = wave + hh * 4;
    float acc[8] = {0.f, 0.f, 0.f, 0.f, 0.f, 0.f, 0.f, 0.f};
    for (int j = 0; j < 33; ++j) {
      float pj = ps[h * 33 + j];
      short8 kk = *(const short8*)(kvs + j * 512 + lane * 8);
#pragma unroll
      for (int q = 0; q < 8; ++q) acc[q] += pj * b2f((bfraw)kk[q]);
    }
    union { bfraw o[8]; uint4 v4; } pk;
#pragma unroll
    for (int q = 0; q < 8; ++q) pk.o[q] = f2b(acc[q]);
    *(uint4*)(cout + (b * 8 + h) * 512 + lane * 8) = pk.v4;
  }
}

// ---------------- residual + LayerNorm ----------------
__global__ __launch_bounds__(256) void k_ln(float* __restrict__ tf, bfraw* __restrict__ tb,
                                            const float* __restrict__ delta,
                                            const float* __restrict__ g, const float* __restrict__ be) {
  const int lane = threadIdx.x & 63, wave = threadIdx.x >> 6;
  const long row = (long)blockIdx.x * 4 + wave;
  float* tr = tf + row * 512;
  const float* dr = delta + row * 512;
  float v[8];
  float4 a0 = *(const float4*)(tr + lane * 8);
  float4 a1 = *(const float4*)(tr + lane * 8 + 4);
  float4 d0 = *(const float4*)(dr + lane * 8);
  float4 d1 = *(const float4*)(dr + lane * 8 + 4);
  v[0] = a0.x + d0.x; v[1] = a0.y + d0.y; v[2] = a0.z + d0.z; v[3] = a0.w + d0.w;
  v[4] = a1.x + d1.x; v[5] = a1.y + d1.y; v[6] = a1.z + d1.z; v[7] = a1.w + d1.w;
  float s = 0.f;
#pragma unroll
  for (int q = 0; q < 8; ++q) s += v[q];
#pragma unroll
  for (int off = 1; off < 64; off <<= 1) s += __shfl_xor(s, off);
  const float mean = s * (1.f / 512.f);
  float sq = 0.f;
#pragma unroll
  for (int q = 0; q < 8; ++q) { float d = v[q] - mean; sq += d * d; }
#pragma unroll
  for (int off = 1; off < 64; off <<= 1) sq += __shfl_xor(sq, off);
  const float rs = 1.f / sqrtf(sq * (1.f / 512.f) + 1e-5f);
  float4 g0 = *(const float4*)(g + lane * 8);
  float4 g1 = *(const float4*)(g + lane * 8 + 4);
  float4 b0 = *(const float4*)(be + lane * 8);
  float4 b1 = *(const float4*)(be + lane * 8 + 4);
  float gg[8] = {g0.x, g0.y, g0.z, g0.w, g1.x, g1.y, g1.z, g1.w};
  float bb[8] = {b0.x, b0.y, b0.z, b0.w, b1.x, b1.y, b1.z, b1.w};
  float o[8];
  union { bfraw u16[8]; uint4 u4; } pk;
#pragma unroll
  for (int q = 0; q < 8; ++q) {
    o[q] = (v[q] - mean) * rs * gg[q] + bb[q];
    pk.u16[q] = f2b(o[q]);
  }
  *(float4*)(tr + lane * 8) = make_float4(o[0], o[1], o[2], o[3]);
  *(float4*)(tr + lane * 8 + 4) = make_float4(o[4], o[5], o[6], o[7]);
  *(uint4*)(tb + row * 512 + lane * 8) = pk.u4;
}

// ---------------- final triple-normalize ----------------
__global__ __launch_bounds__(64) void k_final(const float* __restrict__ tf, const float* __restrict__ coarse,
                                              float* __restrict__ out) {
  const int lane = threadIdx.x;
  const long b = blockIdx.x;
  const float* fr = tf + b * 512;
  const float* cr = coarse + b * 512;
  float4 f0 = *(const float4*)(fr + lane * 8);
  float4 f1 = *(const float4*)(fr + lane * 8 + 4);
  float4 c0 = *(const float4*)(cr + lane * 8);
  float4 c1 = *(const float4*)(cr + lane * 8 + 4);
  float f[8] = {f0.x, f0.y, f0.z, f0.w, f1.x, f1.y, f1.z, f1.w};
  float c[8] = {c0.x, c0.y, c0.z, c0.w, c1.x, c1.y, c1.z, c1.w};
  float sf = 0.f, sc = 0.f;
#pragma unroll
  for (int q = 0; q < 8; ++q) { sf += f[q] * f[q]; sc += c[q] * c[q]; }
#pragma unroll
  for (int off = 1; off < 64; off <<= 1) { sf += __shfl_xor(sf, off); sc += __shfl_xor(sc, off); }
  const float rf = 1.f / sqrtf(sf), rc = 1.f / sqrtf(sc);
  float a[8];
  float sa = 0.f;
#pragma unroll
  for (int q = 0; q < 8; ++q) { a[q] = f[q] * rf + c[q] * rc; sa += a[q] * a[q]; }
#pragma unroll
  for (int off = 1; off < 64; off <<= 1) sa += __shfl_xor(sa, off);
  const float ra = 1.f / sqrtf(sa);
  *(float4*)(out + b * 512 + lane * 8) = make_float4(a[0] * ra, a[1] * ra, a[2] * ra, a[3] * ra);
  *(float4*)(out + b * 512 + lane * 8 + 4) = make_float4(a[4] * ra, a[5] * ra, a[6] * ra, a[7] * ra);
}

// ---------------- workspace layout (bytes) ----------------
constexpr long OFF_XB = 0;                    //  4,194,304
constexpr long OFF_WKT = 4194304;             //  3,145,728
constexpr long OFF_SAOUT = 7340032;           //  3,145,728 (Wo bf16)
constexpr long OFF_WSAB = 10485760;           //  3,145,728 (Wsa bf16)
constexpr long OFF_CAWQ = 13631488;           //  3,145,728
constexpr long OFF_CAWV = 16777216;           //  3,145,728
constexpr long OFF_CAOUT = 19922944;          //  3,145,728
constexpr long OFF_REGW = 23068672;           //    524,288
constexpr long OFF_L1B = 23592960;            // 12,582,912 (all layers)
constexpr long OFF_L2B = 36175872;            // 12,582,912
constexpr long OFF_BSA = 48758784;            //     16,384
constexpr long OFF_TIDX = 48775168;           //    524,288
constexpr long OFF_WSM = 49299456;            //    524,288
constexpr long OFF_REGION = 49823744;         // 138,412,032 (WvT preamble / score bf16 / kv)
constexpr long OFF_POOL = 188235776;          // 83,886,080
constexpr long P_TF = 0;                      // 8,388,608 fp32 (phase1: cval)
constexpr long P_TB = 8388608;                // 4,194,304 bf16 (phase1: cidx lo)
constexpr long P_QBF = 12582912;              // 4,194,304 bf16 (phase1: cidx hi)
constexpr long P_UBUF = 16777216;             // 33,554,432 (phase1: cfb 51.2MB spans UBUF+part CBUF)
constexpr long P_CBUF = 50331648;             // 33,554,432 (delta +0, coarse +8,388,608)
constexpr long WS_TOTAL = OFF_POOL + 83886080;  // 272,121,856

extern "C" void kernel_launch(void* const* d_in, const int* in_sizes, int n_in,
                              void* d_out, int out_size, void* d_ws, size_t ws_size,
                              hipStream_t stream) {
  if (n_in < 25) return;
  if (ws_size < (size_t)WS_TOTAL) return;

  const float* x = (const float*)d_in[0];
  const float* cf = (const float*)d_in[1];
  const float* type_emb = (const float*)d_in[2];
  const float* pos_emb = (const float*)d_in[3];
  const float* cls = (const float*)d_in[4];
  const float* sa_in_w = (const float*)d_in[5];
  const float* sa_in_b = (const float*)d_in[6];
  const float* sa_out_w = (const float*)d_in[7];
  const float* sa_out_b = (const float*)d_in[8];
  const float* ca_in_w = (const float*)d_in[9];
  const float* ca_in_b = (const float*)d_in[10];
  const float* ca_out_w = (const float*)d_in[11];
  const float* ca_out_b = (const float*)d_in[12];
  const float* lin1_w = (const float*)d_in[13];
  const float* lin1_b = (const float*)d_in[14];
  const float* lin2_w = (const float*)d_in[15];
  const float* lin2_b = (const float*)d_in[16];
  const float* ln1_g = (const float*)d_in[17];
  const float* ln1_bp = (const float*)d_in[18];
  const float* ln2_g = (const float*)d_in[19];
  const float* ln2_bp = (const float*)d_in[20];
  const float* ln3_g = (const float*)d_in[21];
  const float* ln3_bp = (const float*)d_in[22];
  const float* region_w = (const float*)d_in[23];
  const float* region_b = (const float*)d_in[24];

  char* ws = (char*)d_ws;
  bfraw* xb = (bfraw*)(ws + OFF_XB);
  bfraw* wkT = (bfraw*)(ws + OFF_WKT);
  bfraw* saout = (bfraw*)(ws + OFF_SAOUT);
  bfraw* wsab = (bfraw*)(ws + OFF_WSAB);
  bfraw* cawq = (bfraw*)(ws + OFF_CAWQ);
  bfraw* cawv = (bfraw*)(ws + OFF_CAWV);
  bfraw* caout = (bfraw*)(ws + OFF_CAOUT);
  bfraw* regw = (bfraw*)(ws + OFF_REGW);
  bfraw* l1b = (bfraw*)(ws + OFF_L1B);
  bfraw* l2b = (bfraw*)(ws + OFF_L2B);
  float* bsa = (float*)(ws + OFF_BSA);
  int* tidx = (int*)(ws + OFF_TIDX);
  float* wsm = (float*)(ws + OFF_WSM);
  bfraw* WvT = (bfraw*)(ws + OFF_REGION);  // preamble only
  bfraw* scoreb = (bfraw*)(ws + OFF_REGION);
  bfraw* kv = (bfraw*)(ws + OFF_REGION);
  char* pool = ws + OFF_POOL;
  float* tf = (float*)(pool + P_TF);
  float* cval = (float*)(pool + P_TF);
  bfraw* tb = (bfraw*)(pool + P_TB);
  int* cidx = (int*)(pool + P_TB);
  bfraw* qbf = (bfraw*)(pool + P_QBF);
  bfraw* tmpb = (bfraw*)(pool + P_QBF);
  bfraw* ubuf = (bfraw*)(pool + P_UBUF);
  bfraw* ffb = (bfraw*)(pool + P_UBUF);
  bfraw* cfb = (bfraw*)(pool + P_UBUF);  // 51.2 MB, phase-1 only
  bfraw* cbuf = (bfraw*)(pool + P_CBUF);
  float* delta = (float*)(pool + P_CBUF);
  float* coarse = (float*)(pool + P_CBUF + 8388608);

  dim3 blk(256);

  // ---- preamble: conversions + SA fold ----
  k_cvt<<<2048, blk, 0, stream>>>(x, xb, 524288);
  k_cvt<<<25000, blk, 0, stream>>>(cf, cfb, 6400000);
  k_cvt<<<1536, blk, 0, stream>>>(sa_out_w, saout, 393216);
  k_cvt<<<1536, blk, 0, stream>>>(ca_out_w, caout, 393216);
  k_cvt<<<256, blk, 0, stream>>>(region_w, regw, 65536);
  k_cvt<<<6144, blk, 0, stream>>>(lin1_w, l1b, 1572864);
  k_cvt<<<6144, blk, 0, stream>>>(lin2_w, l2b, 1572864);
  k_cvt_s<<<1536, blk, 0, stream>>>(ca_in_w, cawq, 65536, 196608, 6);
  k_cvt_s<<<1536, blk, 0, stream>>>(ca_in_w + 1024 * 512, cawv, 65536, 196608, 6);
  k_prep<<<6144, blk, 0, stream>>>(ca_in_w, wkT);
  k_tr<<<dim3(16, 16, 6), blk, 0, stream>>>(sa_in_w, WvT);
  k_gemm<64, false, true, false, false, false><<<dim3(4, 8, 6), blk, 0, stream>>>(
      saout, 512, 262144, WvT, 512, 262144, nullptr, wsab, 512, 262144, nullptr, 0, 512, 512);
  k_bsa<<<6, blk, 0, stream>>>(sa_out_w, sa_in_b, sa_out_b, bsa);

  // ---- score GEMM (bf16 out, XCD-swizzled) + per-chunk top-64 ----
  for (int c = 0; c < NCHUNK; ++c) {
    k_gemm<128, false, true, false, false, true><<<dim3(1792, 1, 1), blk, 0, stream>>>(
        xb, 512, 0, cfb + (long)c * CHUNK * 512, 512, 0,
        nullptr, scoreb, CHUNK_LD, 0, nullptr, 0, CHUNK, 512);
    k_select<<<4096, blk, 0, stream>>>(scoreb, cval, cidx, c);
  }
  k_refine<<<4096, blk, 0, stream>>>(cval, cidx, x, cf, tidx, wsm);
  k_buildkv<<<4096, blk, 0, stream>>>(x, cfb, type_emb, pos_emb, wsm, tidx, kv);
  k_init_t<<<8192, blk, 0, stream>>>(cls, tf, tb);

  for (int i = 0; i < LAYERS; ++i) {
    const bfraw* ca_wq = cawq + (long)i * 262144;
    const float* ca_bq = ca_in_b + (long)i * 1536;
    const bfraw* ca_wv = cawv + (long)i * 262144;
    const float* ca_bv = ca_in_b + (long)i * 1536 + 1024;
    const bfraw* ca_wo = caout + (long)i * 262144;
    const float* ca_bo = ca_out_b + (long)i * 512;
    const bfraw* wkTi = wkT + (long)i * 8 * 512 * 64;

    // Self-attention folded: delta = t @ Wsa^T + bsa
    k_gemm<64, true, false, false, true, false><<<dim3(4, 64, 1), blk, 0, stream>>>(
        tb, 512, 0, wsab + (long)i * 262144, 512, 0, delta, nullptr, 512, 0, bsa + i * 512, 0, 512, 512);
    k_ln<<<1024, blk, 0, stream>>>(tf, tb, delta, ln1_g + i * 512, ln1_bp + i * 512);

    // Cross-attention (re-associated)
    k_gemm<64, false, true, false, true, false><<<dim3(4, 64, 1), blk, 0, stream>>>(
        tb, 512, 0, ca_wq, 512, 0, nullptr, qbf, 512, 0, ca_bq, 0, 512, 512);
    k_gemm<64, false, true, false, false, false><<<dim3(4, 64, 8), blk, 0, stream>>>(
        qbf, 512, 64, wkTi, 64, 32768, nullptr, ubuf, 4096, 512, nullptr, 0, 512, 64);
    k_attn<<<4096, blk, 0, stream>>>(ubuf, kv, cbuf);
    k_gemm<64, false, true, false, true, false><<<dim3(1, 64, 8), blk, 0, stream>>>(
        cbuf, 4096, 512, ca_wv, 512, 32768, nullptr, tmpb, 512, 64, ca_bv, 64, 64, 512);
    k_gemm<64, true, false, false, true, false><<<dim3(4, 64, 1), blk, 0, stream>>>(
        tmpb, 512, 0, ca_wo, 512, 0, delta, nullptr, 512, 0, ca_bo, 0, 512, 512);
    k_ln<<<1024, blk, 0, stream>>>(tf, tb, delta, ln2_g + i * 512, ln2_bp + i * 512);

    // FFN
    k_gemm<64, false, true, true, true, false><<<dim3(16, 64, 1), blk, 0, stream>>>(
        tb, 512, 0, l1b + (long)i * 1048576, 512, 0, nullptr, ffb, 2048, 0, lin1_b + i * 2048, 0, 2048, 512);
    k_gemm<64, true, false, false, true, false><<<dim3(4, 64, 1), blk, 0, stream>>>(
        ffb, 2048, 0, l2b + (long)i * 1048576, 2048, 0, delta, nullptr, 512, 0, lin2_b + i * 512, 0, 512, 2048);
    k_ln<<<1024, blk, 0, stream>>>(tf, tb, delta, ln3_g + i * 512, ln3_bp + i * 512);
  }

  k_gemm<64, true, false, false, true, false><<<dim3(4, 64, 1), blk, 0, stream>>>(
      xb, 512, 0, regw, 512, 0, coarse, nullptr, 512, 0, region_b, 0, 512, 512);
  k_final<<<4096, dim3(64), 0, stream>>>(tf, coarse, (float*)d_out);
}

// Round 5
// 2949.014 us; speedup vs baseline: 1.7474x; 1.7474x over previous
//
#include <hip/hip_runtime.h>
#include <cstdint>

typedef unsigned short bfraw;
typedef __attribute__((ext_vector_type(8))) short short8;
typedef __attribute__((ext_vector_type(4))) float f32x4;
typedef __attribute__((ext_vector_type(4))) unsigned int u32x4;

#define DEV static __device__ __forceinline__

constexpr int NCHUNK = 8;
constexpr int CHUNK = 6250;
constexpr int CHUNK_LD = 6272;
constexpr int LAYERS = 6;

DEV float b2f(bfraw s) { return __uint_as_float(((unsigned)s) << 16); }
DEV bfraw f2b(float f) {
  unsigned u = __float_as_uint(f);
  u += 0x7FFFu + ((u >> 16) & 1u);
  return (bfraw)(u >> 16);
}
DEV float keyinv16(unsigned k) {
  unsigned raw = (k & 0x8000u) ? (k ^ 0x8000u) : (~k & 0xFFFFu);
  return b2f((bfraw)raw);
}

// ---------------- fp32 -> bf16 conversion ----------------
__global__ __launch_bounds__(256) void k_cvt(const float* __restrict__ src,
                                             bfraw* __restrict__ dst, int n4) {
  int i = blockIdx.x * 256 + threadIdx.x;
  if (i < n4) {
    float4 v = ((const float4*)src)[i];
    ushort4 o;
    o.x = f2b(v.x); o.y = f2b(v.y); o.z = f2b(v.z); o.w = f2b(v.w);
    ((ushort4*)dst)[i] = o;
  }
}

// strided-chunk fp32 -> bf16 (gathers nch chunks of n4PerChunk float4s)
__global__ __launch_bounds__(256) void k_cvt_s(const float* __restrict__ src,
                                               bfraw* __restrict__ dst,
                                               int n4PerChunk, long srcStride4, int nch) {
  long i = (long)blockIdx.x * 256 + threadIdx.x;
  if (i < (long)n4PerChunk * nch) {
    int c = (int)(i / n4PerChunk);
    int j = (int)(i % n4PerChunk);
    float4 v = ((const float4*)src)[c * srcStride4 + j];
    ushort4 o;
    o.x = f2b(v.x); o.y = f2b(v.y); o.z = f2b(v.z); o.w = f2b(v.w);
    ((ushort4*)dst)[i] = o;
  }
}

// ---------------- transpose sa Wv slice: WvT[l][k][j] = sa_in_w[l,1024+j,k] ----------------
__global__ __launch_bounds__(256) void k_tr(const float* __restrict__ sa_in_w,
                                            bfraw* __restrict__ WvT) {
  __shared__ float tile[32][33];
  const int tx = threadIdx.x & 31, ty = threadIdx.x >> 5;  // 32 x 8
  const int j0 = blockIdx.y * 32, k0 = blockIdx.x * 32;
  const long l = blockIdx.z;
#pragma unroll
  for (int p = 0; p < 4; ++p)
    tile[ty + p * 8][tx] = sa_in_w[(l * 1536 + 1024 + j0 + ty + p * 8) * 512 + k0 + tx];
  __syncthreads();
#pragma unroll
  for (int p = 0; p < 4; ++p)
    WvT[l * 262144 + (long)(k0 + ty + p * 8) * 512 + j0 + tx] = f2b(tile[tx][ty + p * 8]);
}

// ---------------- bsa[l,m] = sum_j Wo[l,m,j]*bv[l,j] + bo[l,m] ----------------
__global__ __launch_bounds__(256) void k_bsa(const float* __restrict__ sa_out_w,
                                             const float* __restrict__ sa_in_b,
                                             const float* __restrict__ sa_out_b,
                                             float* __restrict__ bsa) {
  __shared__ float bv[512];
  const int t = threadIdx.x;
  const long l = blockIdx.x;
  bv[t] = sa_in_b[l * 1536 + 1024 + t];
  bv[t + 256] = sa_in_b[l * 1536 + 1024 + t + 256];
  __syncthreads();
#pragma unroll
  for (int h = 0; h < 2; ++h) {
    int m = t + h * 256;
    const float* wr = sa_out_w + (l * 512 + m) * 512;
    float s = 0.f;
    for (int q = 0; q < 128; ++q) {
      float4 v = ((const float4*)wr)[q];
      s += v.x * bv[q * 4] + v.y * bv[q * 4 + 1] + v.z * bv[q * 4 + 2] + v.w * bv[q * 4 + 3];
    }
    bsa[l * 512 + m] = s + sa_out_b[l * 512 + m];
  }
}

// ---------------- Generic bt-GEMM: C[M,N] = A[M,K] @ B[N,K]^T (+bias) ----------------
// TM=128: 4 waves 2x2, each 4x4 of 16x16x32 MFMA. TM=64: 4 waves 1x4, each 4x2.
// Staging via async global_load_lds width=16 (m97 structure): no VGPR round-trip,
// no ds_writes; compiler's pre-barrier vmcnt(0) drains the DMA. XOR swizzle is
// preserved by pre-swizzling the GLOBAL source address (kc = sCh^(fr&7)) while the
// LDS destination stays linear (thread t's dest t*16B == fr*128 + sCh*16 bytes).
// Epilogue stages output tile in LDS, streams out nt dwordx4.
template <int TM, bool OUTF32, bool OUTBF, bool RELU, bool BIAS, bool SWZ>
__global__ __launch_bounds__(256, 2) void k_gemm(
    const bfraw* __restrict__ A, int lda, long sA,
    const bfraw* __restrict__ B, int ldb, long sB,
    float* __restrict__ Cf, bfraw* __restrict__ Cb, int ldc, long sC,
    const float* __restrict__ bias, int sBias,
    int N, int K) {
  constexpr int WR = TM / 64;       // wave-row groups (2 or 1)
  constexpr int CW = 32 * WR;       // cols per wave (64 or 32)
  constexpr int JT = CW / 16;       // j tiles (4 or 2)
  constexpr int AP = TM / 32;       // A staging rounds (4 or 2)
  constexpr int STAGE_B = TM * 64 * 2 + 128 * 64 * 2;
  constexpr int EPP = OUTF32 ? 132 : 136;  // epilogue LDS pitch (elements)
  constexpr int EP_B = OUTF32 ? TM * 132 * 4 : TM * 136 * 2;
  constexpr int SMEM_B = STAGE_B > EP_B ? STAGE_B : EP_B;
  __shared__ __align__(16) char smem[SMEM_B];
  bfraw* lsA = (bfraw*)smem;
  bfraw* lsB = (bfraw*)(smem + TM * 64 * 2);
  const int t = threadIdx.x;
  const int lane = t & 63;
  const int wave = t >> 6;
  const int wr = (TM == 128) ? (wave & 1) : 0;
  const int wc = (TM == 128) ? (wave >> 1) : wave;
  int bx, by;
  if (SWZ) {
    int l = blockIdx.x;
    int xcd = l & 7;
    int s = l >> 3;
    by = s / 7;
    int bxi = s % 7;
    bx = bxi * 8 + xcd;
    if (bx * 128 >= N) return;
  } else {
    bx = blockIdx.x;
    by = blockIdx.y;
  }
  const int z = blockIdx.z;
  A += (long)z * sA;
  B += (long)z * sB;

  const int sRow = t >> 3;  // 0..31
  const int sCh = t & 7;
  const int rowA0 = by * TM;
  const int colB0 = bx * 128;

  f32x4 acc[4][JT];
#pragma unroll
  for (int i = 0; i < 4; ++i)
#pragma unroll
    for (int j = 0; j < JT; ++j) {
      acc[i][j][0] = 0.f; acc[i][j][1] = 0.f; acc[i][j][2] = 0.f; acc[i][j][3] = 0.f;
    }

  const int nk = K >> 6;
  // Per-thread swizzled global source bases (element offsets), LDS dests linear.
  // A round p: fr = p*32 + sRow, kc = sCh ^ (fr&7); LDS dest = lsA + p*4096B + wave*1024B.
  const bfraw* aSrc[AP];
#pragma unroll
  for (int p = 0; p < AP; ++p) {
    int fr = p * 32 + sRow;
    int kc = sCh ^ (fr & 7);
    aSrc[p] = A + (long)(rowA0 + fr) * lda + kc * 8;
  }
  const bfraw* bSrc[4];
#pragma unroll
  for (int p = 0; p < 4; ++p) {
    int fr = p * 32 + sRow;
    int kc = sCh ^ (fr & 7);
    int rB = colB0 + fr;
    if (rB >= N) rB = N - 1;  // clamp; polluted cols masked at store
    bSrc[p] = B + (long)rB * ldb + kc * 8;
  }

  for (int kt = 0; kt < nk; ++kt) {
    __syncthreads();  // previous tile fully consumed by all waves
#pragma unroll
    for (int p = 0; p < AP; ++p)
      __builtin_amdgcn_global_load_lds(
          (const unsigned int*)(aSrc[p] + kt * 64),
          (unsigned int*)(smem + p * 4096 + wave * 1024), 16, 0, 0);
#pragma unroll
    for (int p = 0; p < 4; ++p)
      __builtin_amdgcn_global_load_lds(
          (const unsigned int*)(bSrc[p] + kt * 64),
          (unsigned int*)(smem + TM * 128 + p * 4096 + wave * 1024), 16, 0, 0);
    __syncthreads();  // compiler emits s_waitcnt vmcnt(0) before s_barrier -> LDS ready
#pragma unroll
    for (int ks = 0; ks < 2; ++ks) {
      short8 af[4], bfm[JT];
#pragma unroll
      for (int i = 0; i < 4; ++i) {
        int r = wr * 64 + i * 16 + (lane & 15);
        int q = ks * 4 + (lane >> 4);
        af[i] = *(const short8*)(lsA + r * 64 + ((q ^ (r & 7)) * 8));
      }
#pragma unroll
      for (int j = 0; j < JT; ++j) {
        int n = wc * CW + j * 16 + (lane & 15);
        int q = ks * 4 + (lane >> 4);
        bfm[j] = *(const short8*)(lsB + n * 64 + ((q ^ (n & 7)) * 8));
      }
#pragma unroll
      for (int i = 0; i < 4; ++i)
#pragma unroll
        for (int j = 0; j < JT; ++j)
          acc[i][j] = __builtin_amdgcn_mfma_f32_16x16x32_bf16(af[i], bfm[j], acc[i][j], 0, 0, 0);
    }
  }

  // ---- epilogue: stage tile in LDS, stream out with nt dwordx4 ----
  __syncthreads();  // all waves done reading lsA/lsB before we alias over them
  const int Nrem = N - colB0;  // valid cols in this tile (may exceed 128)
  if (OUTBF) {
    unsigned short* ep = (unsigned short*)smem;
#pragma unroll
    for (int j = 0; j < JT; ++j) {
      int cl = wc * CW + j * 16 + (lane & 15);
      int n = colB0 + cl;
      float bv = 0.f;
      if (BIAS) bv = (n < N) ? bias[(long)z * sBias + n] : 0.f;
#pragma unroll
      for (int i = 0; i < 4; ++i) {
        int r0 = wr * 64 + i * 16 + ((lane >> 4) << 2);
#pragma unroll
        for (int r = 0; r < 4; ++r) {
          float v = acc[i][j][r] + bv;
          if (RELU) v = fmaxf(v, 0.f);
          ep[(r0 + r) * EPP + cl] = f2b(v);
        }
      }
    }
    __syncthreads();
#pragma unroll
    for (int pass = 0; pass < TM / 16; ++pass) {
      int row = pass * 16 + (t >> 4);
      int c0 = (t & 15) * 8;
      long base = (long)(rowA0 + row) * ldc + (long)z * sC + colB0;
      if (c0 + 8 <= Nrem) {
        u32x4 v = *(const u32x4*)(ep + row * EPP + c0);
        __builtin_nontemporal_store(v, (u32x4*)(Cb + base + c0));
      } else if (c0 < Nrem) {
        for (int q = c0; q < Nrem && q < 128; ++q) Cb[base + q] = (bfraw)ep[row * EPP + q];
      }
    }
  }
  if (OUTF32) {
    float* ep = (float*)smem;
#pragma unroll
    for (int j = 0; j < JT; ++j) {
      int cl = wc * CW + j * 16 + (lane & 15);
      int n = colB0 + cl;
      float bv = 0.f;
      if (BIAS) bv = (n < N) ? bias[(long)z * sBias + n] : 0.f;
#pragma unroll
      for (int i = 0; i < 4; ++i) {
        int r0 = wr * 64 + i * 16 + ((lane >> 4) << 2);
#pragma unroll
        for (int r = 0; r < 4; ++r) {
          float v = acc[i][j][r] + bv;
          if (RELU) v = fmaxf(v, 0.f);
          ep[(r0 + r) * EPP + cl] = v;
        }
      }
    }
    __syncthreads();
#pragma unroll
    for (int pass = 0; pass < TM / 8; ++pass) {
      int row = pass * 8 + (t >> 5);
      int c0 = (t & 31) * 4;
      long base = (long)(rowA0 + row) * ldc + (long)z * sC + colB0;
      if (c0 + 4 <= Nrem) {
        f32x4 v = *(const f32x4*)(ep + row * EPP + c0);
        __builtin_nontemporal_store(v, (f32x4*)(Cf + base + c0));
      } else if (c0 < Nrem) {
        for (int q = c0; q < Nrem && q < 128; ++q) Cf[base + q] = ep[row * EPP + q];
      }
    }
  }
}

// ---------------- per-row top-64 of one bf16 score chunk (2-level radix select) ----------------
__global__ __launch_bounds__(256) void k_select(const bfraw* __restrict__ scores,
                                                float* __restrict__ cval, int* __restrict__ cidx,
                                                int chunk) {
  __shared__ unsigned short keys[CHUNK];
  __shared__ unsigned hist[256];
  __shared__ unsigned sh_sel, sh_rank, cnt_a, cnt_t;
  __shared__ unsigned tiebuf[64];
  const int t = threadIdx.x;
  const long b = blockIdx.x;
  const bfraw* row = scores + b * CHUNK_LD;
  for (int i = t; i < CHUNK; i += 256) {
    unsigned u = row[i];
    keys[i] = (u & 0x8000u) ? (unsigned short)(~u) : (unsigned short)(u | 0x8000u);
  }
  if (t == 0) { cnt_a = 0; cnt_t = 0; }
  unsigned prefix = 0, pmask = 0, rank = 64;
  for (int lev = 0; lev < 2; ++lev) {
    const int sh = 8 - lev * 8;
    hist[t] = 0;
    __syncthreads();
    for (int i = t; i < CHUNK; i += 256) {
      unsigned k = keys[i];
      if ((k & pmask) == prefix) atomicAdd(&hist[(k >> sh) & 255u], 1u);
    }
    __syncthreads();
    if (t < 64) {  // wave0: suffix-scan buckets, find bucket containing rank
      unsigned h0 = hist[t * 4], h1 = hist[t * 4 + 1], h2 = hist[t * 4 + 2], h3 = hist[t * 4 + 3];
      unsigned lsum = h0 + h1 + h2 + h3;
      unsigned suf = lsum;
#pragma unroll
      for (int off = 1; off < 64; off <<= 1) {
        unsigned vv = __shfl_down(suf, off);
        if (t + off < 64) suf += vv;
      }
      unsigned c = suf - lsum;
      unsigned hs[4] = {h0, h1, h2, h3};
#pragma unroll
      for (int q = 3; q >= 0; --q) {
        if (rank > c && rank <= c + hs[q]) { sh_sel = (unsigned)(t * 4 + q); sh_rank = rank - c; }
        c += hs[q];
      }
    }
    __syncthreads();
    prefix |= sh_sel << sh;
    pmask |= 255u << sh;
    rank = sh_rank;
    __syncthreads();
  }
  const unsigned cutkey = prefix;
  float* ov = cval + (b * NCHUNK + chunk) * 64;
  int* oi = cidx + (b * NCHUNK + chunk) * 64;
  for (int i = t; i < CHUNK; i += 256) {
    unsigned k = keys[i];
    if (k > cutkey) {
      unsigned p = atomicAdd(&cnt_a, 1u);
      ov[p] = keyinv16(k);
      oi[p] = chunk * CHUNK + i;
    } else if (k == cutkey) {
      unsigned p = atomicAdd(&cnt_t, 1u);
      if (p < 64) tiebuf[p] = (unsigned)i;
    }
  }
  __syncthreads();
  if (t == 0) {  // fill remaining slots from ties (lowest index first)
    int need = (int)rank;
    int tc = cnt_t < 64u ? (int)cnt_t : 64;
    int base = (int)cnt_a;
    float cv = keyinv16(cutkey);
    for (int s2 = 0; s2 < need; ++s2) {
      unsigned best = 0xFFFFFFFFu; int bq = 0;
      for (int q2 = 0; q2 < tc; ++q2)
        if (tiebuf[q2] < best) { best = tiebuf[q2]; bq = q2; }
      tiebuf[bq] = 0xFFFFFFFFu;
      ov[base + s2] = cv;
      oi[base + s2] = chunk * CHUNK + (int)best;
    }
  }
}

// ---------------- Refine: sort 512 cands, exact fp32 rescore top-64, top-32 + softmax ----------------
__global__ __launch_bounds__(256) void k_refine(const float* __restrict__ cval,
                                                const int* __restrict__ cidx,
                                                const float* __restrict__ x,
                                                const float* __restrict__ cf,
                                                int* __restrict__ tidx, float* __restrict__ w) {
  __shared__ float sv[512];
  __shared__ int si[512];
  __shared__ float xs[512];
  __shared__ float rv[64];
  __shared__ int ri[64];
  const int t = threadIdx.x;
  const long b = blockIdx.x;
  sv[t] = cval[b * 512 + t]; sv[t + 256] = cval[b * 512 + t + 256];
  si[t] = cidx[b * 512 + t]; si[t + 256] = cidx[b * 512 + t + 256];
  xs[t] = x[b * 512 + t]; xs[t + 256] = x[b * 512 + t + 256];
  __syncthreads();
  for (int k = 2; k <= 512; k <<= 1)
    for (int j = k >> 1; j >= 1; j >>= 1) {
      int i = ((t & ~(j - 1)) << 1) | (t & (j - 1));
      int p = i | j;
      bool dir = ((i & k) == 0);
      float va = sv[i], vb = sv[p];
      int ia = si[i], ib = si[p];
      bool pBetter = (vb > va) || (vb == va && ib < ia);
      if (pBetter == dir) { sv[i] = vb; sv[p] = va; si[i] = ib; si[p] = ia; }
      __syncthreads();
    }
  const int c = t >> 2, sub = t & 3;
  const int idx = si[c];
  const float* cr = cf + (long)idx * 512 + sub * 128;
  float s = 0.f;
#pragma unroll 8
  for (int q = 0; q < 32; ++q) {
    float4 vv = ((const float4*)cr)[q];
    const float* xr = xs + sub * 128 + q * 4;
    s += vv.x * xr[0] + vv.y * xr[1] + vv.z * xr[2] + vv.w * xr[3];
  }
  s += __shfl_xor(s, 1);
  s += __shfl_xor(s, 2);
  if (sub == 0) { rv[c] = s; ri[c] = idx; }
  __syncthreads();
  if (t < 64) {
    float v = rv[t];
    int ix = ri[t];
    for (int k = 2; k <= 64; k <<= 1)
      for (int j = k >> 1; j >= 1; j >>= 1) {
        float ov = __shfl_xor(v, j);
        int oi = __shfl_xor(ix, j);
        bool up = ((t & k) == 0);
        bool low = ((t & j) == 0);
        bool oBetter = (ov > v) || (ov == v && oi < ix);
        if (oBetter == (up == low)) { v = ov; ix = oi; }
      }
    float m = __shfl(v, 0);
    float e = (t < 32) ? __expf(v - m) : 0.f;
    float ssum = e;
#pragma unroll
    for (int off = 1; off < 64; off <<= 1) ssum += __shfl_xor(ssum, off);
    if (t < 32) {
      w[b * 32 + t] = e / ssum;
      tidx[b * 32 + t] = ix;
    }
  }
}

// ---------------- Build kv (B,33,512) bf16 ----------------
__global__ __launch_bounds__(256) void k_buildkv(const float* __restrict__ x, const bfraw* __restrict__ cfb,
                                                 const float* __restrict__ type_emb,
                                                 const float* __restrict__ pos_emb,
                                                 const float* __restrict__ w, const int* __restrict__ tidx,
                                                 bfraw* __restrict__ kv) {
  const int t = threadIdx.x;
  const long b = blockIdx.x;
  bfraw* out = kv + b * (33 * 512);
  const float* xr = x + b * 512;
  for (int d = t; d < 512; d += 256) out[d] = f2b(xr[d] + type_emb[d]);
  for (int j = 0; j < 32; ++j) {
    const long ci = tidx[b * 32 + j];
    const float wj = w[b * 32 + j];
    const bfraw* cr = cfb + ci * 512;
    bfraw* o = out + (j + 1) * 512;
    for (int d = t; d < 512; d += 256)
      o[d] = f2b(wj * b2f(cr[d]) + pos_emb[j * 512 + d] + type_emb[512 + d]);
  }
}

// ---------------- t init ----------------
__global__ __launch_bounds__(256) void k_init_t(const float* __restrict__ cls, float* __restrict__ tf,
                                                bfraw* __restrict__ tb) {
  const long i = (long)blockIdx.x * 256 + threadIdx.x;
  const int d = (int)(i & 511);
  tf[i] = cls[d];
  tb[i] = f2b(cls[d]);
}

// ---------------- wkT prep: wkT[i,h,d,e] = ca_in_w[i, 512 + h*64 + e, d] ----------------
__global__ __launch_bounds__(256) void k_prep(const float* __restrict__ ca_in_w, bfraw* __restrict__ wkT) {
  const long o = (long)blockIdx.x * 256 + threadIdx.x;
  const int e = (int)(o & 63);
  long r = o >> 6;
  const int d = (int)(r & 511); r >>= 9;
  const int h = (int)(r & 7);
  const int i = (int)(r >> 3);
  wkT[o] = f2b(ca_in_w[((long)i * 1536 + 512 + h * 64 + e) * 512 + d]);
}

// ---------------- CA attention core ----------------
__global__ __launch_bounds__(256) void k_attn(const bfraw* __restrict__ u, const bfraw* __restrict__ kv,
                                              bfraw* __restrict__ cout) {
  __shared__ __align__(16) bfraw kvs[33 * 512];
  __shared__ __align__(16) bfraw us[8 * 512];
  __shared__ float ps[8 * 33];
  const int t = threadIdx.x, lane = t & 63, wave = t >> 6;
  const long b = blockIdx.x;

  const uint4* kg = (const uint4*)(kv + b * (33 * 512));
  uint4* kd = (uint4*)kvs;
  for (int i = t; i < 33 * 512 / 8; i += 256) kd[i] = kg[i];
  const uint4* ug = (const uint4*)(u + b * (8 * 512));
  uint4* ud = (uint4*)us;
  for (int i = t; i < 8 * 512 / 8; i += 256) ud[i] = ug[i];
  __syncthreads();

  float u0[8], u1[8];
#pragma unroll
  for (int q = 0; q < 8; ++q) {
    u0[q] = b2f(us[wave * 512 + lane * 8 + q]);
    u1[q] = b2f(us[(wave + 4) * 512 + lane * 8 + q]);
  }
  for (int j = 0; j < 33; ++j) {
    short8 kk = *(const short8*)(kvs + j * 512 + lane * 8);
    float p0 = 0.f, p1 = 0.f;
#pragma unroll
    for (int q = 0; q < 8; ++q) {
      float kvv = b2f((bfraw)kk[q]);
      p0 += u0[q] * kvv;
      p1 += u1[q] * kvv;
    }
#pragma unroll
    for (int off = 1; off < 64; off <<= 1) {
      p0 += __shfl_xor(p0, off);
      p1 += __shfl_xor(p1, off);
    }
    if (lane == 0) {
      ps[wave * 33 + j] = p0 * 0.125f;
      ps[(wave + 4) * 33 + j] = p1 * 0.125f;
    }
  }
  __syncthreads();
#pragma unroll
  for (int hh = 0; hh < 2; ++hh) {
    int h = wave + hh * 4;
    float sv2 = (lane < 33) ? ps[h * 33 + lane] : -3.0e38f;
    float m = sv2;
#pragma unroll
    for (int off = 1; off < 64; off <<= 1) m = fmaxf(m, __shfl_xor(m, off));
    float e = (lane < 33) ? __expf(sv2 - m) : 0.f;
    float s = e;
#pragma unroll
    for (int off = 1; off < 64; off <<= 1) s += __shfl_xor(s, off);
    if (lane < 33) ps[h * 33 + lane] = e / s;
  }
  __syncthreads();
#pragma unroll
  for (int hh = 0; hh < 2; ++hh) {
    int h = wave + hh * 4;
    float acc[8] = {0.f, 0.f, 0.f, 0.f, 0.f, 0.f, 0.f, 0.f};
    for (int j = 0; j < 33; ++j) {
      float pj = ps[h * 33 + j];
      short8 kk = *(const short8*)(kvs + j * 512 + lane * 8);
#pragma unroll
      for (int q = 0; q < 8; ++q) acc[q] += pj * b2f((bfraw)kk[q]);
    }
    union { bfraw o[8]; uint4 v4; } pk;
#pragma unroll
    for (int q = 0; q < 8; ++q) pk.o[q] = f2b(acc[q]);
    *(uint4*)(cout + (b * 8 + h) * 512 + lane * 8) = pk.v4;
  }
}

// ---------------- residual + LayerNorm ----------------
__global__ __launch_bounds__(256) void k_ln(float* __restrict__ tf, bfraw* __restrict__ tb,
                                            const float* __restrict__ delta,
                                            const float* __restrict__ g, const float* __restrict__ be) {
  const int lane = threadIdx.x & 63, wave = threadIdx.x >> 6;
  const long row = (long)blockIdx.x * 4 + wave;
  float* tr = tf + row * 512;
  const float* dr = delta + row * 512;
  float v[8];
  float4 a0 = *(const float4*)(tr + lane * 8);
  float4 a1 = *(const float4*)(tr + lane * 8 + 4);
  float4 d0 = *(const float4*)(dr + lane * 8);
  float4 d1 = *(const float4*)(dr + lane * 8 + 4);
  v[0] = a0.x + d0.x; v[1] = a0.y + d0.y; v[2] = a0.z + d0.z; v[3] = a0.w + d0.w;
  v[4] = a1.x + d1.x; v[5] = a1.y + d1.y; v[6] = a1.z + d1.z; v[7] = a1.w + d1.w;
  float s = 0.f;
#pragma unroll
  for (int q = 0; q < 8; ++q) s += v[q];
#pragma unroll
  for (int off = 1; off < 64; off <<= 1) s += __shfl_xor(s, off);
  const float mean = s * (1.f / 512.f);
  float sq = 0.f;
#pragma unroll
  for (int q = 0; q < 8; ++q) { float d = v[q] - mean; sq += d * d; }
#pragma unroll
  for (int off = 1; off < 64; off <<= 1) sq += __shfl_xor(sq, off);
  const float rs = 1.f / sqrtf(sq * (1.f / 512.f) + 1e-5f);
  float4 g0 = *(const float4*)(g + lane * 8);
  float4 g1 = *(const float4*)(g + lane * 8 + 4);
  float4 b0 = *(const float4*)(be + lane * 8);
  float4 b1 = *(const float4*)(be + lane * 8 + 4);
  float gg[8] = {g0.x, g0.y, g0.z, g0.w, g1.x, g1.y, g1.z, g1.w};
  float bb[8] = {b0.x, b0.y, b0.z, b0.w, b1.x, b1.y, b1.z, b1.w};
  float o[8];
  union { bfraw u16[8]; uint4 u4; } pk;
#pragma unroll
  for (int q = 0; q < 8; ++q) {
    o[q] = (v[q] - mean) * rs * gg[q] + bb[q];
    pk.u16[q] = f2b(o[q]);
  }
  *(float4*)(tr + lane * 8) = make_float4(o[0], o[1], o[2], o[3]);
  *(float4*)(tr + lane * 8 + 4) = make_float4(o[4], o[5], o[6], o[7]);
  *(uint4*)(tb + row * 512 + lane * 8) = pk.u4;
}

// ---------------- final triple-normalize ----------------
__global__ __launch_bounds__(64) void k_final(const float* __restrict__ tf, const float* __restrict__ coarse,
                                              float* __restrict__ out) {
  const int lane = threadIdx.x;
  const long b = blockIdx.x;
  const float* fr = tf + b * 512;
  const float* cr = coarse + b * 512;
  float4 f0 = *(const float4*)(fr + lane * 8);
  float4 f1 = *(const float4*)(fr + lane * 8 + 4);
  float4 c0 = *(const float4*)(cr + lane * 8);
  float4 c1 = *(const float4*)(cr + lane * 8 + 4);
  float f[8] = {f0.x, f0.y, f0.z, f0.w, f1.x, f1.y, f1.z, f1.w};
  float c[8] = {c0.x, c0.y, c0.z, c0.w, c1.x, c1.y, c1.z, c1.w};
  float sf = 0.f, sc = 0.f;
#pragma unroll
  for (int q = 0; q < 8; ++q) { sf += f[q] * f[q]; sc += c[q] * c[q]; }
#pragma unroll
  for (int off = 1; off < 64; off <<= 1) { sf += __shfl_xor(sf, off); sc += __shfl_xor(sc, off); }
  const float rf = 1.f / sqrtf(sf), rc = 1.f / sqrtf(sc);
  float a[8];
  float sa = 0.f;
#pragma unroll
  for (int q = 0; q < 8; ++q) { a[q] = f[q] * rf + c[q] * rc; sa += a[q] * a[q]; }
#pragma unroll
  for (int off = 1; off < 64; off <<= 1) sa += __shfl_xor(sa, off);
  const float ra = 1.f / sqrtf(sa);
  *(float4*)(out + b * 512 + lane * 8) = make_float4(a[0] * ra, a[1] * ra, a[2] * ra, a[3] * ra);
  *(float4*)(out + b * 512 + lane * 8 + 4) = make_float4(a[4] * ra, a[5] * ra, a[6] * ra, a[7] * ra);
}

// ---------------- workspace layout (bytes) ----------------
constexpr long OFF_XB = 0;                    //  4,194,304
constexpr long OFF_WKT = 4194304;             //  3,145,728
constexpr long OFF_SAOUT = 7340032;           //  3,145,728 (Wo bf16)
constexpr long OFF_WSAB = 10485760;           //  3,145,728 (Wsa bf16)
constexpr long OFF_CAWQ = 13631488;           //  3,145,728
constexpr long OFF_CAWV = 16777216;           //  3,145,728
constexpr long OFF_CAOUT = 19922944;          //  3,145,728
constexpr long OFF_REGW = 23068672;           //    524,288
constexpr long OFF_L1B = 23592960;            // 12,582,912 (all layers)
constexpr long OFF_L2B = 36175872;            // 12,582,912
constexpr long OFF_BSA = 48758784;            //     16,384
constexpr long OFF_TIDX = 48775168;           //    524,288
constexpr long OFF_WSM = 49299456;            //    524,288
constexpr long OFF_REGION = 49823744;         // 138,412,032 (WvT preamble / score bf16 / kv)
constexpr long OFF_POOL = 188235776;          // 83,886,080
constexpr long P_TF = 0;                      // 8,388,608 fp32 (phase1: cval)
constexpr long P_TB = 8388608;                // 4,194,304 bf16 (phase1: cidx lo)
constexpr long P_QBF = 12582912;              // 4,194,304 bf16 (phase1: cidx hi)
constexpr long P_UBUF = 16777216;             // 33,554,432 (phase1: cfb 51.2MB spans UBUF+part CBUF)
constexpr long P_CBUF = 50331648;             // 33,554,432 (delta +0, coarse +8,388,608)
constexpr long WS_TOTAL = OFF_POOL + 83886080;  // 272,121,856

extern "C" void kernel_launch(void* const* d_in, const int* in_sizes, int n_in,
                              void* d_out, int out_size, void* d_ws, size_t ws_size,
                              hipStream_t stream) {
  if (n_in < 25) return;
  if (ws_size < (size_t)WS_TOTAL) return;

  const float* x = (const float*)d_in[0];
  const float* cf = (const float*)d_in[1];
  const float* type_emb = (const float*)d_in[2];
  const float* pos_emb = (const float*)d_in[3];
  const float* cls = (const float*)d_in[4];
  const float* sa_in_w = (const float*)d_in[5];
  const float* sa_in_b = (const float*)d_in[6];
  const float* sa_out_w = (const float*)d_in[7];
  const float* sa_out_b = (const float*)d_in[8];
  const float* ca_in_w = (const float*)d_in[9];
  const float* ca_in_b = (const float*)d_in[10];
  const float* ca_out_w = (const float*)d_in[11];
  const float* ca_out_b = (const float*)d_in[12];
  const float* lin1_w = (const float*)d_in[13];
  const float* lin1_b = (const float*)d_in[14];
  const float* lin2_w = (const float*)d_in[15];
  const float* lin2_b = (const float*)d_in[16];
  const float* ln1_g = (const float*)d_in[17];
  const float* ln1_bp = (const float*)d_in[18];
  const float* ln2_g = (const float*)d_in[19];
  const float* ln2_bp = (const float*)d_in[20];
  const float* ln3_g = (const float*)d_in[21];
  const float* ln3_bp = (const float*)d_in[22];
  const float* region_w = (const float*)d_in[23];
  const float* region_b = (const float*)d_in[24];

  char* ws = (char*)d_ws;
  bfraw* xb = (bfraw*)(ws + OFF_XB);
  bfraw* wkT = (bfraw*)(ws + OFF_WKT);
  bfraw* saout = (bfraw*)(ws + OFF_SAOUT);
  bfraw* wsab = (bfraw*)(ws + OFF_WSAB);
  bfraw* cawq = (bfraw*)(ws + OFF_CAWQ);
  bfraw* cawv = (bfraw*)(ws + OFF_CAWV);
  bfraw* caout = (bfraw*)(ws + OFF_CAOUT);
  bfraw* regw = (bfraw*)(ws + OFF_REGW);
  bfraw* l1b = (bfraw*)(ws + OFF_L1B);
  bfraw* l2b = (bfraw*)(ws + OFF_L2B);
  float* bsa = (float*)(ws + OFF_BSA);
  int* tidx = (int*)(ws + OFF_TIDX);
  float* wsm = (float*)(ws + OFF_WSM);
  bfraw* WvT = (bfraw*)(ws + OFF_REGION);  // preamble only
  bfraw* scoreb = (bfraw*)(ws + OFF_REGION);
  bfraw* kv = (bfraw*)(ws + OFF_REGION);
  char* pool = ws + OFF_POOL;
  float* tf = (float*)(pool + P_TF);
  float* cval = (float*)(pool + P_TF);
  bfraw* tb = (bfraw*)(pool + P_TB);
  int* cidx = (int*)(pool + P_TB);
  bfraw* qbf = (bfraw*)(pool + P_QBF);
  bfraw* tmpb = (bfraw*)(pool + P_QBF);
  bfraw* ubuf = (bfraw*)(pool + P_UBUF);
  bfraw* ffb = (bfraw*)(pool + P_UBUF);
  bfraw* cfb = (bfraw*)(pool + P_UBUF);  // 51.2 MB, phase-1 only
  bfraw* cbuf = (bfraw*)(pool + P_CBUF);
  float* delta = (float*)(pool + P_CBUF);
  float* coarse = (float*)(pool + P_CBUF + 8388608);

  dim3 blk(256);

  // ---- preamble: conversions + SA fold ----
  k_cvt<<<2048, blk, 0, stream>>>(x, xb, 524288);
  k_cvt<<<25000, blk, 0, stream>>>(cf, cfb, 6400000);
  k_cvt<<<1536, blk, 0, stream>>>(sa_out_w, saout, 393216);
  k_cvt<<<1536, blk, 0, stream>>>(ca_out_w, caout, 393216);
  k_cvt<<<256, blk, 0, stream>>>(region_w, regw, 65536);
  k_cvt<<<6144, blk, 0, stream>>>(lin1_w, l1b, 1572864);
  k_cvt<<<6144, blk, 0, stream>>>(lin2_w, l2b, 1572864);
  k_cvt_s<<<1536, blk, 0, stream>>>(ca_in_w, cawq, 65536, 196608, 6);
  k_cvt_s<<<1536, blk, 0, stream>>>(ca_in_w + 1024 * 512, cawv, 65536, 196608, 6);
  k_prep<<<6144, blk, 0, stream>>>(ca_in_w, wkT);
  k_tr<<<dim3(16, 16, 6), blk, 0, stream>>>(sa_in_w, WvT);
  k_gemm<64, false, true, false, false, false><<<dim3(4, 8, 6), blk, 0, stream>>>(
      saout, 512, 262144, WvT, 512, 262144, nullptr, wsab, 512, 262144, nullptr, 0, 512, 512);
  k_bsa<<<6, blk, 0, stream>>>(sa_out_w, sa_in_b, sa_out_b, bsa);

  // ---- score GEMM (bf16 out, XCD-swizzled) + per-chunk top-64 ----
  for (int c = 0; c < NCHUNK; ++c) {
    k_gemm<128, false, true, false, false, true><<<dim3(1792, 1, 1), blk, 0, stream>>>(
        xb, 512, 0, cfb + (long)c * CHUNK * 512, 512, 0,
        nullptr, scoreb, CHUNK_LD, 0, nullptr, 0, CHUNK, 512);
    k_select<<<4096, blk, 0, stream>>>(scoreb, cval, cidx, c);
  }
  k_refine<<<4096, blk, 0, stream>>>(cval, cidx, x, cf, tidx, wsm);
  k_buildkv<<<4096, blk, 0, stream>>>(x, cfb, type_emb, pos_emb, wsm, tidx, kv);
  k_init_t<<<8192, blk, 0, stream>>>(cls, tf, tb);

  for (int i = 0; i < LAYERS; ++i) {
    const bfraw* ca_wq = cawq + (long)i * 262144;
    const float* ca_bq = ca_in_b + (long)i * 1536;
    const bfraw* ca_wv = cawv + (long)i * 262144;
    const float* ca_bv = ca_in_b + (long)i * 1536 + 1024;
    const bfraw* ca_wo = caout + (long)i * 262144;
    const float* ca_bo = ca_out_b + (long)i * 512;
    const bfraw* wkTi = wkT + (long)i * 8 * 512 * 64;

    // Self-attention folded: delta = t @ Wsa^T + bsa
    k_gemm<64, true, false, false, true, false><<<dim3(4, 64, 1), blk, 0, stream>>>(
        tb, 512, 0, wsab + (long)i * 262144, 512, 0, delta, nullptr, 512, 0, bsa + i * 512, 0, 512, 512);
    k_ln<<<1024, blk, 0, stream>>>(tf, tb, delta, ln1_g + i * 512, ln1_bp + i * 512);

    // Cross-attention (re-associated)
    k_gemm<64, false, true, false, true, false><<<dim3(4, 64, 1), blk, 0, stream>>>(
        tb, 512, 0, ca_wq, 512, 0, nullptr, qbf, 512, 0, ca_bq, 0, 512, 512);
    k_gemm<64, false, true, false, false, false><<<dim3(4, 64, 8), blk, 0, stream>>>(
        qbf, 512, 64, wkTi, 64, 32768, nullptr, ubuf, 4096, 512, nullptr, 0, 512, 64);
    k_attn<<<4096, blk, 0, stream>>>(ubuf, kv, cbuf);
    k_gemm<64, false, true, false, true, false><<<dim3(1, 64, 8), blk, 0, stream>>>(
        cbuf, 4096, 512, ca_wv, 512, 32768, nullptr, tmpb, 512, 64, ca_bv, 64, 64, 512);
    k_gemm<64, true, false, false, true, false><<<dim3(4, 64, 1), blk, 0, stream>>>(
        tmpb, 512, 0, ca_wo, 512, 0, delta, nullptr, 512, 0, ca_bo, 0, 512, 512);
    k_ln<<<1024, blk, 0, stream>>>(tf, tb, delta, ln2_g + i * 512, ln2_bp + i * 512);

    // FFN
    k_gemm<64, false, true, true, true, false><<<dim3(16, 64, 1), blk, 0, stream>>>(
        tb, 512, 0, l1b + (long)i * 1048576, 512, 0, nullptr, ffb, 2048, 0, lin1_b + i * 2048, 0, 2048, 512);
    k_gemm<64, true, false, false, true, false><<<dim3(4, 64, 1), blk, 0, stream>>>(
        ffb, 2048, 0, l2b + (long)i * 1048576, 2048, 0, delta, nullptr, 512, 0, lin2_b + i * 512, 0, 512, 2048);
    k_ln<<<1024, blk, 0, stream>>>(tf, tb, delta, ln3_g + i * 512, ln3_bp + i * 512);
  }

  k_gemm<64, true, false, false, true, false><<<dim3(4, 64, 1), blk, 0, stream>>>(
      xb, 512, 0, regw, 512, 0, coarse, nullptr, 512, 0, region_b, 0, 512, 512);
  k_final<<<4096, dim3(64), 0, stream>>>(tf, coarse, (float*)d_out);
}

// Round 6
// 2476.744 us; speedup vs baseline: 2.0806x; 1.1907x over previous
//
#include <hip/hip_runtime.h>
#include <cstdint>

typedef unsigned short bfraw;
typedef __attribute__((ext_vector_type(8))) short short8;
typedef __attribute__((ext_vector_type(4))) float f32x4;
typedef __attribute__((ext_vector_type(4))) unsigned int u32x4;

#define DEV static __device__ __forceinline__

constexpr int NCHUNK = 8;
constexpr int CHUNK = 6250;
constexpr int CHUNK_LD = 6272;
constexpr int LAYERS = 6;

DEV float b2f(bfraw s) { return __uint_as_float(((unsigned)s) << 16); }
DEV bfraw f2b(float f) {
  unsigned u = __float_as_uint(f);
  u += 0x7FFFu + ((u >> 16) & 1u);
  return (bfraw)(u >> 16);
}
DEV float keyinv16(unsigned k) {
  unsigned raw = (k & 0x8000u) ? (k ^ 0x8000u) : (~k & 0xFFFFu);
  return b2f((bfraw)raw);
}

// ---------------- fp32 -> bf16 conversion ----------------
__global__ __launch_bounds__(256) void k_cvt(const float* __restrict__ src,
                                             bfraw* __restrict__ dst, int n4) {
  int i = blockIdx.x * 256 + threadIdx.x;
  if (i < n4) {
    float4 v = ((const float4*)src)[i];
    ushort4 o;
    o.x = f2b(v.x); o.y = f2b(v.y); o.z = f2b(v.z); o.w = f2b(v.w);
    ((ushort4*)dst)[i] = o;
  }
}

// strided-chunk fp32 -> bf16 (gathers nch chunks of n4PerChunk float4s)
__global__ __launch_bounds__(256) void k_cvt_s(const float* __restrict__ src,
                                               bfraw* __restrict__ dst,
                                               int n4PerChunk, long srcStride4, int nch) {
  long i = (long)blockIdx.x * 256 + threadIdx.x;
  if (i < (long)n4PerChunk * nch) {
    int c = (int)(i / n4PerChunk);
    int j = (int)(i % n4PerChunk);
    float4 v = ((const float4*)src)[c * srcStride4 + j];
    ushort4 o;
    o.x = f2b(v.x); o.y = f2b(v.y); o.z = f2b(v.z); o.w = f2b(v.w);
    ((ushort4*)dst)[i] = o;
  }
}

// ---------------- transpose sa Wv slice: WvT[l][k][j] = sa_in_w[l,1024+j,k] ----------------
__global__ __launch_bounds__(256) void k_tr(const float* __restrict__ sa_in_w,
                                            bfraw* __restrict__ WvT) {
  __shared__ float tile[32][33];
  const int tx = threadIdx.x & 31, ty = threadIdx.x >> 5;  // 32 x 8
  const int j0 = blockIdx.y * 32, k0 = blockIdx.x * 32;
  const long l = blockIdx.z;
#pragma unroll
  for (int p = 0; p < 4; ++p)
    tile[ty + p * 8][tx] = sa_in_w[(l * 1536 + 1024 + j0 + ty + p * 8) * 512 + k0 + tx];
  __syncthreads();
#pragma unroll
  for (int p = 0; p < 4; ++p)
    WvT[l * 262144 + (long)(k0 + ty + p * 8) * 512 + j0 + tx] = f2b(tile[tx][ty + p * 8]);
}

// ---------------- bsa[l,m] = sum_j Wo[l,m,j]*bv[l,j] + bo[l,m] ----------------
__global__ __launch_bounds__(256) void k_bsa(const float* __restrict__ sa_out_w,
                                             const float* __restrict__ sa_in_b,
                                             const float* __restrict__ sa_out_b,
                                             float* __restrict__ bsa) {
  __shared__ float bv[512];
  const int t = threadIdx.x;
  const long l = blockIdx.x;
  bv[t] = sa_in_b[l * 1536 + 1024 + t];
  bv[t + 256] = sa_in_b[l * 1536 + 1024 + t + 256];
  __syncthreads();
#pragma unroll
  for (int h = 0; h < 2; ++h) {
    int m = t + h * 256;
    const float* wr = sa_out_w + (l * 512 + m) * 512;
    float s = 0.f;
    for (int q = 0; q < 128; ++q) {
      float4 v = ((const float4*)wr)[q];
      s += v.x * bv[q * 4] + v.y * bv[q * 4 + 1] + v.z * bv[q * 4 + 2] + v.w * bv[q * 4 + 3];
    }
    bsa[l * 512 + m] = s + sa_out_b[l * 512 + m];
  }
}

// ---------------- Generic bt-GEMM: C[M,N] = A[M,K] @ B[N,K]^T (+bias) ----------------
// TM=128: 4 waves 2x2, each 4x4 of 16x16x32 MFMA. TM=64: 4 waves 1x4, each 4x2.
// Staging via async global_load_lds width=16 (m97 structure): no VGPR round-trip,
// no ds_writes; compiler's pre-barrier vmcnt(0) drains the DMA. XOR swizzle is
// preserved by pre-swizzling the GLOBAL source address (kc = sCh^(fr&7)) while the
// LDS destination stays linear (thread t's dest t*16B == fr*128 + sCh*16 bytes).
// Epilogue stages output tile in LDS, streams out nt dwordx4.
template <int TM, bool OUTF32, bool OUTBF, bool RELU, bool BIAS, bool SWZ>
__global__ __launch_bounds__(256, 2) void k_gemm(
    const bfraw* __restrict__ A, int lda, long sA,
    const bfraw* __restrict__ B, int ldb, long sB,
    float* __restrict__ Cf, bfraw* __restrict__ Cb, int ldc, long sC,
    const float* __restrict__ bias, int sBias,
    int N, int K) {
  constexpr int WR = TM / 64;       // wave-row groups (2 or 1)
  constexpr int CW = 32 * WR;       // cols per wave (64 or 32)
  constexpr int JT = CW / 16;       // j tiles (4 or 2)
  constexpr int AP = TM / 32;       // A staging rounds (4 or 2)
  constexpr int STAGE_B = TM * 64 * 2 + 128 * 64 * 2;
  constexpr int EPP = OUTF32 ? 132 : 136;  // epilogue LDS pitch (elements)
  constexpr int EP_B = OUTF32 ? TM * 132 * 4 : TM * 136 * 2;
  constexpr int SMEM_B = STAGE_B > EP_B ? STAGE_B : EP_B;
  __shared__ __align__(16) char smem[SMEM_B];
  bfraw* lsA = (bfraw*)smem;
  bfraw* lsB = (bfraw*)(smem + TM * 64 * 2);
  const int t = threadIdx.x;
  const int lane = t & 63;
  const int wave = t >> 6;
  const int wr = (TM == 128) ? (wave & 1) : 0;
  const int wc = (TM == 128) ? (wave >> 1) : wave;
  int bx, by;
  if (SWZ) {
    int l = blockIdx.x;
    int xcd = l & 7;
    int s = l >> 3;
    by = s / 7;
    int bxi = s % 7;
    bx = bxi * 8 + xcd;
    if (bx * 128 >= N) return;
  } else {
    bx = blockIdx.x;
    by = blockIdx.y;
  }
  const int z = blockIdx.z;
  A += (long)z * sA;
  B += (long)z * sB;

  const int sRow = t >> 3;  // 0..31
  const int sCh = t & 7;
  const int rowA0 = by * TM;
  const int colB0 = bx * 128;

  f32x4 acc[4][JT];
#pragma unroll
  for (int i = 0; i < 4; ++i)
#pragma unroll
    for (int j = 0; j < JT; ++j) {
      acc[i][j][0] = 0.f; acc[i][j][1] = 0.f; acc[i][j][2] = 0.f; acc[i][j][3] = 0.f;
    }

  const int nk = K >> 6;
  // Per-thread swizzled global source bases (element offsets), LDS dests linear.
  // A round p: fr = p*32 + sRow, kc = sCh ^ (fr&7); LDS dest = lsA + p*4096B + wave*1024B.
  const bfraw* aSrc[AP];
#pragma unroll
  for (int p = 0; p < AP; ++p) {
    int fr = p * 32 + sRow;
    int kc = sCh ^ (fr & 7);
    aSrc[p] = A + (long)(rowA0 + fr) * lda + kc * 8;
  }
  const bfraw* bSrc[4];
#pragma unroll
  for (int p = 0; p < 4; ++p) {
    int fr = p * 32 + sRow;
    int kc = sCh ^ (fr & 7);
    int rB = colB0 + fr;
    if (rB >= N) rB = N - 1;  // clamp; polluted cols masked at store
    bSrc[p] = B + (long)rB * ldb + kc * 8;
  }

  for (int kt = 0; kt < nk; ++kt) {
    __syncthreads();  // previous tile fully consumed by all waves
#pragma unroll
    for (int p = 0; p < AP; ++p)
      __builtin_amdgcn_global_load_lds(
          (const unsigned int*)(aSrc[p] + kt * 64),
          (unsigned int*)(smem + p * 4096 + wave * 1024), 16, 0, 0);
#pragma unroll
    for (int p = 0; p < 4; ++p)
      __builtin_amdgcn_global_load_lds(
          (const unsigned int*)(bSrc[p] + kt * 64),
          (unsigned int*)(smem + TM * 128 + p * 4096 + wave * 1024), 16, 0, 0);
    __syncthreads();  // compiler emits s_waitcnt vmcnt(0) before s_barrier -> LDS ready
#pragma unroll
    for (int ks = 0; ks < 2; ++ks) {
      short8 af[4], bfm[JT];
#pragma unroll
      for (int i = 0; i < 4; ++i) {
        int r = wr * 64 + i * 16 + (lane & 15);
        int q = ks * 4 + (lane >> 4);
        af[i] = *(const short8*)(lsA + r * 64 + ((q ^ (r & 7)) * 8));
      }
#pragma unroll
      for (int j = 0; j < JT; ++j) {
        int n = wc * CW + j * 16 + (lane & 15);
        int q = ks * 4 + (lane >> 4);
        bfm[j] = *(const short8*)(lsB + n * 64 + ((q ^ (n & 7)) * 8));
      }
#pragma unroll
      for (int i = 0; i < 4; ++i)
#pragma unroll
        for (int j = 0; j < JT; ++j)
          acc[i][j] = __builtin_amdgcn_mfma_f32_16x16x32_bf16(af[i], bfm[j], acc[i][j], 0, 0, 0);
    }
  }

  // ---- epilogue: stage tile in LDS, stream out with nt dwordx4 ----
  __syncthreads();  // all waves done reading lsA/lsB before we alias over them
  const int Nrem = N - colB0;  // valid cols in this tile (may exceed 128)
  if (OUTBF) {
    unsigned short* ep = (unsigned short*)smem;
#pragma unroll
    for (int j = 0; j < JT; ++j) {
      int cl = wc * CW + j * 16 + (lane & 15);
      int n = colB0 + cl;
      float bv = 0.f;
      if (BIAS) bv = (n < N) ? bias[(long)z * sBias + n] : 0.f;
#pragma unroll
      for (int i = 0; i < 4; ++i) {
        int r0 = wr * 64 + i * 16 + ((lane >> 4) << 2);
#pragma unroll
        for (int r = 0; r < 4; ++r) {
          float v = acc[i][j][r] + bv;
          if (RELU) v = fmaxf(v, 0.f);
          ep[(r0 + r) * EPP + cl] = f2b(v);
        }
      }
    }
    __syncthreads();
#pragma unroll
    for (int pass = 0; pass < TM / 16; ++pass) {
      int row = pass * 16 + (t >> 4);
      int c0 = (t & 15) * 8;
      long base = (long)(rowA0 + row) * ldc + (long)z * sC + colB0;
      if (c0 + 8 <= Nrem) {
        u32x4 v = *(const u32x4*)(ep + row * EPP + c0);
        __builtin_nontemporal_store(v, (u32x4*)(Cb + base + c0));
      } else if (c0 < Nrem) {
        for (int q = c0; q < Nrem && q < 128; ++q) Cb[base + q] = (bfraw)ep[row * EPP + q];
      }
    }
  }
  if (OUTF32) {
    float* ep = (float*)smem;
#pragma unroll
    for (int j = 0; j < JT; ++j) {
      int cl = wc * CW + j * 16 + (lane & 15);
      int n = colB0 + cl;
      float bv = 0.f;
      if (BIAS) bv = (n < N) ? bias[(long)z * sBias + n] : 0.f;
#pragma unroll
      for (int i = 0; i < 4; ++i) {
        int r0 = wr * 64 + i * 16 + ((lane >> 4) << 2);
#pragma unroll
        for (int r = 0; r < 4; ++r) {
          float v = acc[i][j][r] + bv;
          if (RELU) v = fmaxf(v, 0.f);
          ep[(r0 + r) * EPP + cl] = v;
        }
      }
    }
    __syncthreads();
#pragma unroll
    for (int pass = 0; pass < TM / 8; ++pass) {
      int row = pass * 8 + (t >> 5);
      int c0 = (t & 31) * 4;
      long base = (long)(rowA0 + row) * ldc + (long)z * sC + colB0;
      if (c0 + 4 <= Nrem) {
        f32x4 v = *(const f32x4*)(ep + row * EPP + c0);
        __builtin_nontemporal_store(v, (f32x4*)(Cf + base + c0));
      } else if (c0 < Nrem) {
        for (int q = c0; q < Nrem && q < 128; ++q) Cf[base + q] = ep[row * EPP + q];
      }
    }
  }
}

// ---------------- per-row top-64 of one bf16 score chunk (2-level radix select) ----------------
__global__ __launch_bounds__(256) void k_select(const bfraw* __restrict__ scores,
                                                float* __restrict__ cval, int* __restrict__ cidx,
                                                int chunk) {
  __shared__ unsigned short keys[CHUNK];
  __shared__ unsigned hist[256];
  __shared__ unsigned sh_sel, sh_rank, cnt_a, cnt_t;
  __shared__ unsigned tiebuf[64];
  const int t = threadIdx.x;
  const long b = blockIdx.x;
  const bfraw* row = scores + b * CHUNK_LD;
  for (int i = t; i < CHUNK; i += 256) {
    unsigned u = row[i];
    keys[i] = (u & 0x8000u) ? (unsigned short)(~u) : (unsigned short)(u | 0x8000u);
  }
  if (t == 0) { cnt_a = 0; cnt_t = 0; }
  unsigned prefix = 0, pmask = 0, rank = 64;
  for (int lev = 0; lev < 2; ++lev) {
    const int sh = 8 - lev * 8;
    hist[t] = 0;
    __syncthreads();
    for (int i = t; i < CHUNK; i += 256) {
      unsigned k = keys[i];
      if ((k & pmask) == prefix) atomicAdd(&hist[(k >> sh) & 255u], 1u);
    }
    __syncthreads();
    if (t < 64) {  // wave0: suffix-scan buckets, find bucket containing rank
      unsigned h0 = hist[t * 4], h1 = hist[t * 4 + 1], h2 = hist[t * 4 + 2], h3 = hist[t * 4 + 3];
      unsigned lsum = h0 + h1 + h2 + h3;
      unsigned suf = lsum;
#pragma unroll
      for (int off = 1; off < 64; off <<= 1) {
        unsigned vv = __shfl_down(suf, off);
        if (t + off < 64) suf += vv;
      }
      unsigned c = suf - lsum;
      unsigned hs[4] = {h0, h1, h2, h3};
#pragma unroll
      for (int q = 3; q >= 0; --q) {
        if (rank > c && rank <= c + hs[q]) { sh_sel = (unsigned)(t * 4 + q); sh_rank = rank - c; }
        c += hs[q];
      }
    }
    __syncthreads();
    prefix |= sh_sel << sh;
    pmask |= 255u << sh;
    rank = sh_rank;
    __syncthreads();
  }
  const unsigned cutkey = prefix;
  float* ov = cval + (b * NCHUNK + chunk) * 64;
  int* oi = cidx + (b * NCHUNK + chunk) * 64;
  for (int i = t; i < CHUNK; i += 256) {
    unsigned k = keys[i];
    if (k > cutkey) {
      unsigned p = atomicAdd(&cnt_a, 1u);
      ov[p] = keyinv16(k);
      oi[p] = chunk * CHUNK + i;
    } else if (k == cutkey) {
      unsigned p = atomicAdd(&cnt_t, 1u);
      if (p < 64) tiebuf[p] = (unsigned)i;
    }
  }
  __syncthreads();
  if (t == 0) {  // fill remaining slots from ties (lowest index first)
    int need = (int)rank;
    int tc = cnt_t < 64u ? (int)cnt_t : 64;
    int base = (int)cnt_a;
    float cv = keyinv16(cutkey);
    for (int s2 = 0; s2 < need; ++s2) {
      unsigned best = 0xFFFFFFFFu; int bq = 0;
      for (int q2 = 0; q2 < tc; ++q2)
        if (tiebuf[q2] < best) { best = tiebuf[q2]; bq = q2; }
      tiebuf[bq] = 0xFFFFFFFFu;
      ov[base + s2] = cv;
      oi[base + s2] = chunk * CHUNK + (int)best;
    }
  }
}

// ---------------- Refine: sort 512 cands, exact fp32 rescore top-64, top-32 + softmax ----------------
__global__ __launch_bounds__(256) void k_refine(const float* __restrict__ cval,
                                                const int* __restrict__ cidx,
                                                const float* __restrict__ x,
                                                const float* __restrict__ cf,
                                                int* __restrict__ tidx, float* __restrict__ w) {
  __shared__ float sv[512];
  __shared__ int si[512];
  __shared__ float xs[512];
  __shared__ float rv[64];
  __shared__ int ri[64];
  const int t = threadIdx.x;
  const long b = blockIdx.x;
  sv[t] = cval[b * 512 + t]; sv[t + 256] = cval[b * 512 + t + 256];
  si[t] = cidx[b * 512 + t]; si[t + 256] = cidx[b * 512 + t + 256];
  xs[t] = x[b * 512 + t]; xs[t + 256] = x[b * 512 + t + 256];
  __syncthreads();
  for (int k = 2; k <= 512; k <<= 1)
    for (int j = k >> 1; j >= 1; j >>= 1) {
      int i = ((t & ~(j - 1)) << 1) | (t & (j - 1));
      int p = i | j;
      bool dir = ((i & k) == 0);
      float va = sv[i], vb = sv[p];
      int ia = si[i], ib = si[p];
      bool pBetter = (vb > va) || (vb == va && ib < ia);
      if (pBetter == dir) { sv[i] = vb; sv[p] = va; si[i] = ib; si[p] = ia; }
      __syncthreads();
    }
  const int c = t >> 2, sub = t & 3;
  const int idx = si[c];
  const float* cr = cf + (long)idx * 512 + sub * 128;
  float s = 0.f;
#pragma unroll 8
  for (int q = 0; q < 32; ++q) {
    float4 vv = ((const float4*)cr)[q];
    const float* xr = xs + sub * 128 + q * 4;
    s += vv.x * xr[0] + vv.y * xr[1] + vv.z * xr[2] + vv.w * xr[3];
  }
  s += __shfl_xor(s, 1);
  s += __shfl_xor(s, 2);
  if (sub == 0) { rv[c] = s; ri[c] = idx; }
  __syncthreads();
  if (t < 64) {
    float v = rv[t];
    int ix = ri[t];
    for (int k = 2; k <= 64; k <<= 1)
      for (int j = k >> 1; j >= 1; j >>= 1) {
        float ov = __shfl_xor(v, j);
        int oi = __shfl_xor(ix, j);
        bool up = ((t & k) == 0);
        bool low = ((t & j) == 0);
        bool oBetter = (ov > v) || (ov == v && oi < ix);
        if (oBetter == (up == low)) { v = ov; ix = oi; }
      }
    float m = __shfl(v, 0);
    float e = (t < 32) ? __expf(v - m) : 0.f;
    float ssum = e;
#pragma unroll
    for (int off = 1; off < 64; off <<= 1) ssum += __shfl_xor(ssum, off);
    if (t < 32) {
      w[b * 32 + t] = e / ssum;
      tidx[b * 32 + t] = ix;
    }
  }
}

// ---------------- Build kv (B,33,512) bf16 ----------------
__global__ __launch_bounds__(256) void k_buildkv(const float* __restrict__ x, const bfraw* __restrict__ cfb,
                                                 const float* __restrict__ type_emb,
                                                 const float* __restrict__ pos_emb,
                                                 const float* __restrict__ w, const int* __restrict__ tidx,
                                                 bfraw* __restrict__ kv) {
  const int t = threadIdx.x;
  const long b = blockIdx.x;
  bfraw* out = kv + b * (33 * 512);
  const float* xr = x + b * 512;
  for (int d = t; d < 512; d += 256) out[d] = f2b(xr[d] + type_emb[d]);
  for (int j = 0; j < 32; ++j) {
    const long ci = tidx[b * 32 + j];
    const float wj = w[b * 32 + j];
    const bfraw* cr = cfb + ci * 512;
    bfraw* o = out + (j + 1) * 512;
    for (int d = t; d < 512; d += 256)
      o[d] = f2b(wj * b2f(cr[d]) + pos_emb[j * 512 + d] + type_emb[512 + d]);
  }
}

// ---------------- t init ----------------
__global__ __launch_bounds__(256) void k_init_t(const float* __restrict__ cls, float* __restrict__ tf,
                                                bfraw* __restrict__ tb) {
  const long i = (long)blockIdx.x * 256 + threadIdx.x;
  const int d = (int)(i & 511);
  tf[i] = cls[d];
  tb[i] = f2b(cls[d]);
}

// ---------------- wkT prep: wkT[i,h,d,e] = ca_in_w[i, 512 + h*64 + e, d] ----------------
__global__ __launch_bounds__(256) void k_prep(const float* __restrict__ ca_in_w, bfraw* __restrict__ wkT) {
  const long o = (long)blockIdx.x * 256 + threadIdx.x;
  const int e = (int)(o & 63);
  long r = o >> 6;
  const int d = (int)(r & 511); r >>= 9;
  const int h = (int)(r & 7);
  const int i = (int)(r >> 3);
  wkT[o] = f2b(ca_in_w[((long)i * 1536 + 512 + h * 64 + e) * 512 + d]);
}

// ---------------- CA attention core: MFMA QK^T + scalar PV ----------------
// S[h,j] = u[h,:]*kv[j,:] as 16x16x32 MFMA (waves 0,1 take j-tiles 0/1; j=32 scalar
// on wave 2). kv/us staged via global_load_lds with k_gemm's XOR-chunk swizzle
// (linear LDS dest, pre-swizzled global src). Softmax + PV unchanged in structure.
__global__ __launch_bounds__(256) void k_attn(const bfraw* __restrict__ u, const bfraw* __restrict__ kv,
                                              bfraw* __restrict__ cout) {
  __shared__ __align__(16) bfraw kvs[33 * 512];
  __shared__ __align__(16) bfraw us[8 * 512];
  __shared__ float ps[8 * 48];
  const int t = threadIdx.x, lane = t & 63, wave = t >> 6;
  const long b = blockIdx.x;
  const bfraw* kvg = kv + b * (33 * 512);
  const bfraw* ug = u + b * (8 * 512);

  // stage: logical chunk c (0..63) of row r lives at LDS chunk c; global source is
  // chunk (c&56)|((c&7)^(r&7)) so that swizzled READS return logical data.
  {
#pragma unroll
    for (int r = 0; r < 8; ++r) {
      int row = r * 4 + wave;  // wave-uniform
      int sc = (lane & 56) | ((lane & 7) ^ (row & 7));
      __builtin_amdgcn_global_load_lds((const unsigned int*)(kvg + row * 512 + sc * 8),
                                       (unsigned int*)(kvs + row * 512), 16, 0, 0);
    }
    if (wave == 0)
      __builtin_amdgcn_global_load_lds((const unsigned int*)(kvg + 32 * 512 + lane * 8),
                                       (unsigned int*)(kvs + 32 * 512), 16, 0, 0);
#pragma unroll
    for (int r = 0; r < 2; ++r) {
      int row = r * 4 + wave;
      int sc = (lane & 56) | ((lane & 7) ^ (row & 7));
      __builtin_amdgcn_global_load_lds((const unsigned int*)(ug + row * 512 + sc * 8),
                                       (unsigned int*)(us + row * 512), 16, 0, 0);
    }
  }
  __syncthreads();

  // ---- QK^T ----
  if (wave < 2) {
    const int jj = wave * 16 + (lane & 15);  // B row (j), all valid (0..31)
    const int rr = lane & 7;                 // A row: duplicate heads into rows 8..15
    f32x4 acc = {0.f, 0.f, 0.f, 0.f};
#pragma unroll
    for (int ks = 0; ks < 16; ++ks) {
      int q = ks * 4 + (lane >> 4);  // logical chunk 0..63
      short8 af = *(const short8*)(us + rr * 512 + (((q & 56) | ((q & 7) ^ rr)) * 8));
      short8 bf = *(const short8*)(kvs + jj * 512 + (((q & 56) | ((q & 7) ^ (jj & 7))) * 8));
      acc = __builtin_amdgcn_mfma_f32_16x16x32_bf16(af, bf, acc, 0, 0, 0);
    }
#pragma unroll
    for (int r = 0; r < 4; ++r) {
      int row = (lane >> 4) * 4 + r;
      if (row < 8) ps[row * 48 + wave * 16 + (lane & 15)] = acc[r] * 0.125f;
    }
  } else if (wave == 2) {
    // j = 32 column: scalar dot, 8 lanes per head
    int h = lane >> 3, seg = lane & 7;
    float s = 0.f;
#pragma unroll
    for (int i = 0; i < 8; ++i) {
      int c = seg * 8 + i;
      short8 kk = *(const short8*)(kvs + 32 * 512 + c * 8);  // row 32: r&7==0, unswizzled
      short8 uu = *(const short8*)(us + h * 512 + (((c & 56) | ((c & 7) ^ h)) * 8));
#pragma unroll
      for (int e = 0; e < 8; ++e) s += b2f((bfraw)uu[e]) * b2f((bfraw)kk[e]);
    }
    s += __shfl_xor(s, 1);
    s += __shfl_xor(s, 2);
    s += __shfl_xor(s, 4);
    if (seg == 0) ps[h * 48 + 32] = s * 0.125f;
  }
  __syncthreads();

  // ---- softmax (2 heads per wave) ----
#pragma unroll
  for (int hh = 0; hh < 2; ++hh) {
    int h = wave + hh * 4;
    float sv2 = (lane < 33) ? ps[h * 48 + lane] : -3.0e38f;
    float m = sv2;
#pragma unroll
    for (int off = 1; off < 64; off <<= 1) m = fmaxf(m, __shfl_xor(m, off));
    float e = (lane < 33) ? __expf(sv2 - m) : 0.f;
    float s = e;
#pragma unroll
    for (int off = 1; off < 64; off <<= 1) s += __shfl_xor(s, off);
    if (lane < 33) ps[h * 48 + lane] = e / s;
  }
  __syncthreads();

  // ---- PV (scalar, swizzle-aware) ----
#pragma unroll
  for (int hh = 0; hh < 2; ++hh) {
    int h = wave + hh * 4;
    float acc[8] = {0.f, 0.f, 0.f, 0.f, 0.f, 0.f, 0.f, 0.f};
    for (int j = 0; j < 33; ++j) {
      float pj = ps[h * 48 + j];
      int c = (lane & 56) | ((lane & 7) ^ (j & 7));
      short8 kk = *(const short8*)(kvs + j * 512 + c * 8);
#pragma unroll
      for (int q = 0; q < 8; ++q) acc[q] += pj * b2f((bfraw)kk[q]);
    }
    union { bfraw o[8]; uint4 v4; } pk;
#pragma unroll
    for (int q = 0; q < 8; ++q) pk.o[q] = f2b(acc[q]);
    *(uint4*)(cout + (b * 8 + h) * 512 + lane * 8) = pk.v4;
  }
}

// ---------------- residual + LayerNorm ----------------
__global__ __launch_bounds__(256) void k_ln(float* __restrict__ tf, bfraw* __restrict__ tb,
                                            const float* __restrict__ delta,
                                            const float* __restrict__ g, const float* __restrict__ be) {
  const int lane = threadIdx.x & 63, wave = threadIdx.x >> 6;
  const long row = (long)blockIdx.x * 4 + wave;
  float* tr = tf + row * 512;
  const float* dr = delta + row * 512;
  float v[8];
  float4 a0 = *(const float4*)(tr + lane * 8);
  float4 a1 = *(const float4*)(tr + lane * 8 + 4);
  float4 d0 = *(const float4*)(dr + lane * 8);
  float4 d1 = *(const float4*)(dr + lane * 8 + 4);
  v[0] = a0.x + d0.x; v[1] = a0.y + d0.y; v[2] = a0.z + d0.z; v[3] = a0.w + d0.w;
  v[4] = a1.x + d1.x; v[5] = a1.y + d1.y; v[6] = a1.z + d1.z; v[7] = a1.w + d1.w;
  float s = 0.f;
#pragma unroll
  for (int q = 0; q < 8; ++q) s += v[q];
#pragma unroll
  for (int off = 1; off < 64; off <<= 1) s += __shfl_xor(s, off);
  const float mean = s * (1.f / 512.f);
  float sq = 0.f;
#pragma unroll
  for (int q = 0; q < 8; ++q) { float d = v[q] - mean; sq += d * d; }
#pragma unroll
  for (int off = 1; off < 64; off <<= 1) sq += __shfl_xor(sq, off);
  const float rs = 1.f / sqrtf(sq * (1.f / 512.f) + 1e-5f);
  float4 g0 = *(const float4*)(g + lane * 8);
  float4 g1 = *(const float4*)(g + lane * 8 + 4);
  float4 b0 = *(const float4*)(be + lane * 8);
  float4 b1 = *(const float4*)(be + lane * 8 + 4);
  float gg[8] = {g0.x, g0.y, g0.z, g0.w, g1.x, g1.y, g1.z, g1.w};
  float bb[8] = {b0.x, b0.y, b0.z, b0.w, b1.x, b1.y, b1.z, b1.w};
  float o[8];
  union { bfraw u16[8]; uint4 u4; } pk;
#pragma unroll
  for (int q = 0; q < 8; ++q) {
    o[q] = (v[q] - mean) * rs * gg[q] + bb[q];
    pk.u16[q] = f2b(o[q]);
  }
  *(float4*)(tr + lane * 8) = make_float4(o[0], o[1], o[2], o[3]);
  *(float4*)(tr + lane * 8 + 4) = make_float4(o[4], o[5], o[6], o[7]);
  *(uint4*)(tb + row * 512 + lane * 8) = pk.u4;
}

// ---------------- final triple-normalize ----------------
__global__ __launch_bounds__(64) void k_final(const float* __restrict__ tf, const float* __restrict__ coarse,
                                              float* __restrict__ out) {
  const int lane = threadIdx.x;
  const long b = blockIdx.x;
  const float* fr = tf + b * 512;
  const float* cr = coarse + b * 512;
  float4 f0 = *(const float4*)(fr + lane * 8);
  float4 f1 = *(const float4*)(fr + lane * 8 + 4);
  float4 c0 = *(const float4*)(cr + lane * 8);
  float4 c1 = *(const float4*)(cr + lane * 8 + 4);
  float f[8] = {f0.x, f0.y, f0.z, f0.w, f1.x, f1.y, f1.z, f1.w};
  float c[8] = {c0.x, c0.y, c0.z, c0.w, c1.x, c1.y, c1.z, c1.w};
  float sf = 0.f, sc = 0.f;
#pragma unroll
  for (int q = 0; q < 8; ++q) { sf += f[q] * f[q]; sc += c[q] * c[q]; }
#pragma unroll
  for (int off = 1; off < 64; off <<= 1) { sf += __shfl_xor(sf, off); sc += __shfl_xor(sc, off); }
  const float rf = 1.f / sqrtf(sf), rc = 1.f / sqrtf(sc);
  float a[8];
  float sa = 0.f;
#pragma unroll
  for (int q = 0; q < 8; ++q) { a[q] = f[q] * rf + c[q] * rc; sa += a[q] * a[q]; }
#pragma unroll
  for (int off = 1; off < 64; off <<= 1) sa += __shfl_xor(sa, off);
  const float ra = 1.f / sqrtf(sa);
  *(float4*)(out + b * 512 + lane * 8) = make_float4(a[0] * ra, a[1] * ra, a[2] * ra, a[3] * ra);
  *(float4*)(out + b * 512 + lane * 8 + 4) = make_float4(a[4] * ra, a[5] * ra, a[6] * ra, a[7] * ra);
}

// ---------------- workspace layout (bytes) ----------------
constexpr long OFF_XB = 0;                    //  4,194,304
constexpr long OFF_WKT = 4194304;             //  3,145,728
constexpr long OFF_SAOUT = 7340032;           //  3,145,728 (Wo bf16)
constexpr long OFF_WSAB = 10485760;           //  3,145,728 (Wsa bf16)
constexpr long OFF_CAWQ = 13631488;           //  3,145,728
constexpr long OFF_CAWV = 16777216;           //  3,145,728
constexpr long OFF_CAOUT = 19922944;          //  3,145,728
constexpr long OFF_REGW = 23068672;           //    524,288
constexpr long OFF_L1B = 23592960;            // 12,582,912 (all layers)
constexpr long OFF_L2B = 36175872;            // 12,582,912
constexpr long OFF_BSA = 48758784;            //     16,384
constexpr long OFF_TIDX = 48775168;           //    524,288
constexpr long OFF_WSM = 49299456;            //    524,288
constexpr long OFF_REGION = 49823744;         // 138,412,032 (WvT preamble / score bf16 / kv)
constexpr long OFF_POOL = 188235776;          // 83,886,080
constexpr long P_TF = 0;                      // 8,388,608 fp32 (phase1: cval)
constexpr long P_TB = 8388608;                // 4,194,304 bf16 (phase1: cidx lo)
constexpr long P_QBF = 12582912;              // 4,194,304 bf16 (phase1: cidx hi)
constexpr long P_UBUF = 16777216;             // 33,554,432 (phase1: cfb 51.2MB spans UBUF+part CBUF)
constexpr long P_CBUF = 50331648;             // 33,554,432 (delta +0, coarse +8,388,608)
constexpr long WS_TOTAL = OFF_POOL + 83886080;  // 272,121,856

extern "C" void kernel_launch(void* const* d_in, const int* in_sizes, int n_in,
                              void* d_out, int out_size, void* d_ws, size_t ws_size,
                              hipStream_t stream) {
  if (n_in < 25) return;
  if (ws_size < (size_t)WS_TOTAL) return;

  const float* x = (const float*)d_in[0];
  const float* cf = (const float*)d_in[1];
  const float* type_emb = (const float*)d_in[2];
  const float* pos_emb = (const float*)d_in[3];
  const float* cls = (const float*)d_in[4];
  const float* sa_in_w = (const float*)d_in[5];
  const float* sa_in_b = (const float*)d_in[6];
  const float* sa_out_w = (const float*)d_in[7];
  const float* sa_out_b = (const float*)d_in[8];
  const float* ca_in_w = (const float*)d_in[9];
  const float* ca_in_b = (const float*)d_in[10];
  const float* ca_out_w = (const float*)d_in[11];
  const float* ca_out_b = (const float*)d_in[12];
  const float* lin1_w = (const float*)d_in[13];
  const float* lin1_b = (const float*)d_in[14];
  const float* lin2_w = (const float*)d_in[15];
  const float* lin2_b = (const float*)d_in[16];
  const float* ln1_g = (const float*)d_in[17];
  const float* ln1_bp = (const float*)d_in[18];
  const float* ln2_g = (const float*)d_in[19];
  const float* ln2_bp = (const float*)d_in[20];
  const float* ln3_g = (const float*)d_in[21];
  const float* ln3_bp = (const float*)d_in[22];
  const float* region_w = (const float*)d_in[23];
  const float* region_b = (const float*)d_in[24];

  char* ws = (char*)d_ws;
  bfraw* xb = (bfraw*)(ws + OFF_XB);
  bfraw* wkT = (bfraw*)(ws + OFF_WKT);
  bfraw* saout = (bfraw*)(ws + OFF_SAOUT);
  bfraw* wsab = (bfraw*)(ws + OFF_WSAB);
  bfraw* cawq = (bfraw*)(ws + OFF_CAWQ);
  bfraw* cawv = (bfraw*)(ws + OFF_CAWV);
  bfraw* caout = (bfraw*)(ws + OFF_CAOUT);
  bfraw* regw = (bfraw*)(ws + OFF_REGW);
  bfraw* l1b = (bfraw*)(ws + OFF_L1B);
  bfraw* l2b = (bfraw*)(ws + OFF_L2B);
  float* bsa = (float*)(ws + OFF_BSA);
  int* tidx = (int*)(ws + OFF_TIDX);
  float* wsm = (float*)(ws + OFF_WSM);
  bfraw* WvT = (bfraw*)(ws + OFF_REGION);  // preamble only
  bfraw* scoreb = (bfraw*)(ws + OFF_REGION);
  bfraw* kv = (bfraw*)(ws + OFF_REGION);
  char* pool = ws + OFF_POOL;
  float* tf = (float*)(pool + P_TF);
  float* cval = (float*)(pool + P_TF);
  bfraw* tb = (bfraw*)(pool + P_TB);
  int* cidx = (int*)(pool + P_TB);
  bfraw* qbf = (bfraw*)(pool + P_QBF);
  bfraw* tmpb = (bfraw*)(pool + P_QBF);
  bfraw* ubuf = (bfraw*)(pool + P_UBUF);
  bfraw* ffb = (bfraw*)(pool + P_UBUF);
  bfraw* cfb = (bfraw*)(pool + P_UBUF);  // 51.2 MB, phase-1 only
  bfraw* cbuf = (bfraw*)(pool + P_CBUF);
  float* delta = (float*)(pool + P_CBUF);
  float* coarse = (float*)(pool + P_CBUF + 8388608);

  dim3 blk(256);

  // ---- preamble: conversions + SA fold ----
  k_cvt<<<2048, blk, 0, stream>>>(x, xb, 524288);
  k_cvt<<<25000, blk, 0, stream>>>(cf, cfb, 6400000);
  k_cvt<<<1536, blk, 0, stream>>>(sa_out_w, saout, 393216);
  k_cvt<<<1536, blk, 0, stream>>>(ca_out_w, caout, 393216);
  k_cvt<<<256, blk, 0, stream>>>(region_w, regw, 65536);
  k_cvt<<<6144, blk, 0, stream>>>(lin1_w, l1b, 1572864);
  k_cvt<<<6144, blk, 0, stream>>>(lin2_w, l2b, 1572864);
  k_cvt_s<<<1536, blk, 0, stream>>>(ca_in_w, cawq, 65536, 196608, 6);
  k_cvt_s<<<1536, blk, 0, stream>>>(ca_in_w + 1024 * 512, cawv, 65536, 196608, 6);
  k_prep<<<6144, blk, 0, stream>>>(ca_in_w, wkT);
  k_tr<<<dim3(16, 16, 6), blk, 0, stream>>>(sa_in_w, WvT);
  k_gemm<64, false, true, false, false, false><<<dim3(4, 8, 6), blk, 0, stream>>>(
      saout, 512, 262144, WvT, 512, 262144, nullptr, wsab, 512, 262144, nullptr, 0, 512, 512);
  k_bsa<<<6, blk, 0, stream>>>(sa_out_w, sa_in_b, sa_out_b, bsa);

  // ---- score GEMM (bf16 out, XCD-swizzled) + per-chunk top-64 ----
  for (int c = 0; c < NCHUNK; ++c) {
    k_gemm<128, false, true, false, false, true><<<dim3(1792, 1, 1), blk, 0, stream>>>(
        xb, 512, 0, cfb + (long)c * CHUNK * 512, 512, 0,
        nullptr, scoreb, CHUNK_LD, 0, nullptr, 0, CHUNK, 512);
    k_select<<<4096, blk, 0, stream>>>(scoreb, cval, cidx, c);
  }
  k_refine<<<4096, blk, 0, stream>>>(cval, cidx, x, cf, tidx, wsm);
  k_buildkv<<<4096, blk, 0, stream>>>(x, cfb, type_emb, pos_emb, wsm, tidx, kv);
  k_init_t<<<8192, blk, 0, stream>>>(cls, tf, tb);

  for (int i = 0; i < LAYERS; ++i) {
    const bfraw* ca_wq = cawq + (long)i * 262144;
    const float* ca_bq = ca_in_b + (long)i * 1536;
    const bfraw* ca_wv = cawv + (long)i * 262144;
    const float* ca_bv = ca_in_b + (long)i * 1536 + 1024;
    const bfraw* ca_wo = caout + (long)i * 262144;
    const float* ca_bo = ca_out_b + (long)i * 512;
    const bfraw* wkTi = wkT + (long)i * 8 * 512 * 64;

    // Self-attention folded: delta = t @ Wsa^T + bsa
    k_gemm<64, true, false, false, true, false><<<dim3(4, 64, 1), blk, 0, stream>>>(
        tb, 512, 0, wsab + (long)i * 262144, 512, 0, delta, nullptr, 512, 0, bsa + i * 512, 0, 512, 512);
    k_ln<<<1024, blk, 0, stream>>>(tf, tb, delta, ln1_g + i * 512, ln1_bp + i * 512);

    // Cross-attention (re-associated)
    k_gemm<64, false, true, false, true, false><<<dim3(4, 64, 1), blk, 0, stream>>>(
        tb, 512, 0, ca_wq, 512, 0, nullptr, qbf, 512, 0, ca_bq, 0, 512, 512);
    k_gemm<64, false, true, false, false, false><<<dim3(4, 64, 8), blk, 0, stream>>>(
        qbf, 512, 64, wkTi, 64, 32768, nullptr, ubuf, 4096, 512, nullptr, 0, 512, 64);
    k_attn<<<4096, blk, 0, stream>>>(ubuf, kv, cbuf);
    k_gemm<64, false, true, false, true, false><<<dim3(1, 64, 8), blk, 0, stream>>>(
        cbuf, 4096, 512, ca_wv, 512, 32768, nullptr, tmpb, 512, 64, ca_bv, 64, 64, 512);
    k_gemm<64, true, false, false, true, false><<<dim3(4, 64, 1), blk, 0, stream>>>(
        tmpb, 512, 0, ca_wo, 512, 0, delta, nullptr, 512, 0, ca_bo, 0, 512, 512);
    k_ln<<<1024, blk, 0, stream>>>(tf, tb, delta, ln2_g + i * 512, ln2_bp + i * 512);

    // FFN
    k_gemm<64, false, true, true, true, false><<<dim3(16, 64, 1), blk, 0, stream>>>(
        tb, 512, 0, l1b + (long)i * 1048576, 512, 0, nullptr, ffb, 2048, 0, lin1_b + i * 2048, 0, 2048, 512);
    k_gemm<64, true, false, false, true, false><<<dim3(4, 64, 1), blk, 0, stream>>>(
        ffb, 2048, 0, l2b + (long)i * 1048576, 2048, 0, delta, nullptr, 512, 0, lin2_b + i * 512, 0, 512, 2048);
    k_ln<<<1024, blk, 0, stream>>>(tf, tb, delta, ln3_g + i * 512, ln3_bp + i * 512);
  }

  k_gemm<64, true, false, false, true, false><<<dim3(4, 64, 1), blk, 0, stream>>>(
      xb, 512, 0, regw, 512, 0, coarse, nullptr, 512, 0, region_b, 0, 512, 512);
  k_final<<<4096, dim3(64), 0, stream>>>(tf, coarse, (float*)d_out);
}

// Round 7
// 2423.453 us; speedup vs baseline: 2.1264x; 1.0220x over previous
//
#include <hip/hip_runtime.h>
#include <cstdint>

typedef unsigned short bfraw;
typedef __attribute__((ext_vector_type(8))) short short8;
typedef __attribute__((ext_vector_type(4))) float f32x4;
typedef __attribute__((ext_vector_type(4))) unsigned int u32x4;

#define DEV static __device__ __forceinline__

constexpr int NCHUNK = 8;
constexpr int CHUNK = 6250;
constexpr int CHUNK_LD = 6272;
constexpr int LAYERS = 6;

DEV float b2f(bfraw s) { return __uint_as_float(((unsigned)s) << 16); }
DEV bfraw f2b(float f) {
  unsigned u = __float_as_uint(f);
  u += 0x7FFFu + ((u >> 16) & 1u);
  return (bfraw)(u >> 16);
}
DEV float keyinv16(unsigned k) {
  unsigned raw = (k & 0x8000u) ? (k ^ 0x8000u) : (~k & 0xFFFFu);
  return b2f((bfraw)raw);
}

// ---------------- fp32 -> bf16 conversion ----------------
__global__ __launch_bounds__(256) void k_cvt(const float* __restrict__ src,
                                             bfraw* __restrict__ dst, int n4) {
  int i = blockIdx.x * 256 + threadIdx.x;
  if (i < n4) {
    float4 v = ((const float4*)src)[i];
    ushort4 o;
    o.x = f2b(v.x); o.y = f2b(v.y); o.z = f2b(v.z); o.w = f2b(v.w);
    ((ushort4*)dst)[i] = o;
  }
}

// strided-chunk fp32 -> bf16 (gathers nch chunks of n4PerChunk float4s)
__global__ __launch_bounds__(256) void k_cvt_s(const float* __restrict__ src,
                                               bfraw* __restrict__ dst,
                                               int n4PerChunk, long srcStride4, int nch) {
  long i = (long)blockIdx.x * 256 + threadIdx.x;
  if (i < (long)n4PerChunk * nch) {
    int c = (int)(i / n4PerChunk);
    int j = (int)(i % n4PerChunk);
    float4 v = ((const float4*)src)[c * srcStride4 + j];
    ushort4 o;
    o.x = f2b(v.x); o.y = f2b(v.y); o.z = f2b(v.z); o.w = f2b(v.w);
    ((ushort4*)dst)[i] = o;
  }
}

// ---------------- transpose sa Wv slice: WvT[l][k][j] = sa_in_w[l,1024+j,k] ----------------
__global__ __launch_bounds__(256) void k_tr(const float* __restrict__ sa_in_w,
                                            bfraw* __restrict__ WvT) {
  __shared__ float tile[32][33];
  const int tx = threadIdx.x & 31, ty = threadIdx.x >> 5;  // 32 x 8
  const int j0 = blockIdx.y * 32, k0 = blockIdx.x * 32;
  const long l = blockIdx.z;
#pragma unroll
  for (int p = 0; p < 4; ++p)
    tile[ty + p * 8][tx] = sa_in_w[(l * 1536 + 1024 + j0 + ty + p * 8) * 512 + k0 + tx];
  __syncthreads();
#pragma unroll
  for (int p = 0; p < 4; ++p)
    WvT[l * 262144 + (long)(k0 + ty + p * 8) * 512 + j0 + tx] = f2b(tile[tx][ty + p * 8]);
}

// ---------------- bsa[l,m] = sum_j Wo[l,m,j]*bv[l,j] + bo[l,m] ----------------
__global__ __launch_bounds__(256) void k_bsa(const float* __restrict__ sa_out_w,
                                             const float* __restrict__ sa_in_b,
                                             const float* __restrict__ sa_out_b,
                                             float* __restrict__ bsa) {
  __shared__ float bv[512];
  const int t = threadIdx.x;
  const long l = blockIdx.x;
  bv[t] = sa_in_b[l * 1536 + 1024 + t];
  bv[t + 256] = sa_in_b[l * 1536 + 1024 + t + 256];
  __syncthreads();
#pragma unroll
  for (int h = 0; h < 2; ++h) {
    int m = t + h * 256;
    const float* wr = sa_out_w + (l * 512 + m) * 512;
    float s = 0.f;
    for (int q = 0; q < 128; ++q) {
      float4 v = ((const float4*)wr)[q];
      s += v.x * bv[q * 4] + v.y * bv[q * 4 + 1] + v.z * bv[q * 4 + 2] + v.w * bv[q * 4 + 3];
    }
    bsa[l * 512 + m] = s + sa_out_b[l * 512 + m];
  }
}

// ---------------- Generic bt-GEMM: C[M,N] = A[M,K] @ B[N,K]^T (+bias) ----------------
// TM=128: 4 waves 2x2, each 4x4 of 16x16x32 MFMA. TM=64: 4 waves 1x4, each 4x2.
// Staging via async global_load_lds width=16 (m97 structure): no VGPR round-trip,
// no ds_writes; compiler's pre-barrier vmcnt(0) drains the DMA. XOR swizzle is
// preserved by pre-swizzling the GLOBAL source address (kc = sCh^(fr&7)) while the
// LDS destination stays linear. Epilogue stages output tile in LDS, writes plain
// coalesced dwordx4 (NOT nt: consumers re-read C from L3 across kernel boundary).
template <int TM, bool OUTF32, bool OUTBF, bool RELU, bool BIAS, bool SWZ>
__global__ __launch_bounds__(256, 2) void k_gemm(
    const bfraw* __restrict__ A, int lda, long sA,
    const bfraw* __restrict__ B, int ldb, long sB,
    float* __restrict__ Cf, bfraw* __restrict__ Cb, int ldc, long sC,
    const float* __restrict__ bias, int sBias,
    int N, int K) {
  constexpr int WR = TM / 64;       // wave-row groups (2 or 1)
  constexpr int CW = 32 * WR;       // cols per wave (64 or 32)
  constexpr int JT = CW / 16;       // j tiles (4 or 2)
  constexpr int AP = TM / 32;       // A staging rounds (4 or 2)
  constexpr int STAGE_B = TM * 64 * 2 + 128 * 64 * 2;
  constexpr int EPP = OUTF32 ? 132 : 136;  // epilogue LDS pitch (elements)
  constexpr int EP_B = OUTF32 ? TM * 132 * 4 : TM * 136 * 2;
  constexpr int SMEM_B = STAGE_B > EP_B ? STAGE_B : EP_B;
  __shared__ __align__(16) char smem[SMEM_B];
  bfraw* lsA = (bfraw*)smem;
  bfraw* lsB = (bfraw*)(smem + TM * 64 * 2);
  const int t = threadIdx.x;
  const int lane = t & 63;
  const int wave = t >> 6;
  const int wr = (TM == 128) ? (wave & 1) : 0;
  const int wc = (TM == 128) ? (wave >> 1) : wave;
  int bx, by;
  if (SWZ) {
    int l = blockIdx.x;
    int xcd = l & 7;
    int s = l >> 3;
    by = s / 7;
    int bxi = s % 7;
    bx = bxi * 8 + xcd;
    if (bx * 128 >= N) return;
  } else {
    bx = blockIdx.x;
    by = blockIdx.y;
  }
  const int z = blockIdx.z;
  A += (long)z * sA;
  B += (long)z * sB;

  const int sRow = t >> 3;  // 0..31
  const int sCh = t & 7;
  const int rowA0 = by * TM;
  const int colB0 = bx * 128;

  f32x4 acc[4][JT];
#pragma unroll
  for (int i = 0; i < 4; ++i)
#pragma unroll
    for (int j = 0; j < JT; ++j) {
      acc[i][j][0] = 0.f; acc[i][j][1] = 0.f; acc[i][j][2] = 0.f; acc[i][j][3] = 0.f;
    }

  const int nk = K >> 6;
  // Per-thread swizzled global source bases (element offsets), LDS dests linear.
  const bfraw* aSrc[AP];
#pragma unroll
  for (int p = 0; p < AP; ++p) {
    int fr = p * 32 + sRow;
    int kc = sCh ^ (fr & 7);
    aSrc[p] = A + (long)(rowA0 + fr) * lda + kc * 8;
  }
  const bfraw* bSrc[4];
#pragma unroll
  for (int p = 0; p < 4; ++p) {
    int fr = p * 32 + sRow;
    int kc = sCh ^ (fr & 7);
    int rB = colB0 + fr;
    if (rB >= N) rB = N - 1;  // clamp; polluted cols masked at store
    bSrc[p] = B + (long)rB * ldb + kc * 8;
  }

  for (int kt = 0; kt < nk; ++kt) {
    __syncthreads();  // previous tile fully consumed by all waves
#pragma unroll
    for (int p = 0; p < AP; ++p)
      __builtin_amdgcn_global_load_lds(
          (const unsigned int*)(aSrc[p] + kt * 64),
          (unsigned int*)(smem + p * 4096 + wave * 1024), 16, 0, 0);
#pragma unroll
    for (int p = 0; p < 4; ++p)
      __builtin_amdgcn_global_load_lds(
          (const unsigned int*)(bSrc[p] + kt * 64),
          (unsigned int*)(smem + TM * 128 + p * 4096 + wave * 1024), 16, 0, 0);
    __syncthreads();  // compiler emits s_waitcnt vmcnt(0) before s_barrier -> LDS ready
#pragma unroll
    for (int ks = 0; ks < 2; ++ks) {
      short8 af[4], bfm[JT];
#pragma unroll
      for (int i = 0; i < 4; ++i) {
        int r = wr * 64 + i * 16 + (lane & 15);
        int q = ks * 4 + (lane >> 4);
        af[i] = *(const short8*)(lsA + r * 64 + ((q ^ (r & 7)) * 8));
      }
#pragma unroll
      for (int j = 0; j < JT; ++j) {
        int n = wc * CW + j * 16 + (lane & 15);
        int q = ks * 4 + (lane >> 4);
        bfm[j] = *(const short8*)(lsB + n * 64 + ((q ^ (n & 7)) * 8));
      }
#pragma unroll
      for (int i = 0; i < 4; ++i)
#pragma unroll
        for (int j = 0; j < JT; ++j)
          acc[i][j] = __builtin_amdgcn_mfma_f32_16x16x32_bf16(af[i], bfm[j], acc[i][j], 0, 0, 0);
    }
  }

  // ---- epilogue: stage tile in LDS, write coalesced rows ----
  __syncthreads();  // all waves done reading lsA/lsB before we alias over them
  const int Nrem = N - colB0;  // valid cols in this tile (may exceed 128)
  if (OUTBF) {
    unsigned short* ep = (unsigned short*)smem;
#pragma unroll
    for (int j = 0; j < JT; ++j) {
      int cl = wc * CW + j * 16 + (lane & 15);
      int n = colB0 + cl;
      float bv = 0.f;
      if (BIAS) bv = (n < N) ? bias[(long)z * sBias + n] : 0.f;
#pragma unroll
      for (int i = 0; i < 4; ++i) {
        int r0 = wr * 64 + i * 16 + ((lane >> 4) << 2);
#pragma unroll
        for (int r = 0; r < 4; ++r) {
          float v = acc[i][j][r] + bv;
          if (RELU) v = fmaxf(v, 0.f);
          ep[(r0 + r) * EPP + cl] = f2b(v);
        }
      }
    }
    __syncthreads();
#pragma unroll
    for (int pass = 0; pass < TM / 16; ++pass) {
      int row = pass * 16 + (t >> 4);
      int c0 = (t & 15) * 8;
      long base = (long)(rowA0 + row) * ldc + (long)z * sC + colB0;
      if (c0 + 8 <= Nrem) {
        u32x4 v = *(const u32x4*)(ep + row * EPP + c0);
        *(u32x4*)(Cb + base + c0) = v;
      } else if (c0 < Nrem) {
        for (int q = c0; q < Nrem && q < 128; ++q) Cb[base + q] = (bfraw)ep[row * EPP + q];
      }
    }
  }
  if (OUTF32) {
    float* ep = (float*)smem;
#pragma unroll
    for (int j = 0; j < JT; ++j) {
      int cl = wc * CW + j * 16 + (lane & 15);
      int n = colB0 + cl;
      float bv = 0.f;
      if (BIAS) bv = (n < N) ? bias[(long)z * sBias + n] : 0.f;
#pragma unroll
      for (int i = 0; i < 4; ++i) {
        int r0 = wr * 64 + i * 16 + ((lane >> 4) << 2);
#pragma unroll
        for (int r = 0; r < 4; ++r) {
          float v = acc[i][j][r] + bv;
          if (RELU) v = fmaxf(v, 0.f);
          ep[(r0 + r) * EPP + cl] = v;
        }
      }
    }
    __syncthreads();
#pragma unroll
    for (int pass = 0; pass < TM / 8; ++pass) {
      int row = pass * 8 + (t >> 5);
      int c0 = (t & 31) * 4;
      long base = (long)(rowA0 + row) * ldc + (long)z * sC + colB0;
      if (c0 + 4 <= Nrem) {
        f32x4 v = *(const f32x4*)(ep + row * EPP + c0);
        *(f32x4*)(Cf + base + c0) = v;
      } else if (c0 < Nrem) {
        for (int q = c0; q < Nrem && q < 128; ++q) Cf[base + q] = ep[row * EPP + q];
      }
    }
  }
}

// ---------------- per-row top-64 of one bf16 score chunk (2-level radix select) ----------------
__global__ __launch_bounds__(256) void k_select(const bfraw* __restrict__ scores,
                                                float* __restrict__ cval, int* __restrict__ cidx,
                                                int chunk) {
  __shared__ unsigned short keys[CHUNK];
  __shared__ unsigned hist[256];
  __shared__ unsigned sh_sel, sh_rank, cnt_a, cnt_t;
  __shared__ unsigned tiebuf[64];
  const int t = threadIdx.x;
  const long b = blockIdx.x;
  const bfraw* row = scores + b * CHUNK_LD;
  for (int i = t; i < CHUNK; i += 256) {
    unsigned u = row[i];
    keys[i] = (u & 0x8000u) ? (unsigned short)(~u) : (unsigned short)(u | 0x8000u);
  }
  if (t == 0) { cnt_a = 0; cnt_t = 0; }
  unsigned prefix = 0, pmask = 0, rank = 64;
  for (int lev = 0; lev < 2; ++lev) {
    const int sh = 8 - lev * 8;
    hist[t] = 0;
    __syncthreads();
    for (int i = t; i < CHUNK; i += 256) {
      unsigned k = keys[i];
      if ((k & pmask) == prefix) atomicAdd(&hist[(k >> sh) & 255u], 1u);
    }
    __syncthreads();
    if (t < 64) {  // wave0: suffix-scan buckets, find bucket containing rank
      unsigned h0 = hist[t * 4], h1 = hist[t * 4 + 1], h2 = hist[t * 4 + 2], h3 = hist[t * 4 + 3];
      unsigned lsum = h0 + h1 + h2 + h3;
      unsigned suf = lsum;
#pragma unroll
      for (int off = 1; off < 64; off <<= 1) {
        unsigned vv = __shfl_down(suf, off);
        if (t + off < 64) suf += vv;
      }
      unsigned c = suf - lsum;
      unsigned hs[4] = {h0, h1, h2, h3};
#pragma unroll
      for (int q = 3; q >= 0; --q) {
        if (rank > c && rank <= c + hs[q]) { sh_sel = (unsigned)(t * 4 + q); sh_rank = rank - c; }
        c += hs[q];
      }
    }
    __syncthreads();
    prefix |= sh_sel << sh;
    pmask |= 255u << sh;
    rank = sh_rank;
    __syncthreads();
  }
  const unsigned cutkey = prefix;
  float* ov = cval + (b * NCHUNK + chunk) * 64;
  int* oi = cidx + (b * NCHUNK + chunk) * 64;
  for (int i = t; i < CHUNK; i += 256) {
    unsigned k = keys[i];
    if (k > cutkey) {
      unsigned p = atomicAdd(&cnt_a, 1u);
      ov[p] = keyinv16(k);
      oi[p] = chunk * CHUNK + i;
    } else if (k == cutkey) {
      unsigned p = atomicAdd(&cnt_t, 1u);
      if (p < 64) tiebuf[p] = (unsigned)i;
    }
  }
  __syncthreads();
  if (t == 0) {  // fill remaining slots from ties (lowest index first)
    int need = (int)rank;
    int tc = cnt_t < 64u ? (int)cnt_t : 64;
    int base = (int)cnt_a;
    float cv = keyinv16(cutkey);
    for (int s2 = 0; s2 < need; ++s2) {
      unsigned best = 0xFFFFFFFFu; int bq = 0;
      for (int q2 = 0; q2 < tc; ++q2)
        if (tiebuf[q2] < best) { best = tiebuf[q2]; bq = q2; }
      tiebuf[bq] = 0xFFFFFFFFu;
      ov[base + s2] = cv;
      oi[base + s2] = chunk * CHUNK + (int)best;
    }
  }
}

// ---------------- Refine: sort 512 cands, exact fp32 rescore top-64, top-32 + softmax ----------------
// Rescore: one WAVE per candidate row (coalesced 2KB burst, x-slice in registers,
// 6-step shfl reduce), 16 independent rows per wave for memory-level parallelism.
__global__ __launch_bounds__(256) void k_refine(const float* __restrict__ cval,
                                                const int* __restrict__ cidx,
                                                const float* __restrict__ x,
                                                const float* __restrict__ cf,
                                                int* __restrict__ tidx, float* __restrict__ w) {
  __shared__ float sv[512];
  __shared__ int si[512];
  __shared__ float xs[512];
  __shared__ float rv[64];
  __shared__ int ri[64];
  const int t = threadIdx.x;
  const int lane = t & 63, wave = t >> 6;
  const long b = blockIdx.x;
  sv[t] = cval[b * 512 + t]; sv[t + 256] = cval[b * 512 + t + 256];
  si[t] = cidx[b * 512 + t]; si[t + 256] = cidx[b * 512 + t + 256];
  xs[t] = x[b * 512 + t]; xs[t + 256] = x[b * 512 + t + 256];
  __syncthreads();
  for (int k = 2; k <= 512; k <<= 1)
    for (int j = k >> 1; j >= 1; j >>= 1) {
      int i = ((t & ~(j - 1)) << 1) | (t & (j - 1));
      int p = i | j;
      bool dir = ((i & k) == 0);
      float va = sv[i], vb = sv[p];
      int ia = si[i], ib = si[p];
      bool pBetter = (vb > va) || (vb == va && ib < ia);
      if (pBetter == dir) { sv[i] = vb; sv[p] = va; si[i] = ib; si[p] = ia; }
      __syncthreads();
    }
  // exact fp32 rescore of top-64: wave per row, coalesced
  float xr[8];
  {
    float4 a = *(const float4*)(xs + lane * 8);
    float4 b2 = *(const float4*)(xs + lane * 8 + 4);
    xr[0] = a.x; xr[1] = a.y; xr[2] = a.z; xr[3] = a.w;
    xr[4] = b2.x; xr[5] = b2.y; xr[6] = b2.z; xr[7] = b2.w;
  }
#pragma unroll
  for (int k = 0; k < 16; ++k) {
    int c = wave * 16 + k;
    int idx = si[c];
    const float* cr = cf + (long)idx * 512 + lane * 8;
    float4 v0 = *(const float4*)cr;
    float4 v1 = *(const float4*)(cr + 4);
    float s = v0.x * xr[0] + v0.y * xr[1] + v0.z * xr[2] + v0.w * xr[3]
            + v1.x * xr[4] + v1.y * xr[5] + v1.z * xr[6] + v1.w * xr[7];
#pragma unroll
    for (int off = 1; off < 64; off <<= 1) s += __shfl_xor(s, off);
    if (lane == 0) { rv[c] = s; ri[c] = idx; }
  }
  __syncthreads();
  if (t < 64) {
    float v = rv[t];
    int ix = ri[t];
    for (int k = 2; k <= 64; k <<= 1)
      for (int j = k >> 1; j >= 1; j >>= 1) {
        float ov = __shfl_xor(v, j);
        int oi = __shfl_xor(ix, j);
        bool up = ((t & k) == 0);
        bool low = ((t & j) == 0);
        bool oBetter = (ov > v) || (ov == v && oi < ix);
        if (oBetter == (up == low)) { v = ov; ix = oi; }
      }
    float m = __shfl(v, 0);
    float e = (t < 32) ? __expf(v - m) : 0.f;
    float ssum = e;
#pragma unroll
    for (int off = 1; off < 64; off <<= 1) ssum += __shfl_xor(ssum, off);
    if (t < 32) {
      w[b * 32 + t] = e / ssum;
      tidx[b * 32 + t] = ix;
    }
  }
}

// ---------------- Build kv (B,33,512) bf16 ----------------
__global__ __launch_bounds__(256) void k_buildkv(const float* __restrict__ x, const bfraw* __restrict__ cfb,
                                                 const float* __restrict__ type_emb,
                                                 const float* __restrict__ pos_emb,
                                                 const float* __restrict__ w, const int* __restrict__ tidx,
                                                 bfraw* __restrict__ kv) {
  const int t = threadIdx.x;
  const long b = blockIdx.x;
  bfraw* out = kv + b * (33 * 512);
  const float* xr = x + b * 512;
  for (int d = t; d < 512; d += 256) out[d] = f2b(xr[d] + type_emb[d]);
  for (int j = 0; j < 32; ++j) {
    const long ci = tidx[b * 32 + j];
    const float wj = w[b * 32 + j];
    const bfraw* cr = cfb + ci * 512;
    bfraw* o = out + (j + 1) * 512;
    for (int d = t; d < 512; d += 256)
      o[d] = f2b(wj * b2f(cr[d]) + pos_emb[j * 512 + d] + type_emb[512 + d]);
  }
}

// ---------------- t init ----------------
__global__ __launch_bounds__(256) void k_init_t(const float* __restrict__ cls, float* __restrict__ tf,
                                                bfraw* __restrict__ tb) {
  const long i = (long)blockIdx.x * 256 + threadIdx.x;
  const int d = (int)(i & 511);
  tf[i] = cls[d];
  tb[i] = f2b(cls[d]);
}

// ---------------- wkT prep: wkT[i,h,d,e] = ca_in_w[i, 512 + h*64 + e, d] ----------------
__global__ __launch_bounds__(256) void k_prep(const float* __restrict__ ca_in_w, bfraw* __restrict__ wkT) {
  const long o = (long)blockIdx.x * 256 + threadIdx.x;
  const int e = (int)(o & 63);
  long r = o >> 6;
  const int d = (int)(r & 511); r >>= 9;
  const int h = (int)(r & 7);
  const int i = (int)(r >> 3);
  wkT[o] = f2b(ca_in_w[((long)i * 1536 + 512 + h * 64 + e) * 512 + d]);
}

// ---------------- CA attention core: MFMA QK^T + scalar PV ----------------
__global__ __launch_bounds__(256) void k_attn(const bfraw* __restrict__ u, const bfraw* __restrict__ kv,
                                              bfraw* __restrict__ cout) {
  __shared__ __align__(16) bfraw kvs[33 * 512];
  __shared__ __align__(16) bfraw us[8 * 512];
  __shared__ float ps[8 * 48];
  const int t = threadIdx.x, lane = t & 63, wave = t >> 6;
  const long b = blockIdx.x;
  const bfraw* kvg = kv + b * (33 * 512);
  const bfraw* ug = u + b * (8 * 512);

  // stage: logical chunk c (0..63) of row r lives at LDS chunk c; global source is
  // chunk (c&56)|((c&7)^(r&7)) so that swizzled READS return logical data.
  {
#pragma unroll
    for (int r = 0; r < 8; ++r) {
      int row = r * 4 + wave;  // wave-uniform
      int sc = (lane & 56) | ((lane & 7) ^ (row & 7));
      __builtin_amdgcn_global_load_lds((const unsigned int*)(kvg + row * 512 + sc * 8),
                                       (unsigned int*)(kvs + row * 512), 16, 0, 0);
    }
    if (wave == 0)
      __builtin_amdgcn_global_load_lds((const unsigned int*)(kvg + 32 * 512 + lane * 8),
                                       (unsigned int*)(kvs + 32 * 512), 16, 0, 0);
#pragma unroll
    for (int r = 0; r < 2; ++r) {
      int row = r * 4 + wave;
      int sc = (lane & 56) | ((lane & 7) ^ (row & 7));
      __builtin_amdgcn_global_load_lds((const unsigned int*)(ug + row * 512 + sc * 8),
                                       (unsigned int*)(us + row * 512), 16, 0, 0);
    }
  }
  __syncthreads();

  // ---- QK^T ----
  if (wave < 2) {
    const int jj = wave * 16 + (lane & 15);  // B row (j), all valid (0..31)
    const int rr = lane & 7;                 // A row: duplicate heads into rows 8..15
    f32x4 acc = {0.f, 0.f, 0.f, 0.f};
#pragma unroll
    for (int ks = 0; ks < 16; ++ks) {
      int q = ks * 4 + (lane >> 4);  // logical chunk 0..63
      short8 af = *(const short8*)(us + rr * 512 + (((q & 56) | ((q & 7) ^ rr)) * 8));
      short8 bf = *(const short8*)(kvs + jj * 512 + (((q & 56) | ((q & 7) ^ (jj & 7))) * 8));
      acc = __builtin_amdgcn_mfma_f32_16x16x32_bf16(af, bf, acc, 0, 0, 0);
    }
#pragma unroll
    for (int r = 0; r < 4; ++r) {
      int row = (lane >> 4) * 4 + r;
      if (row < 8) ps[row * 48 + wave * 16 + (lane & 15)] = acc[r] * 0.125f;
    }
  } else if (wave == 2) {
    // j = 32 column: scalar dot, 8 lanes per head
    int h = lane >> 3, seg = lane & 7;
    float s = 0.f;
#pragma unroll
    for (int i = 0; i < 8; ++i) {
      int c = seg * 8 + i;
      short8 kk = *(const short8*)(kvs + 32 * 512 + c * 8);  // row 32: r&7==0, unswizzled
      short8 uu = *(const short8*)(us + h * 512 + (((c & 56) | ((c & 7) ^ h)) * 8));
#pragma unroll
      for (int e = 0; e < 8; ++e) s += b2f((bfraw)uu[e]) * b2f((bfraw)kk[e]);
    }
    s += __shfl_xor(s, 1);
    s += __shfl_xor(s, 2);
    s += __shfl_xor(s, 4);
    if (seg == 0) ps[h * 48 + 32] = s * 0.125f;
  }
  __syncthreads();

  // ---- softmax (2 heads per wave) ----
#pragma unroll
  for (int hh = 0; hh < 2; ++hh) {
    int h = wave + hh * 4;
    float sv2 = (lane < 33) ? ps[h * 48 + lane] : -3.0e38f;
    float m = sv2;
#pragma unroll
    for (int off = 1; off < 64; off <<= 1) m = fmaxf(m, __shfl_xor(m, off));
    float e = (lane < 33) ? __expf(sv2 - m) : 0.f;
    float s = e;
#pragma unroll
    for (int off = 1; off < 64; off <<= 1) s += __shfl_xor(s, off);
    if (lane < 33) ps[h * 48 + lane] = e / s;
  }
  __syncthreads();

  // ---- PV (scalar, swizzle-aware) ----
#pragma unroll
  for (int hh = 0; hh < 2; ++hh) {
    int h = wave + hh * 4;
    float acc[8] = {0.f, 0.f, 0.f, 0.f, 0.f, 0.f, 0.f, 0.f};
    for (int j = 0; j < 33; ++j) {
      float pj = ps[h * 48 + j];
      int c = (lane & 56) | ((lane & 7) ^ (j & 7));
      short8 kk = *(const short8*)(kvs + j * 512 + c * 8);
#pragma unroll
      for (int q = 0; q < 8; ++q) acc[q] += pj * b2f((bfraw)kk[q]);
    }
    union { bfraw o[8]; uint4 v4; } pk;
#pragma unroll
    for (int q = 0; q < 8; ++q) pk.o[q] = f2b(acc[q]);
    *(uint4*)(cout + (b * 8 + h) * 512 + lane * 8) = pk.v4;
  }
}

// ---------------- residual + LayerNorm ----------------
__global__ __launch_bounds__(256) void k_ln(float* __restrict__ tf, bfraw* __restrict__ tb,
                                            const float* __restrict__ delta,
                                            const float* __restrict__ g, const float* __restrict__ be) {
  const int lane = threadIdx.x & 63, wave = threadIdx.x >> 6;
  const long row = (long)blockIdx.x * 4 + wave;
  float* tr = tf + row * 512;
  const float* dr = delta + row * 512;
  float v[8];
  float4 a0 = *(const float4*)(tr + lane * 8);
  float4 a1 = *(const float4*)(tr + lane * 8 + 4);
  float4 d0 = *(const float4*)(dr + lane * 8);
  float4 d1 = *(const float4*)(dr + lane * 8 + 4);
  v[0] = a0.x + d0.x; v[1] = a0.y + d0.y; v[2] = a0.z + d0.z; v[3] = a0.w + d0.w;
  v[4] = a1.x + d1.x; v[5] = a1.y + d1.y; v[6] = a1.z + d1.z; v[7] = a1.w + d1.w;
  float s = 0.f;
#pragma unroll
  for (int q = 0; q < 8; ++q) s += v[q];
#pragma unroll
  for (int off = 1; off < 64; off <<= 1) s += __shfl_xor(s, off);
  const float mean = s * (1.f / 512.f);
  float sq = 0.f;
#pragma unroll
  for (int q = 0; q < 8; ++q) { float d = v[q] - mean; sq += d * d; }
#pragma unroll
  for (int off = 1; off < 64; off <<= 1) sq += __shfl_xor(sq, off);
  const float rs = 1.f / sqrtf(sq * (1.f / 512.f) + 1e-5f);
  float4 g0 = *(const float4*)(g + lane * 8);
  float4 g1 = *(const float4*)(g + lane * 8 + 4);
  float4 b0 = *(const float4*)(be + lane * 8);
  float4 b1 = *(const float4*)(be + lane * 8 + 4);
  float gg[8] = {g0.x, g0.y, g0.z, g0.w, g1.x, g1.y, g1.z, g1.w};
  float bb[8] = {b0.x, b0.y, b0.z, b0.w, b1.x, b1.y, b1.z, b1.w};
  float o[8];
  union { bfraw u16[8]; uint4 u4; } pk;
#pragma unroll
  for (int q = 0; q < 8; ++q) {
    o[q] = (v[q] - mean) * rs * gg[q] + bb[q];
    pk.u16[q] = f2b(o[q]);
  }
  *(float4*)(tr + lane * 8) = make_float4(o[0], o[1], o[2], o[3]);
  *(float4*)(tr + lane * 8 + 4) = make_float4(o[4], o[5], o[6], o[7]);
  *(uint4*)(tb + row * 512 + lane * 8) = pk.u4;
}

// ---------------- final triple-normalize ----------------
__global__ __launch_bounds__(64) void k_final(const float* __restrict__ tf, const float* __restrict__ coarse,
                                              float* __restrict__ out) {
  const int lane = threadIdx.x;
  const long b = blockIdx.x;
  const float* fr = tf + b * 512;
  const float* cr = coarse + b * 512;
  float4 f0 = *(const float4*)(fr + lane * 8);
  float4 f1 = *(const float4*)(fr + lane * 8 + 4);
  float4 c0 = *(const float4*)(cr + lane * 8);
  float4 c1 = *(const float4*)(cr + lane * 8 + 4);
  float f[8] = {f0.x, f0.y, f0.z, f0.w, f1.x, f1.y, f1.z, f1.w};
  float c[8] = {c0.x, c0.y, c0.z, c0.w, c1.x, c1.y, c1.z, c1.w};
  float sf = 0.f, sc = 0.f;
#pragma unroll
  for (int q = 0; q < 8; ++q) { sf += f[q] * f[q]; sc += c[q] * c[q]; }
#pragma unroll
  for (int off = 1; off < 64; off <<= 1) { sf += __shfl_xor(sf, off); sc += __shfl_xor(sc, off); }
  const float rf = 1.f / sqrtf(sf), rc = 1.f / sqrtf(sc);
  float a[8];
  float sa = 0.f;
#pragma unroll
  for (int q = 0; q < 8; ++q) { a[q] = f[q] * rf + c[q] * rc; sa += a[q] * a[q]; }
#pragma unroll
  for (int off = 1; off < 64; off <<= 1) sa += __shfl_xor(sa, off);
  const float ra = 1.f / sqrtf(sa);
  *(float4*)(out + b * 512 + lane * 8) = make_float4(a[0] * ra, a[1] * ra, a[2] * ra, a[3] * ra);
  *(float4*)(out + b * 512 + lane * 8 + 4) = make_float4(a[4] * ra, a[5] * ra, a[6] * ra, a[7] * ra);
}

// ---------------- workspace layout (bytes) ----------------
constexpr long OFF_XB = 0;                    //  4,194,304
constexpr long OFF_WKT = 4194304;             //  3,145,728
constexpr long OFF_SAOUT = 7340032;           //  3,145,728 (Wo bf16)
constexpr long OFF_WSAB = 10485760;           //  3,145,728 (Wsa bf16)
constexpr long OFF_CAWQ = 13631488;           //  3,145,728
constexpr long OFF_CAWV = 16777216;           //  3,145,728
constexpr long OFF_CAOUT = 19922944;          //  3,145,728
constexpr long OFF_REGW = 23068672;           //    524,288
constexpr long OFF_L1B = 23592960;            // 12,582,912 (all layers)
constexpr long OFF_L2B = 36175872;            // 12,582,912
constexpr long OFF_BSA = 48758784;            //     16,384
constexpr long OFF_TIDX = 48775168;           //    524,288
constexpr long OFF_WSM = 49299456;            //    524,288
constexpr long OFF_REGION = 49823744;         // 138,412,032 (WvT preamble / score bf16 / kv)
constexpr long OFF_POOL = 188235776;          // 83,886,080
constexpr long P_TF = 0;                      // 8,388,608 fp32 (phase1: cval)
constexpr long P_TB = 8388608;                // 4,194,304 bf16 (phase1: cidx lo)
constexpr long P_QBF = 12582912;              // 4,194,304 bf16 (phase1: cidx hi)
constexpr long P_UBUF = 16777216;             // 33,554,432 (phase1: cfb 51.2MB spans UBUF+part CBUF)
constexpr long P_CBUF = 50331648;             // 33,554,432 (delta +0, coarse +8,388,608)
constexpr long WS_TOTAL = OFF_POOL + 83886080;  // 272,121,856

extern "C" void kernel_launch(void* const* d_in, const int* in_sizes, int n_in,
                              void* d_out, int out_size, void* d_ws, size_t ws_size,
                              hipStream_t stream) {
  if (n_in < 25) return;
  if (ws_size < (size_t)WS_TOTAL) return;

  const float* x = (const float*)d_in[0];
  const float* cf = (const float*)d_in[1];
  const float* type_emb = (const float*)d_in[2];
  const float* pos_emb = (const float*)d_in[3];
  const float* cls = (const float*)d_in[4];
  const float* sa_in_w = (const float*)d_in[5];
  const float* sa_in_b = (const float*)d_in[6];
  const float* sa_out_w = (const float*)d_in[7];
  const float* sa_out_b = (const float*)d_in[8];
  const float* ca_in_w = (const float*)d_in[9];
  const float* ca_in_b = (const float*)d_in[10];
  const float* ca_out_w = (const float*)d_in[11];
  const float* ca_out_b = (const float*)d_in[12];
  const float* lin1_w = (const float*)d_in[13];
  const float* lin1_b = (const float*)d_in[14];
  const float* lin2_w = (const float*)d_in[15];
  const float* lin2_b = (const float*)d_in[16];
  const float* ln1_g = (const float*)d_in[17];
  const float* ln1_bp = (const float*)d_in[18];
  const float* ln2_g = (const float*)d_in[19];
  const float* ln2_bp = (const float*)d_in[20];
  const float* ln3_g = (const float*)d_in[21];
  const float* ln3_bp = (const float*)d_in[22];
  const float* region_w = (const float*)d_in[23];
  const float* region_b = (const float*)d_in[24];

  char* ws = (char*)d_ws;
  bfraw* xb = (bfraw*)(ws + OFF_XB);
  bfraw* wkT = (bfraw*)(ws + OFF_WKT);
  bfraw* saout = (bfraw*)(ws + OFF_SAOUT);
  bfraw* wsab = (bfraw*)(ws + OFF_WSAB);
  bfraw* cawq = (bfraw*)(ws + OFF_CAWQ);
  bfraw* cawv = (bfraw*)(ws + OFF_CAWV);
  bfraw* caout = (bfraw*)(ws + OFF_CAOUT);
  bfraw* regw = (bfraw*)(ws + OFF_REGW);
  bfraw* l1b = (bfraw*)(ws + OFF_L1B);
  bfraw* l2b = (bfraw*)(ws + OFF_L2B);
  float* bsa = (float*)(ws + OFF_BSA);
  int* tidx = (int*)(ws + OFF_TIDX);
  float* wsm = (float*)(ws + OFF_WSM);
  bfraw* WvT = (bfraw*)(ws + OFF_REGION);  // preamble only
  bfraw* scoreb = (bfraw*)(ws + OFF_REGION);
  bfraw* kv = (bfraw*)(ws + OFF_REGION);
  char* pool = ws + OFF_POOL;
  float* tf = (float*)(pool + P_TF);
  float* cval = (float*)(pool + P_TF);
  bfraw* tb = (bfraw*)(pool + P_TB);
  int* cidx = (int*)(pool + P_TB);
  bfraw* qbf = (bfraw*)(pool + P_QBF);
  bfraw* tmpb = (bfraw*)(pool + P_QBF);
  bfraw* ubuf = (bfraw*)(pool + P_UBUF);
  bfraw* ffb = (bfraw*)(pool + P_UBUF);
  bfraw* cfb = (bfraw*)(pool + P_UBUF);  // 51.2 MB, phase-1 only
  bfraw* cbuf = (bfraw*)(pool + P_CBUF);
  float* delta = (float*)(pool + P_CBUF);
  float* coarse = (float*)(pool + P_CBUF + 8388608);

  dim3 blk(256);

  // ---- preamble: conversions + SA fold ----
  k_cvt<<<2048, blk, 0, stream>>>(x, xb, 524288);
  k_cvt<<<25000, blk, 0, stream>>>(cf, cfb, 6400000);
  k_cvt<<<1536, blk, 0, stream>>>(sa_out_w, saout, 393216);
  k_cvt<<<1536, blk, 0, stream>>>(ca_out_w, caout, 393216);
  k_cvt<<<256, blk, 0, stream>>>(region_w, regw, 65536);
  k_cvt<<<6144, blk, 0, stream>>>(lin1_w, l1b, 1572864);
  k_cvt<<<6144, blk, 0, stream>>>(lin2_w, l2b, 1572864);
  k_cvt_s<<<1536, blk, 0, stream>>>(ca_in_w, cawq, 65536, 196608, 6);
  k_cvt_s<<<1536, blk, 0, stream>>>(ca_in_w + 1024 * 512, cawv, 65536, 196608, 6);
  k_prep<<<6144, blk, 0, stream>>>(ca_in_w, wkT);
  k_tr<<<dim3(16, 16, 6), blk, 0, stream>>>(sa_in_w, WvT);
  k_gemm<64, false, true, false, false, false><<<dim3(4, 8, 6), blk, 0, stream>>>(
      saout, 512, 262144, WvT, 512, 262144, nullptr, wsab, 512, 262144, nullptr, 0, 512, 512);
  k_bsa<<<6, blk, 0, stream>>>(sa_out_w, sa_in_b, sa_out_b, bsa);

  // ---- score GEMM (bf16 out, XCD-swizzled) + per-chunk top-64 ----
  for (int c = 0; c < NCHUNK; ++c) {
    k_gemm<128, false, true, false, false, true><<<dim3(1792, 1, 1), blk, 0, stream>>>(
        xb, 512, 0, cfb + (long)c * CHUNK * 512, 512, 0,
        nullptr, scoreb, CHUNK_LD, 0, nullptr, 0, CHUNK, 512);
    k_select<<<4096, blk, 0, stream>>>(scoreb, cval, cidx, c);
  }
  k_refine<<<4096, blk, 0, stream>>>(cval, cidx, x, cf, tidx, wsm);
  k_buildkv<<<4096, blk, 0, stream>>>(x, cfb, type_emb, pos_emb, wsm, tidx, kv);
  k_init_t<<<8192, blk, 0, stream>>>(cls, tf, tb);

  for (int i = 0; i < LAYERS; ++i) {
    const bfraw* ca_wq = cawq + (long)i * 262144;
    const float* ca_bq = ca_in_b + (long)i * 1536;
    const bfraw* ca_wv = cawv + (long)i * 262144;
    const float* ca_bv = ca_in_b + (long)i * 1536 + 1024;
    const bfraw* ca_wo = caout + (long)i * 262144;
    const float* ca_bo = ca_out_b + (long)i * 512;
    const bfraw* wkTi = wkT + (long)i * 8 * 512 * 64;

    // Self-attention folded: delta = t @ Wsa^T + bsa
    k_gemm<64, true, false, false, true, false><<<dim3(4, 64, 1), blk, 0, stream>>>(
        tb, 512, 0, wsab + (long)i * 262144, 512, 0, delta, nullptr, 512, 0, bsa + i * 512, 0, 512, 512);
    k_ln<<<1024, blk, 0, stream>>>(tf, tb, delta, ln1_g + i * 512, ln1_bp + i * 512);

    // Cross-attention (re-associated)
    k_gemm<64, false, true, false, true, false><<<dim3(4, 64, 1), blk, 0, stream>>>(
        tb, 512, 0, ca_wq, 512, 0, nullptr, qbf, 512, 0, ca_bq, 0, 512, 512);
    k_gemm<64, false, true, false, false, false><<<dim3(4, 64, 8), blk, 0, stream>>>(
        qbf, 512, 64, wkTi, 64, 32768, nullptr, ubuf, 4096, 512, nullptr, 0, 512, 64);
    k_attn<<<4096, blk, 0, stream>>>(ubuf, kv, cbuf);
    k_gemm<64, false, true, false, true, false><<<dim3(1, 64, 8), blk, 0, stream>>>(
        cbuf, 4096, 512, ca_wv, 512, 32768, nullptr, tmpb, 512, 64, ca_bv, 64, 64, 512);
    k_gemm<64, true, false, false, true, false><<<dim3(4, 64, 1), blk, 0, stream>>>(
        tmpb, 512, 0, ca_wo, 512, 0, delta, nullptr, 512, 0, ca_bo, 0, 512, 512);
    k_ln<<<1024, blk, 0, stream>>>(tf, tb, delta, ln2_g + i * 512, ln2_bp + i * 512);

    // FFN
    k_gemm<64, false, true, true, true, false><<<dim3(16, 64, 1), blk, 0, stream>>>(
        tb, 512, 0, l1b + (long)i * 1048576, 512, 0, nullptr, ffb, 2048, 0, lin1_b + i * 2048, 0, 2048, 512);
    k_gemm<64, true, false, false, true, false><<<dim3(4, 64, 1), blk, 0, stream>>>(
        ffb, 2048, 0, l2b + (long)i * 1048576, 2048, 0, delta, nullptr, 512, 0, lin2_b + i * 512, 0, 512, 2048);
    k_ln<<<1024, blk, 0, stream>>>(tf, tb, delta, ln3_g + i * 512, ln3_bp + i * 512);
  }

  k_gemm<64, true, false, false, true, false><<<dim3(4, 64, 1), blk, 0, stream>>>(
      xb, 512, 0, regw, 512, 0, coarse, nullptr, 512, 0, region_b, 0, 512, 512);
  k_final<<<4096, dim3(64), 0, stream>>>(tf, coarse, (float*)d_out);
}

// Round 8
// 2225.753 us; speedup vs baseline: 2.3153x; 1.0888x over previous
//
#include <hip/hip_runtime.h>
#include <cstdint>

typedef unsigned short bfraw;
typedef __attribute__((ext_vector_type(8))) short short8;
typedef __attribute__((ext_vector_type(4))) float f32x4;
typedef __attribute__((ext_vector_type(4))) unsigned int u32x4;

#define DEV static __device__ __forceinline__

constexpr int NCHUNK = 8;
constexpr int CHUNK = 6250;
constexpr int CHUNK_LD = 6272;
constexpr int LAYERS = 6;

DEV float b2f(bfraw s) { return __uint_as_float(((unsigned)s) << 16); }
DEV bfraw f2b(float f) {
  unsigned u = __float_as_uint(f);
  u += 0x7FFFu + ((u >> 16) & 1u);
  return (bfraw)(u >> 16);
}
DEV float keyinv16(unsigned k) {
  unsigned raw = (k & 0x8000u) ? (k ^ 0x8000u) : (~k & 0xFFFFu);
  return b2f((bfraw)raw);
}

// ---------------- fp32 -> bf16 conversion ----------------
__global__ __launch_bounds__(256) void k_cvt(const float* __restrict__ src,
                                             bfraw* __restrict__ dst, int n4) {
  int i = blockIdx.x * 256 + threadIdx.x;
  if (i < n4) {
    float4 v = ((const float4*)src)[i];
    ushort4 o;
    o.x = f2b(v.x); o.y = f2b(v.y); o.z = f2b(v.z); o.w = f2b(v.w);
    ((ushort4*)dst)[i] = o;
  }
}

// strided-chunk fp32 -> bf16 (gathers nch chunks of n4PerChunk float4s)
__global__ __launch_bounds__(256) void k_cvt_s(const float* __restrict__ src,
                                               bfraw* __restrict__ dst,
                                               int n4PerChunk, long srcStride4, int nch) {
  long i = (long)blockIdx.x * 256 + threadIdx.x;
  if (i < (long)n4PerChunk * nch) {
    int c = (int)(i / n4PerChunk);
    int j = (int)(i % n4PerChunk);
    float4 v = ((const float4*)src)[c * srcStride4 + j];
    ushort4 o;
    o.x = f2b(v.x); o.y = f2b(v.y); o.z = f2b(v.z); o.w = f2b(v.w);
    ((ushort4*)dst)[i] = o;
  }
}

// ---------------- transpose sa Wv slice: WvT[l][k][j] = sa_in_w[l,1024+j,k] ----------------
__global__ __launch_bounds__(256) void k_tr(const float* __restrict__ sa_in_w,
                                            bfraw* __restrict__ WvT) {
  __shared__ float tile[32][33];
  const int tx = threadIdx.x & 31, ty = threadIdx.x >> 5;  // 32 x 8
  const int j0 = blockIdx.y * 32, k0 = blockIdx.x * 32;
  const long l = blockIdx.z;
#pragma unroll
  for (int p = 0; p < 4; ++p)
    tile[ty + p * 8][tx] = sa_in_w[(l * 1536 + 1024 + j0 + ty + p * 8) * 512 + k0 + tx];
  __syncthreads();
#pragma unroll
  for (int p = 0; p < 4; ++p)
    WvT[l * 262144 + (long)(k0 + ty + p * 8) * 512 + j0 + tx] = f2b(tile[tx][ty + p * 8]);
}

// ---------------- bsa[l,m] = sum_j Wo[l,m,j]*bv[l,j] + bo[l,m] ----------------
__global__ __launch_bounds__(256) void k_bsa(const float* __restrict__ sa_out_w,
                                             const float* __restrict__ sa_in_b,
                                             const float* __restrict__ sa_out_b,
                                             float* __restrict__ bsa) {
  __shared__ float bv[512];
  const int t = threadIdx.x;
  const long l = blockIdx.x;
  bv[t] = sa_in_b[l * 1536 + 1024 + t];
  bv[t + 256] = sa_in_b[l * 1536 + 1024 + t + 256];
  __syncthreads();
#pragma unroll
  for (int h = 0; h < 2; ++h) {
    int m = t + h * 256;
    const float* wr = sa_out_w + (l * 512 + m) * 512;
    float s = 0.f;
    for (int q = 0; q < 128; ++q) {
      float4 v = ((const float4*)wr)[q];
      s += v.x * bv[q * 4] + v.y * bv[q * 4 + 1] + v.z * bv[q * 4 + 2] + v.w * bv[q * 4 + 3];
    }
    bsa[l * 512 + m] = s + sa_out_b[l * 512 + m];
  }
}

// ---------------- Generic bt-GEMM: C[M,N] = A[M,K] @ B[N,K]^T (+bias) ----------------
// TM=128: 4 waves 2x2, each 4x4 of 16x16x32 MFMA. TM=64: 4 waves 1x4, each 4x2.
// DOUBLE-BUFFERED global_load_lds staging with COUNTED vmcnt (T3/T4 minimum):
// prologue issues tiles 0,1; each iter waits vmcnt(LPT) (next tile stays in
// flight ACROSS the raw s_barrier), computes, re-issues kt+2 into freed buffer.
// Never vmcnt(0) mid-loop. XOR swizzle via pre-swizzled GLOBAL source, LDS linear.
// Epilogue stages output tile in LDS, writes plain coalesced dwordx4.
template <int TM, bool OUTF32, bool OUTBF, bool RELU, bool BIAS, bool SWZ>
__global__ __launch_bounds__(256, 2) void k_gemm(
    const bfraw* __restrict__ A, int lda, long sA,
    const bfraw* __restrict__ B, int ldb, long sB,
    float* __restrict__ Cf, bfraw* __restrict__ Cb, int ldc, long sC,
    const float* __restrict__ bias, int sBias,
    int N, int K) {
  constexpr int WR = TM / 64;       // wave-row groups (2 or 1)
  constexpr int CW = 32 * WR;       // cols per wave (64 or 32)
  constexpr int JT = CW / 16;       // j tiles (4 or 2)
  constexpr int AP = TM / 32;       // A staging rounds (4 or 2)
  constexpr int ABYT = TM * 128;    // A tile bytes
  constexpr int TILEB = ABYT + 128 * 128;  // one staging buffer (A+B)
  constexpr int STAGE_B = 2 * TILEB;
  constexpr int EPP = OUTF32 ? 132 : 136;  // epilogue LDS pitch (elements)
  constexpr int EP_B = OUTF32 ? TM * 132 * 4 : TM * 136 * 2;
  constexpr int SMEM_B = STAGE_B > EP_B ? STAGE_B : EP_B;
  __shared__ __align__(16) char smem[SMEM_B];
  const int t = threadIdx.x;
  const int lane = t & 63;
  const int wave = t >> 6;
  const int wr = (TM == 128) ? (wave & 1) : 0;
  const int wc = (TM == 128) ? (wave >> 1) : wave;
  int bx, by;
  if (SWZ) {
    int l = blockIdx.x;
    int xcd = l & 7;
    int s = l >> 3;
    by = s / 7;
    int bxi = s % 7;
    bx = bxi * 8 + xcd;
    if (bx * 128 >= N) return;  // block-uniform: no barrier imbalance
  } else {
    bx = blockIdx.x;
    by = blockIdx.y;
  }
  const int z = blockIdx.z;
  A += (long)z * sA;
  B += (long)z * sB;

  const int sRow = t >> 3;  // 0..31
  const int sCh = t & 7;
  const int rowA0 = by * TM;
  const int colB0 = bx * 128;

  f32x4 acc[4][JT];
#pragma unroll
  for (int i = 0; i < 4; ++i)
#pragma unroll
    for (int j = 0; j < JT; ++j) {
      acc[i][j][0] = 0.f; acc[i][j][1] = 0.f; acc[i][j][2] = 0.f; acc[i][j][3] = 0.f;
    }

  const int nk = K >> 6;
  // Per-thread swizzled global source bases, LDS dests linear.
  const bfraw* aSrc[AP];
#pragma unroll
  for (int p = 0; p < AP; ++p) {
    int fr = p * 32 + sRow;
    int kc = sCh ^ (fr & 7);
    aSrc[p] = A + (long)(rowA0 + fr) * lda + kc * 8;
  }
  const bfraw* bSrc[4];
#pragma unroll
  for (int p = 0; p < 4; ++p) {
    int fr = p * 32 + sRow;
    int kc = sCh ^ (fr & 7);
    int rB = colB0 + fr;
    if (rB >= N) rB = N - 1;  // clamp; polluted cols masked at store
    bSrc[p] = B + (long)rB * ldb + kc * 8;
  }

  auto stage = [&](int kt, int buf) {
#pragma unroll
    for (int p = 0; p < AP; ++p)
      __builtin_amdgcn_global_load_lds(
          (const unsigned int*)(aSrc[p] + kt * 64),
          (unsigned int*)(smem + buf * TILEB + p * 4096 + wave * 1024), 16, 0, 0);
#pragma unroll
    for (int p = 0; p < 4; ++p)
      __builtin_amdgcn_global_load_lds(
          (const unsigned int*)(bSrc[p] + kt * 64),
          (unsigned int*)(smem + buf * TILEB + ABYT + p * 4096 + wave * 1024), 16, 0, 0);
  };

  stage(0, 0);
  if (nk > 1) stage(1, 1);
  int cur = 0;
  for (int kt = 0; kt < nk; ++kt) {
    // wait current tile's LPT loads (next tile's stay in flight); LPT = AP+4
    if (kt + 1 < nk) {
      if constexpr (TM == 128) asm volatile("s_waitcnt vmcnt(8)" ::: "memory");
      else asm volatile("s_waitcnt vmcnt(6)" ::: "memory");
    } else {
      asm volatile("s_waitcnt vmcnt(0)" ::: "memory");
    }
    __builtin_amdgcn_s_barrier();  // all waves' cur-tile DMA landed
    __builtin_amdgcn_sched_barrier(0);
    const bfraw* lsA = (const bfraw*)(smem + cur * TILEB);
    const bfraw* lsB = (const bfraw*)(smem + cur * TILEB + ABYT);
#pragma unroll
    for (int ks = 0; ks < 2; ++ks) {
      short8 af[4], bfm[JT];
#pragma unroll
      for (int i = 0; i < 4; ++i) {
        int r = wr * 64 + i * 16 + (lane & 15);
        int q = ks * 4 + (lane >> 4);
        af[i] = *(const short8*)(lsA + r * 64 + ((q ^ (r & 7)) * 8));
      }
#pragma unroll
      for (int j = 0; j < JT; ++j) {
        int n = wc * CW + j * 16 + (lane & 15);
        int q = ks * 4 + (lane >> 4);
        bfm[j] = *(const short8*)(lsB + n * 64 + ((q ^ (n & 7)) * 8));
      }
#pragma unroll
      for (int i = 0; i < 4; ++i)
#pragma unroll
        for (int j = 0; j < JT; ++j)
          acc[i][j] = __builtin_amdgcn_mfma_f32_16x16x32_bf16(af[i], bfm[j], acc[i][j], 0, 0, 0);
    }
    __builtin_amdgcn_s_barrier();  // all waves done reading buf[cur]
    if (kt + 2 < nk) stage(kt + 2, cur);
    cur ^= 1;
  }

  // ---- epilogue: stage tile in LDS, write coalesced rows ----
  __syncthreads();  // drain + sync before aliasing over staging buffers
  const int Nrem = N - colB0;  // valid cols in this tile (may exceed 128)
  if (OUTBF) {
    unsigned short* ep = (unsigned short*)smem;
#pragma unroll
    for (int j = 0; j < JT; ++j) {
      int cl = wc * CW + j * 16 + (lane & 15);
      int n = colB0 + cl;
      float bv = 0.f;
      if (BIAS) bv = (n < N) ? bias[(long)z * sBias + n] : 0.f;
#pragma unroll
      for (int i = 0; i < 4; ++i) {
        int r0 = wr * 64 + i * 16 + ((lane >> 4) << 2);
#pragma unroll
        for (int r = 0; r < 4; ++r) {
          float v = acc[i][j][r] + bv;
          if (RELU) v = fmaxf(v, 0.f);
          ep[(r0 + r) * EPP + cl] = f2b(v);
        }
      }
    }
    __syncthreads();
#pragma unroll
    for (int pass = 0; pass < TM / 16; ++pass) {
      int row = pass * 16 + (t >> 4);
      int c0 = (t & 15) * 8;
      long base = (long)(rowA0 + row) * ldc + (long)z * sC + colB0;
      if (c0 + 8 <= Nrem) {
        u32x4 v = *(const u32x4*)(ep + row * EPP + c0);
        *(u32x4*)(Cb + base + c0) = v;
      } else if (c0 < Nrem) {
        for (int q = c0; q < Nrem && q < 128; ++q) Cb[base + q] = (bfraw)ep[row * EPP + q];
      }
    }
  }
  if (OUTF32) {
    float* ep = (float*)smem;
#pragma unroll
    for (int j = 0; j < JT; ++j) {
      int cl = wc * CW + j * 16 + (lane & 15);
      int n = colB0 + cl;
      float bv = 0.f;
      if (BIAS) bv = (n < N) ? bias[(long)z * sBias + n] : 0.f;
#pragma unroll
      for (int i = 0; i < 4; ++i) {
        int r0 = wr * 64 + i * 16 + ((lane >> 4) << 2);
#pragma unroll
        for (int r = 0; r < 4; ++r) {
          float v = acc[i][j][r] + bv;
          if (RELU) v = fmaxf(v, 0.f);
          ep[(r0 + r) * EPP + cl] = v;
        }
      }
    }
    __syncthreads();
#pragma unroll
    for (int pass = 0; pass < TM / 8; ++pass) {
      int row = pass * 8 + (t >> 5);
      int c0 = (t & 31) * 4;
      long base = (long)(rowA0 + row) * ldc + (long)z * sC + colB0;
      if (c0 + 4 <= Nrem) {
        f32x4 v = *(const f32x4*)(ep + row * EPP + c0);
        *(f32x4*)(Cf + base + c0) = v;
      } else if (c0 < Nrem) {
        for (int q = c0; q < Nrem && q < 128; ++q) Cf[base + q] = ep[row * EPP + q];
      }
    }
  }
}

// ---------------- per-row top-64 of one bf16 score chunk (2-level radix select) ----------------
__global__ __launch_bounds__(256) void k_select(const bfraw* __restrict__ scores,
                                                float* __restrict__ cval, int* __restrict__ cidx,
                                                int chunk) {
  __shared__ unsigned short keys[CHUNK];
  __shared__ unsigned hist[256];
  __shared__ unsigned sh_sel, sh_rank, cnt_a, cnt_t;
  __shared__ unsigned tiebuf[64];
  const int t = threadIdx.x;
  const long b = blockIdx.x;
  const bfraw* row = scores + b * CHUNK_LD;
  for (int i = t; i < CHUNK; i += 256) {
    unsigned u = row[i];
    keys[i] = (u & 0x8000u) ? (unsigned short)(~u) : (unsigned short)(u | 0x8000u);
  }
  if (t == 0) { cnt_a = 0; cnt_t = 0; }
  unsigned prefix = 0, pmask = 0, rank = 64;
  for (int lev = 0; lev < 2; ++lev) {
    const int sh = 8 - lev * 8;
    hist[t] = 0;
    __syncthreads();
    for (int i = t; i < CHUNK; i += 256) {
      unsigned k = keys[i];
      if ((k & pmask) == prefix) atomicAdd(&hist[(k >> sh) & 255u], 1u);
    }
    __syncthreads();
    if (t < 64) {  // wave0: suffix-scan buckets, find bucket containing rank
      unsigned h0 = hist[t * 4], h1 = hist[t * 4 + 1], h2 = hist[t * 4 + 2], h3 = hist[t * 4 + 3];
      unsigned lsum = h0 + h1 + h2 + h3;
      unsigned suf = lsum;
#pragma unroll
      for (int off = 1; off < 64; off <<= 1) {
        unsigned vv = __shfl_down(suf, off);
        if (t + off < 64) suf += vv;
      }
      unsigned c = suf - lsum;
      unsigned hs[4] = {h0, h1, h2, h3};
#pragma unroll
      for (int q = 3; q >= 0; --q) {
        if (rank > c && rank <= c + hs[q]) { sh_sel = (unsigned)(t * 4 + q); sh_rank = rank - c; }
        c += hs[q];
      }
    }
    __syncthreads();
    prefix |= sh_sel << sh;
    pmask |= 255u << sh;
    rank = sh_rank;
    __syncthreads();
  }
  const unsigned cutkey = prefix;
  float* ov = cval + (b * NCHUNK + chunk) * 64;
  int* oi = cidx + (b * NCHUNK + chunk) * 64;
  for (int i = t; i < CHUNK; i += 256) {
    unsigned k = keys[i];
    if (k > cutkey) {
      unsigned p = atomicAdd(&cnt_a, 1u);
      ov[p] = keyinv16(k);
      oi[p] = chunk * CHUNK + i;
    } else if (k == cutkey) {
      unsigned p = atomicAdd(&cnt_t, 1u);
      if (p < 64) tiebuf[p] = (unsigned)i;
    }
  }
  __syncthreads();
  if (t == 0) {  // fill remaining slots from ties (lowest index first)
    int need = (int)rank;
    int tc = cnt_t < 64u ? (int)cnt_t : 64;
    int base = (int)cnt_a;
    float cv = keyinv16(cutkey);
    for (int s2 = 0; s2 < need; ++s2) {
      unsigned best = 0xFFFFFFFFu; int bq = 0;
      for (int q2 = 0; q2 < tc; ++q2)
        if (tiebuf[q2] < best) { best = tiebuf[q2]; bq = q2; }
      tiebuf[bq] = 0xFFFFFFFFu;
      ov[base + s2] = cv;
      oi[base + s2] = chunk * CHUNK + (int)best;
    }
  }
}

// ---------------- Refine: sort 512 cands, exact fp32 rescore top-64, top-32 + softmax ----------------
// Rescore: one WAVE per candidate row (coalesced 2KB burst, x-slice in registers,
// 6-step shfl reduce), 16 independent rows per wave for memory-level parallelism.
__global__ __launch_bounds__(256) void k_refine(const float* __restrict__ cval,
                                                const int* __restrict__ cidx,
                                                const float* __restrict__ x,
                                                const float* __restrict__ cf,
                                                int* __restrict__ tidx, float* __restrict__ w) {
  __shared__ float sv[512];
  __shared__ int si[512];
  __shared__ float xs[512];
  __shared__ float rv[64];
  __shared__ int ri[64];
  const int t = threadIdx.x;
  const int lane = t & 63, wave = t >> 6;
  const long b = blockIdx.x;
  sv[t] = cval[b * 512 + t]; sv[t + 256] = cval[b * 512 + t + 256];
  si[t] = cidx[b * 512 + t]; si[t + 256] = cidx[b * 512 + t + 256];
  xs[t] = x[b * 512 + t]; xs[t + 256] = x[b * 512 + t + 256];
  __syncthreads();
  for (int k = 2; k <= 512; k <<= 1)
    for (int j = k >> 1; j >= 1; j >>= 1) {
      int i = ((t & ~(j - 1)) << 1) | (t & (j - 1));
      int p = i | j;
      bool dir = ((i & k) == 0);
      float va = sv[i], vb = sv[p];
      int ia = si[i], ib = si[p];
      bool pBetter = (vb > va) || (vb == va && ib < ia);
      if (pBetter == dir) { sv[i] = vb; sv[p] = va; si[i] = ib; si[p] = ia; }
      __syncthreads();
    }
  // exact fp32 rescore of top-64: wave per row, coalesced
  float xr[8];
  {
    float4 a = *(const float4*)(xs + lane * 8);
    float4 b2 = *(const float4*)(xs + lane * 8 + 4);
    xr[0] = a.x; xr[1] = a.y; xr[2] = a.z; xr[3] = a.w;
    xr[4] = b2.x; xr[5] = b2.y; xr[6] = b2.z; xr[7] = b2.w;
  }
#pragma unroll
  for (int k = 0; k < 16; ++k) {
    int c = wave * 16 + k;
    int idx = si[c];
    const float* cr = cf + (long)idx * 512 + lane * 8;
    float4 v0 = *(const float4*)cr;
    float4 v1 = *(const float4*)(cr + 4);
    float s = v0.x * xr[0] + v0.y * xr[1] + v0.z * xr[2] + v0.w * xr[3]
            + v1.x * xr[4] + v1.y * xr[5] + v1.z * xr[6] + v1.w * xr[7];
#pragma unroll
    for (int off = 1; off < 64; off <<= 1) s += __shfl_xor(s, off);
    if (lane == 0) { rv[c] = s; ri[c] = idx; }
  }
  __syncthreads();
  if (t < 64) {
    float v = rv[t];
    int ix = ri[t];
    for (int k = 2; k <= 64; k <<= 1)
      for (int j = k >> 1; j >= 1; j >>= 1) {
        float ov = __shfl_xor(v, j);
        int oi = __shfl_xor(ix, j);
        bool up = ((t & k) == 0);
        bool low = ((t & j) == 0);
        bool oBetter = (ov > v) || (ov == v && oi < ix);
        if (oBetter == (up == low)) { v = ov; ix = oi; }
      }
    float m = __shfl(v, 0);
    float e = (t < 32) ? __expf(v - m) : 0.f;
    float ssum = e;
#pragma unroll
    for (int off = 1; off < 64; off <<= 1) ssum += __shfl_xor(ssum, off);
    if (t < 32) {
      w[b * 32 + t] = e / ssum;
      tidx[b * 32 + t] = ix;
    }
  }
}

// ---------------- Build kv (B,33,512) bf16 ----------------
__global__ __launch_bounds__(256) void k_buildkv(const float* __restrict__ x, const bfraw* __restrict__ cfb,
                                                 const float* __restrict__ type_emb,
                                                 const float* __restrict__ pos_emb,
                                                 const float* __restrict__ w, const int* __restrict__ tidx,
                                                 bfraw* __restrict__ kv) {
  const int t = threadIdx.x;
  const long b = blockIdx.x;
  bfraw* out = kv + b * (33 * 512);
  const float* xr = x + b * 512;
  for (int d = t; d < 512; d += 256) out[d] = f2b(xr[d] + type_emb[d]);
  for (int j = 0; j < 32; ++j) {
    const long ci = tidx[b * 32 + j];
    const float wj = w[b * 32 + j];
    const bfraw* cr = cfb + ci * 512;
    bfraw* o = out + (j + 1) * 512;
    for (int d = t; d < 512; d += 256)
      o[d] = f2b(wj * b2f(cr[d]) + pos_emb[j * 512 + d] + type_emb[512 + d]);
  }
}

// ---------------- t init ----------------
__global__ __launch_bounds__(256) void k_init_t(const float* __restrict__ cls, float* __restrict__ tf,
                                                bfraw* __restrict__ tb) {
  const long i = (long)blockIdx.x * 256 + threadIdx.x;
  const int d = (int)(i & 511);
  tf[i] = cls[d];
  tb[i] = f2b(cls[d]);
}

// ---------------- wkT prep: wkT[i,h,d,e] = ca_in_w[i, 512 + h*64 + e, d] ----------------
__global__ __launch_bounds__(256) void k_prep(const float* __restrict__ ca_in_w, bfraw* __restrict__ wkT) {
  const long o = (long)blockIdx.x * 256 + threadIdx.x;
  const int e = (int)(o & 63);
  long r = o >> 6;
  const int d = (int)(r & 511); r >>= 9;
  const int h = (int)(r & 7);
  const int i = (int)(r >> 3);
  wkT[o] = f2b(ca_in_w[((long)i * 1536 + 512 + h * 64 + e) * 512 + d]);
}

// ---------------- CA attention core: MFMA QK^T + scalar PV ----------------
__global__ __launch_bounds__(256) void k_attn(const bfraw* __restrict__ u, const bfraw* __restrict__ kv,
                                              bfraw* __restrict__ cout) {
  __shared__ __align__(16) bfraw kvs[33 * 512];
  __shared__ __align__(16) bfraw us[8 * 512];
  __shared__ float ps[8 * 48];
  const int t = threadIdx.x, lane = t & 63, wave = t >> 6;
  const long b = blockIdx.x;
  const bfraw* kvg = kv + b * (33 * 512);
  const bfraw* ug = u + b * (8 * 512);

  // stage: logical chunk c (0..63) of row r lives at LDS chunk c; global source is
  // chunk (c&56)|((c&7)^(r&7)) so that swizzled READS return logical data.
  {
#pragma unroll
    for (int r = 0; r < 8; ++r) {
      int row = r * 4 + wave;  // wave-uniform
      int sc = (lane & 56) | ((lane & 7) ^ (row & 7));
      __builtin_amdgcn_global_load_lds((const unsigned int*)(kvg + row * 512 + sc * 8),
                                       (unsigned int*)(kvs + row * 512), 16, 0, 0);
    }
    if (wave == 0)
      __builtin_amdgcn_global_load_lds((const unsigned int*)(kvg + 32 * 512 + lane * 8),
                                       (unsigned int*)(kvs + 32 * 512), 16, 0, 0);
#pragma unroll
    for (int r = 0; r < 2; ++r) {
      int row = r * 4 + wave;
      int sc = (lane & 56) | ((lane & 7) ^ (row & 7));
      __builtin_amdgcn_global_load_lds((const unsigned int*)(ug + row * 512 + sc * 8),
                                       (unsigned int*)(us + row * 512), 16, 0, 0);
    }
  }
  __syncthreads();

  // ---- QK^T ----
  if (wave < 2) {
    const int jj = wave * 16 + (lane & 15);  // B row (j), all valid (0..31)
    const int rr = lane & 7;                 // A row: duplicate heads into rows 8..15
    f32x4 acc = {0.f, 0.f, 0.f, 0.f};
#pragma unroll
    for (int ks = 0; ks < 16; ++ks) {
      int q = ks * 4 + (lane >> 4);  // logical chunk 0..63
      short8 af = *(const short8*)(us + rr * 512 + (((q & 56) | ((q & 7) ^ rr)) * 8));
      short8 bf = *(const short8*)(kvs + jj * 512 + (((q & 56) | ((q & 7) ^ (jj & 7))) * 8));
      acc = __builtin_amdgcn_mfma_f32_16x16x32_bf16(af, bf, acc, 0, 0, 0);
    }
#pragma unroll
    for (int r = 0; r < 4; ++r) {
      int row = (lane >> 4) * 4 + r;
      if (row < 8) ps[row * 48 + wave * 16 + (lane & 15)] = acc[r] * 0.125f;
    }
  } else if (wave == 2) {
    // j = 32 column: scalar dot, 8 lanes per head
    int h = lane >> 3, seg = lane & 7;
    float s = 0.f;
#pragma unroll
    for (int i = 0; i < 8; ++i) {
      int c = seg * 8 + i;
      short8 kk = *(const short8*)(kvs + 32 * 512 + c * 8);  // row 32: r&7==0, unswizzled
      short8 uu = *(const short8*)(us + h * 512 + (((c & 56) | ((c & 7) ^ h)) * 8));
#pragma unroll
      for (int e = 0; e < 8; ++e) s += b2f((bfraw)uu[e]) * b2f((bfraw)kk[e]);
    }
    s += __shfl_xor(s, 1);
    s += __shfl_xor(s, 2);
    s += __shfl_xor(s, 4);
    if (seg == 0) ps[h * 48 + 32] = s * 0.125f;
  }
  __syncthreads();

  // ---- softmax (2 heads per wave) ----
#pragma unroll
  for (int hh = 0; hh < 2; ++hh) {
    int h = wave + hh * 4;
    float sv2 = (lane < 33) ? ps[h * 48 + lane] : -3.0e38f;
    float m = sv2;
#pragma unroll
    for (int off = 1; off < 64; off <<= 1) m = fmaxf(m, __shfl_xor(m, off));
    float e = (lane < 33) ? __expf(sv2 - m) : 0.f;
    float s = e;
#pragma unroll
    for (int off = 1; off < 64; off <<= 1) s += __shfl_xor(s, off);
    if (lane < 33) ps[h * 48 + lane] = e / s;
  }
  __syncthreads();

  // ---- PV (scalar, swizzle-aware) ----
#pragma unroll
  for (int hh = 0; hh < 2; ++hh) {
    int h = wave + hh * 4;
    float acc[8] = {0.f, 0.f, 0.f, 0.f, 0.f, 0.f, 0.f, 0.f};
    for (int j = 0; j < 33; ++j) {
      float pj = ps[h * 48 + j];
      int c = (lane & 56) | ((lane & 7) ^ (j & 7));
      short8 kk = *(const short8*)(kvs + j * 512 + c * 8);
#pragma unroll
      for (int q = 0; q < 8; ++q) acc[q] += pj * b2f((bfraw)kk[q]);
    }
    union { bfraw o[8]; uint4 v4; } pk;
#pragma unroll
    for (int q = 0; q < 8; ++q) pk.o[q] = f2b(acc[q]);
    *(uint4*)(cout + (b * 8 + h) * 512 + lane * 8) = pk.v4;
  }
}

// ---------------- residual + LayerNorm ----------------
__global__ __launch_bounds__(256) void k_ln(float* __restrict__ tf, bfraw* __restrict__ tb,
                                            const float* __restrict__ delta,
                                            const float* __restrict__ g, const float* __restrict__ be) {
  const int lane = threadIdx.x & 63, wave = threadIdx.x >> 6;
  const long row = (long)blockIdx.x * 4 + wave;
  float* tr = tf + row * 512;
  const float* dr = delta + row * 512;
  float v[8];
  float4 a0 = *(const float4*)(tr + lane * 8);
  float4 a1 = *(const float4*)(tr + lane * 8 + 4);
  float4 d0 = *(const float4*)(dr + lane * 8);
  float4 d1 = *(const float4*)(dr + lane * 8 + 4);
  v[0] = a0.x + d0.x; v[1] = a0.y + d0.y; v[2] = a0.z + d0.z; v[3] = a0.w + d0.w;
  v[4] = a1.x + d1.x; v[5] = a1.y + d1.y; v[6] = a1.z + d1.z; v[7] = a1.w + d1.w;
  float s = 0.f;
#pragma unroll
  for (int q = 0; q < 8; ++q) s += v[q];
#pragma unroll
  for (int off = 1; off < 64; off <<= 1) s += __shfl_xor(s, off);
  const float mean = s * (1.f / 512.f);
  float sq = 0.f;
#pragma unroll
  for (int q = 0; q < 8; ++q) { float d = v[q] - mean; sq += d * d; }
#pragma unroll
  for (int off = 1; off < 64; off <<= 1) sq += __shfl_xor(sq, off);
  const float rs = 1.f / sqrtf(sq * (1.f / 512.f) + 1e-5f);
  float4 g0 = *(const float4*)(g + lane * 8);
  float4 g1 = *(const float4*)(g + lane * 8 + 4);
  float4 b0 = *(const float4*)(be + lane * 8);
  float4 b1 = *(const float4*)(be + lane * 8 + 4);
  float gg[8] = {g0.x, g0.y, g0.z, g0.w, g1.x, g1.y, g1.z, g1.w};
  float bb[8] = {b0.x, b0.y, b0.z, b0.w, b1.x, b1.y, b1.z, b1.w};
  float o[8];
  union { bfraw u16[8]; uint4 u4; } pk;
#pragma unroll
  for (int q = 0; q < 8; ++q) {
    o[q] = (v[q] - mean) * rs * gg[q] + bb[q];
    pk.u16[q] = f2b(o[q]);
  }
  *(float4*)(tr + lane * 8) = make_float4(o[0], o[1], o[2], o[3]);
  *(float4*)(tr + lane * 8 + 4) = make_float4(o[4], o[5], o[6], o[7]);
  *(uint4*)(tb + row * 512 + lane * 8) = pk.u4;
}

// ---------------- final triple-normalize ----------------
__global__ __launch_bounds__(64) void k_final(const float* __restrict__ tf, const float* __restrict__ coarse,
                                              float* __restrict__ out) {
  const int lane = threadIdx.x;
  const long b = blockIdx.x;
  const float* fr = tf + b * 512;
  const float* cr = coarse + b * 512;
  float4 f0 = *(const float4*)(fr + lane * 8);
  float4 f1 = *(const float4*)(fr + lane * 8 + 4);
  float4 c0 = *(const float4*)(cr + lane * 8);
  float4 c1 = *(const float4*)(cr + lane * 8 + 4);
  float f[8] = {f0.x, f0.y, f0.z, f0.w, f1.x, f1.y, f1.z, f1.w};
  float c[8] = {c0.x, c0.y, c0.z, c0.w, c1.x, c1.y, c1.z, c1.w};
  float sf = 0.f, sc = 0.f;
#pragma unroll
  for (int q = 0; q < 8; ++q) { sf += f[q] * f[q]; sc += c[q] * c[q]; }
#pragma unroll
  for (int off = 1; off < 64; off <<= 1) { sf += __shfl_xor(sf, off); sc += __shfl_xor(sc, off); }
  const float rf = 1.f / sqrtf(sf), rc = 1.f / sqrtf(sc);
  float a[8];
  float sa = 0.f;
#pragma unroll
  for (int q = 0; q < 8; ++q) { a[q] = f[q] * rf + c[q] * rc; sa += a[q] * a[q]; }
#pragma unroll
  for (int off = 1; off < 64; off <<= 1) sa += __shfl_xor(sa, off);
  const float ra = 1.f / sqrtf(sa);
  *(float4*)(out + b * 512 + lane * 8) = make_float4(a[0] * ra, a[1] * ra, a[2] * ra, a[3] * ra);
  *(float4*)(out + b * 512 + lane * 8 + 4) = make_float4(a[4] * ra, a[5] * ra, a[6] * ra, a[7] * ra);
}

// ---------------- workspace layout (bytes) ----------------
constexpr long OFF_XB = 0;                    //  4,194,304
constexpr long OFF_WKT = 4194304;             //  3,145,728
constexpr long OFF_SAOUT = 7340032;           //  3,145,728 (Wo bf16)
constexpr long OFF_WSAB = 10485760;           //  3,145,728 (Wsa bf16)
constexpr long OFF_CAWQ = 13631488;           //  3,145,728
constexpr long OFF_CAWV = 16777216;           //  3,145,728
constexpr long OFF_CAOUT = 19922944;          //  3,145,728
constexpr long OFF_REGW = 23068672;           //    524,288
constexpr long OFF_L1B = 23592960;            // 12,582,912 (all layers)
constexpr long OFF_L2B = 36175872;            // 12,582,912
constexpr long OFF_BSA = 48758784;            //     16,384
constexpr long OFF_TIDX = 48775168;           //    524,288
constexpr long OFF_WSM = 49299456;            //    524,288
constexpr long OFF_REGION = 49823744;         // 138,412,032 (WvT preamble / score bf16 / kv)
constexpr long OFF_POOL = 188235776;          // 83,886,080
constexpr long P_TF = 0;                      // 8,388,608 fp32 (phase1: cval)
constexpr long P_TB = 8388608;                // 4,194,304 bf16 (phase1: cidx lo)
constexpr long P_QBF = 12582912;              // 4,194,304 bf16 (phase1: cidx hi)
constexpr long P_UBUF = 16777216;             // 33,554,432 (phase1: cfb 51.2MB spans UBUF+part CBUF)
constexpr long P_CBUF = 50331648;             // 33,554,432 (delta +0, coarse +8,388,608)
constexpr long WS_TOTAL = OFF_POOL + 83886080;  // 272,121,856

extern "C" void kernel_launch(void* const* d_in, const int* in_sizes, int n_in,
                              void* d_out, int out_size, void* d_ws, size_t ws_size,
                              hipStream_t stream) {
  if (n_in < 25) return;
  if (ws_size < (size_t)WS_TOTAL) return;

  const float* x = (const float*)d_in[0];
  const float* cf = (const float*)d_in[1];
  const float* type_emb = (const float*)d_in[2];
  const float* pos_emb = (const float*)d_in[3];
  const float* cls = (const float*)d_in[4];
  const float* sa_in_w = (const float*)d_in[5];
  const float* sa_in_b = (const float*)d_in[6];
  const float* sa_out_w = (const float*)d_in[7];
  const float* sa_out_b = (const float*)d_in[8];
  const float* ca_in_w = (const float*)d_in[9];
  const float* ca_in_b = (const float*)d_in[10];
  const float* ca_out_w = (const float*)d_in[11];
  const float* ca_out_b = (const float*)d_in[12];
  const float* lin1_w = (const float*)d_in[13];
  const float* lin1_b = (const float*)d_in[14];
  const float* lin2_w = (const float*)d_in[15];
  const float* lin2_b = (const float*)d_in[16];
  const float* ln1_g = (const float*)d_in[17];
  const float* ln1_bp = (const float*)d_in[18];
  const float* ln2_g = (const float*)d_in[19];
  const float* ln2_bp = (const float*)d_in[20];
  const float* ln3_g = (const float*)d_in[21];
  const float* ln3_bp = (const float*)d_in[22];
  const float* region_w = (const float*)d_in[23];
  const float* region_b = (const float*)d_in[24];

  char* ws = (char*)d_ws;
  bfraw* xb = (bfraw*)(ws + OFF_XB);
  bfraw* wkT = (bfraw*)(ws + OFF_WKT);
  bfraw* saout = (bfraw*)(ws + OFF_SAOUT);
  bfraw* wsab = (bfraw*)(ws + OFF_WSAB);
  bfraw* cawq = (bfraw*)(ws + OFF_CAWQ);
  bfraw* cawv = (bfraw*)(ws + OFF_CAWV);
  bfraw* caout = (bfraw*)(ws + OFF_CAOUT);
  bfraw* regw = (bfraw*)(ws + OFF_REGW);
  bfraw* l1b = (bfraw*)(ws + OFF_L1B);
  bfraw* l2b = (bfraw*)(ws + OFF_L2B);
  float* bsa = (float*)(ws + OFF_BSA);
  int* tidx = (int*)(ws + OFF_TIDX);
  float* wsm = (float*)(ws + OFF_WSM);
  bfraw* WvT = (bfraw*)(ws + OFF_REGION);  // preamble only
  bfraw* scoreb = (bfraw*)(ws + OFF_REGION);
  bfraw* kv = (bfraw*)(ws + OFF_REGION);
  char* pool = ws + OFF_POOL;
  float* tf = (float*)(pool + P_TF);
  float* cval = (float*)(pool + P_TF);
  bfraw* tb = (bfraw*)(pool + P_TB);
  int* cidx = (int*)(pool + P_TB);
  bfraw* qbf = (bfraw*)(pool + P_QBF);
  bfraw* tmpb = (bfraw*)(pool + P_QBF);
  bfraw* ubuf = (bfraw*)(pool + P_UBUF);
  bfraw* ffb = (bfraw*)(pool + P_UBUF);
  bfraw* cfb = (bfraw*)(pool + P_UBUF);  // 51.2 MB, phase-1 only
  bfraw* cbuf = (bfraw*)(pool + P_CBUF);
  float* delta = (float*)(pool + P_CBUF);
  float* coarse = (float*)(pool + P_CBUF + 8388608);

  dim3 blk(256);

  // ---- preamble: conversions + SA fold ----
  k_cvt<<<2048, blk, 0, stream>>>(x, xb, 524288);
  k_cvt<<<25000, blk, 0, stream>>>(cf, cfb, 6400000);
  k_cvt<<<1536, blk, 0, stream>>>(sa_out_w, saout, 393216);
  k_cvt<<<1536, blk, 0, stream>>>(ca_out_w, caout, 393216);
  k_cvt<<<256, blk, 0, stream>>>(region_w, regw, 65536);
  k_cvt<<<6144, blk, 0, stream>>>(lin1_w, l1b, 1572864);
  k_cvt<<<6144, blk, 0, stream>>>(lin2_w, l2b, 1572864);
  k_cvt_s<<<1536, blk, 0, stream>>>(ca_in_w, cawq, 65536, 196608, 6);
  k_cvt_s<<<1536, blk, 0, stream>>>(ca_in_w + 1024 * 512, cawv, 65536, 196608, 6);
  k_prep<<<6144, blk, 0, stream>>>(ca_in_w, wkT);
  k_tr<<<dim3(16, 16, 6), blk, 0, stream>>>(sa_in_w, WvT);
  k_gemm<64, false, true, false, false, false><<<dim3(4, 8, 6), blk, 0, stream>>>(
      saout, 512, 262144, WvT, 512, 262144, nullptr, wsab, 512, 262144, nullptr, 0, 512, 512);
  k_bsa<<<6, blk, 0, stream>>>(sa_out_w, sa_in_b, sa_out_b, bsa);

  // ---- score GEMM (bf16 out, XCD-swizzled) + per-chunk top-64 ----
  for (int c = 0; c < NCHUNK; ++c) {
    k_gemm<128, false, true, false, false, true><<<dim3(1792, 1, 1), blk, 0, stream>>>(
        xb, 512, 0, cfb + (long)c * CHUNK * 512, 512, 0,
        nullptr, scoreb, CHUNK_LD, 0, nullptr, 0, CHUNK, 512);
    k_select<<<4096, blk, 0, stream>>>(scoreb, cval, cidx, c);
  }
  k_refine<<<4096, blk, 0, stream>>>(cval, cidx, x, cf, tidx, wsm);
  k_buildkv<<<4096, blk, 0, stream>>>(x, cfb, type_emb, pos_emb, wsm, tidx, kv);
  k_init_t<<<8192, blk, 0, stream>>>(cls, tf, tb);

  for (int i = 0; i < LAYERS; ++i) {
    const bfraw* ca_wq = cawq + (long)i * 262144;
    const float* ca_bq = ca_in_b + (long)i * 1536;
    const bfraw* ca_wv = cawv + (long)i * 262144;
    const float* ca_bv = ca_in_b + (long)i * 1536 + 1024;
    const bfraw* ca_wo = caout + (long)i * 262144;
    const float* ca_bo = ca_out_b + (long)i * 512;
    const bfraw* wkTi = wkT + (long)i * 8 * 512 * 64;

    // Self-attention folded: delta = t @ Wsa^T + bsa
    k_gemm<64, true, false, false, true, false><<<dim3(4, 64, 1), blk, 0, stream>>>(
        tb, 512, 0, wsab + (long)i * 262144, 512, 0, delta, nullptr, 512, 0, bsa + i * 512, 0, 512, 512);
    k_ln<<<1024, blk, 0, stream>>>(tf, tb, delta, ln1_g + i * 512, ln1_bp + i * 512);

    // Cross-attention (re-associated)
    k_gemm<64, false, true, false, true, false><<<dim3(4, 64, 1), blk, 0, stream>>>(
        tb, 512, 0, ca_wq, 512, 0, nullptr, qbf, 512, 0, ca_bq, 0, 512, 512);
    k_gemm<64, false, true, false, false, false><<<dim3(4, 64, 8), blk, 0, stream>>>(
        qbf, 512, 64, wkTi, 64, 32768, nullptr, ubuf, 4096, 512, nullptr, 0, 512, 64);
    k_attn<<<4096, blk, 0, stream>>>(ubuf, kv, cbuf);
    k_gemm<64, false, true, false, true, false><<<dim3(1, 64, 8), blk, 0, stream>>>(
        cbuf, 4096, 512, ca_wv, 512, 32768, nullptr, tmpb, 512, 64, ca_bv, 64, 64, 512);
    k_gemm<64, true, false, false, true, false><<<dim3(4, 64, 1), blk, 0, stream>>>(
        tmpb, 512, 0, ca_wo, 512, 0, delta, nullptr, 512, 0, ca_bo, 0, 512, 512);
    k_ln<<<1024, blk, 0, stream>>>(tf, tb, delta, ln2_g + i * 512, ln2_bp + i * 512);

    // FFN
    k_gemm<64, false, true, true, true, false><<<dim3(16, 64, 1), blk, 0, stream>>>(
        tb, 512, 0, l1b + (long)i * 1048576, 512, 0, nullptr, ffb, 2048, 0, lin1_b + i * 2048, 0, 2048, 512);
    k_gemm<64, true, false, false, true, false><<<dim3(4, 64, 1), blk, 0, stream>>>(
        ffb, 2048, 0, l2b + (long)i * 1048576, 2048, 0, delta, nullptr, 512, 0, lin2_b + i * 512, 0, 512, 2048);
    k_ln<<<1024, blk, 0, stream>>>(tf, tb, delta, ln3_g + i * 512, ln3_bp + i * 512);
  }

  k_gemm<64, true, false, false, true, false><<<dim3(4, 64, 1), blk, 0, stream>>>(
      xb, 512, 0, regw, 512, 0, coarse, nullptr, 512, 0, region_b, 0, 512, 512);
  k_final<<<4096, dim3(64), 0, stream>>>(tf, coarse, (float*)d_out);
}